// Round 6
// baseline (7894.320 us; speedup 1.0000x reference)
//
#include <hip/hip_runtime.h>
#include <hip/hip_bf16.h>
#include <stdint.h>
#include <stddef.h>

// ---------------------------------------------------------------------------
// Seq2Seq BiGRU: B=256 T=512 F=64 H=256 (2-layer bidir encoder),
// decoder DH=512 2-layer, OSL=20, OUT=2.
//
// Round-8 structure:
//  - prep_all / gru_scan / fc_all unchanged (r3-proven).
//  - gemm_gi: r3-proven m-major grid restored (r5's n-major: wall +102 us).
//  - dec_batch REPLACES dec_persist: r3-r5 proved the cross-WG phase
//    structure has a fixed ~20us/phase toll regardless of work placement
//    (810us invariant). New decomposition: 16 WGs x 512 thr, each WG owns
//    16 batch rows and computes the FULL 512-j state for both cells; h0/h1
//    are LDS-resident (2x16KB swizzled), f32 carries in registers, sync is
//    4 __syncthreads()/step. Zero atomics / zero inter-WG traffic.
//    Cost model: 100 MFLOP/WG/step -> ~12.4us/step compute on 16 CUs,
//    weights 6.3MB/step/WG stream from L2/L3 (2 WGs/XCD) under the floor.
// ---------------------------------------------------------------------------

typedef __bf16 bf16_t;
typedef bf16_t bf16x8 __attribute__((ext_vector_type(8)));
typedef float  f32x4  __attribute__((ext_vector_type(4)));

#define B_   256
#define T_   512
#define F_   64
#define H_   256
#define G_   768      // 3*H
#define DH_  512
#define DG_  1536     // 3*DH
#define OSL_ 20

__device__ __forceinline__ float sigm(float x) {
    float e = __builtin_amdgcn_exp2f(-1.442695040888963f * x);
    return __builtin_amdgcn_rcpf(1.0f + e);
}
__device__ __forceinline__ float tanh_(float x) {
    float e = __builtin_amdgcn_exp2f(-2.885390081777927f * x);
    return __builtin_amdgcn_rcpf(1.0f + e) * 2.0f - 1.0f;
}

__device__ __forceinline__ bf16x8 load_f32x8_as_bf16(const float* p) {
    f32x4 u = *(const f32x4*)p;
    f32x4 v = *(const f32x4*)(p + 4);
    bf16x8 r;
    r[0]=(bf16_t)u[0]; r[1]=(bf16_t)u[1]; r[2]=(bf16_t)u[2]; r[3]=(bf16_t)u[3];
    r[4]=(bf16_t)v[0]; r[5]=(bf16_t)v[1]; r[6]=(bf16_t)v[2]; r[7]=(bf16_t)v[3];
    return r;
}

// ------------------------------- fused prep --------------------------------
__global__ __launch_bounds__(256) void prep_all(
    const float* __restrict__ s0, const float* __restrict__ s1,
    const float* __restrict__ s2, const float* __restrict__ s3,
    const float* __restrict__ s4, const float* __restrict__ s5,
    const float* __restrict__ s6,
    bf16_t* __restrict__ d0, bf16_t* __restrict__ d1, bf16_t* __restrict__ d2,
    bf16_t* __restrict__ d3, bf16_t* __restrict__ d4, bf16_t* __restrict__ d5,
    bf16_t* __restrict__ d6,
    const float* __restrict__ wih0d, const float* __restrict__ fcw,
    const float* __restrict__ fcb, const float* __restrict__ bih0d,
    const float* __restrict__ st, bf16_t* __restrict__ weff,
    float* __restrict__ beff, float* __restrict__ ov) {
    int i = blockIdx.x * 256 + threadIdx.x;
    switch (blockIdx.y) {
      case 0: if (i < 2*G_*F_)  d0[i] = (bf16_t)s0[i]; break;
      case 1: if (i < 2*G_*H_)  d1[i] = (bf16_t)s1[i]; break;
      case 2: if (i < 2*G_*DH_) d2[i] = (bf16_t)s2[i]; break;
      case 3: if (i < 2*G_*H_)  d3[i] = (bf16_t)s3[i]; break;
      case 4: if (i < DG_*DH_)  d4[i] = (bf16_t)s4[i]; break;
      case 5: if (i < DG_*DH_)  d5[i] = (bf16_t)s5[i]; break;
      case 6: if (i < DG_*DH_)  d6[i] = (bf16_t)s6[i]; break;
      default: {
        if (i < DG_*DH_) {
          int g = i >> 9, k = i & 511;
          float a0 = wih0d[g * 2], a1 = wih0d[g * 2 + 1];
          weff[i] = (bf16_t)(a0 * fcw[k] + a1 * fcw[DH_ + k]);
          if (k == 0) {
            beff[g] = a0 * fcb[0] + a1 * fcb[1] + bih0d[g];
            ov[g]   = a0 * st[0]  + a1 * st[1]  + bih0d[g];
          }
        }
      } break;
    }
}

// --------------------------- gi chunk GEMM ---------------------------------
__global__ __launch_bounds__(256) void gemm_gi(
    const float* __restrict__ x, const bf16_t* __restrict__ xcat,
    const bf16_t* __restrict__ Bt, bf16_t* __restrict__ gi, int t0, int K) {
    __shared__ bf16_t As[128 * 64];
    __shared__ bf16_t Bs[128 * 64];
    int m0 = blockIdx.x * 128, n0 = blockIdx.y * 128;
    int tid = threadIdx.x;
    int lane = tid & 63, w = tid >> 6;
    int col = lane & 15, quad = lane >> 4;
    int qm = (w >> 1) * 64, qn = (w & 1) * 64;

    int tl = m0 >> 8;              // local chunk time (constant per block)
    int bbase = m0 & 255;          // batch base (0 or 128)
    int t_real = t0 + tl;
    if (n0 >= 768) t_real = (T_ - 1) - t_real;

    f32x4 acc[4][4] = {};
    for (int k0 = 0; k0 < K; k0 += 64) {
        __syncthreads();
#pragma unroll
        for (int i = 0; i < 4; i++) {
            int c = i * 256 + tid;
            int m = c >> 3, kc = c & 7;
            int kcs = kc ^ (m & 7);   // XOR swizzle at source
            bf16x8 av;
            if (K == 64) {
                av = load_f32x8_as_bf16(x + ((size_t)(bbase + m) * T_ + t_real) * F_ + kcs * 8);
            } else {
                av = *(const bf16x8*)(xcat + ((size_t)t_real * B_ + bbase + m) * DH_ + k0 + kcs * 8);
            }
            *(bf16x8*)(&As[c * 8]) = av;
            *(bf16x8*)(&Bs[c * 8]) = *(const bf16x8*)(Bt + (size_t)(n0 + m) * K + k0 + kcs * 8);
        }
        __syncthreads();
#pragma unroll
        for (int kt = 0; kt < 2; kt++) {
            bf16x8 a[4], b[4];
#pragma unroll
            for (int mt = 0; mt < 4; mt++) {
                int r = qm + mt * 16 + col;
                a[mt] = *(const bf16x8*)(&As[(r * 8 + ((kt * 4 + quad) ^ (r & 7))) * 8]);
                int rn = qn + mt * 16 + col;
                b[mt] = *(const bf16x8*)(&Bs[(rn * 8 + ((kt * 4 + quad) ^ (rn & 7))) * 8]);
            }
#pragma unroll
            for (int mt = 0; mt < 4; mt++)
#pragma unroll
                for (int nt = 0; nt < 4; nt++)
                    acc[mt][nt] = __builtin_amdgcn_mfma_f32_16x16x32_bf16(a[mt], b[nt], acc[mt][nt], 0, 0, 0);
        }
    }
#pragma unroll
    for (int mt = 0; mt < 4; mt++)
#pragma unroll
        for (int nt = 0; nt < 4; nt++)
#pragma unroll
            for (int i = 0; i < 4; i++) {
                int row = m0 + qm + mt * 16 + quad * 4 + i;
                int cg  = n0 + qn + nt * 16 + col;
                gi[(size_t)row * DG_ + cg] = (bf16_t)acc[mt][nt][i];
            }
}

// ------------------------------ GRU scan (chunked) -------------------------
__global__ __launch_bounds__(512) void gru_scan(
    const bf16_t* __restrict__ gi, int t0, int tc,
    const bf16_t* __restrict__ whh,
    const float* __restrict__ bih, const float* __restrict__ bhh,
    float* __restrict__ hstate, bf16_t* __restrict__ y, float* __restrict__ hT) {
    __shared__ bf16_t gi_lds[16 * 768];       // [b][768]
    __shared__ bf16_t h_lds[2 * 16 * 264];    // [par][b][256+8 pad]

    int dir = blockIdx.x >> 4;
    int b0  = (blockIdx.x & 15) * 16;
    int tid = threadIdx.x;
    int w = tid >> 6, lane = tid & 63, col = lane & 15, quad = lane >> 4;

    bf16x8 wf[3][2][8];
    const bf16_t* wbase = whh + (size_t)dir * G_ * H_;
#pragma unroll
    for (int g = 0; g < 3; g++)
#pragma unroll
        for (int nt = 0; nt < 2; nt++) {
            int row = g * 256 + w * 32 + nt * 16 + col;
#pragma unroll
            for (int kt = 0; kt < 8; kt++)
                wf[g][nt][kt] = *(const bf16x8*)(wbase + (size_t)row * H_ + kt * 32 + quad * 8);
        }
    float brz[2][2], bin_[2], bhn[2];
#pragma unroll
    for (int nt = 0; nt < 2; nt++) {
        int j = w * 32 + nt * 16 + col;
        brz[0][nt] = bih[dir * G_ + j] + bhh[dir * G_ + j];
        brz[1][nt] = bih[dir * G_ + 256 + j] + bhh[dir * G_ + 256 + j];
        bin_[nt]   = bih[dir * G_ + 512 + j];
        bhn[nt]    = bhh[dir * G_ + 512 + j];
    }
    int bb[3], oo[3];
#pragma unroll
    for (int it = 0; it < 3; it++) {
        int c = it * 512 + tid;
        bb[it] = c / 96;
        oo[it] = (c % 96) * 8;
    }
    float hold[2][4];
#pragma unroll
    for (int nt = 0; nt < 2; nt++)
#pragma unroll
        for (int i = 0; i < 4; i++) {
            int j = w * 32 + nt * 16 + col;
            hold[nt][i] = t0 ? hstate[dir * 65536 + (b0 + quad * 4 + i) * 256 + j] : 0.0f;
        }
    for (int i = tid; i < 16 * 264; i += 512) {
        int b = i / 264, j = i % 264;
        float v = (t0 && j < 256) ? hstate[dir * 65536 + (b0 + b) * 256 + j] : 0.0f;
        h_lds[i] = (bf16_t)v;
    }
#pragma unroll
    for (int it = 0; it < 3; it++) {
        int c = it * 512 + tid;
        *(bf16x8*)(&gi_lds[c * 8]) =
            *(const bf16x8*)(gi + ((size_t)0 * B_ + b0 + bb[it]) * DG_ + dir * G_ + oo[it]);
    }
    __syncthreads();

    for (int s = 0; s < tc; s++) {
        int par = s & 1;
        int t = t0 + s;
        int sn = (s + 1 < tc) ? (s + 1) : s;

        bf16x8 pg[3];
#pragma unroll
        for (int it = 0; it < 3; it++)
            pg[it] = *(const bf16x8*)(gi + ((size_t)sn * B_ + b0 + bb[it]) * DG_ + dir * G_ + oo[it]);

        f32x4 acc[3][2] = {};
        const bf16_t* hcur = &h_lds[par * 4224];
#pragma unroll
        for (int kt = 0; kt < 8; kt++) {
            bf16x8 af = *(const bf16x8*)(hcur + col * 264 + kt * 32 + quad * 8);
#pragma unroll
            for (int g = 0; g < 3; g++)
#pragma unroll
                for (int nt = 0; nt < 2; nt++)
                    acc[g][nt] = __builtin_amdgcn_mfma_f32_16x16x32_bf16(af, wf[g][nt][kt], acc[g][nt], 0, 0, 0);
        }

        bf16_t* hnext = &h_lds[(par ^ 1) * 4224];
        int tp = dir ? (T_ - 1 - t) : t;
#pragma unroll
        for (int nt = 0; nt < 2; nt++) {
            int j = w * 32 + nt * 16 + col;
#pragma unroll
            for (int i = 0; i < 4; i++) {
                int b = quad * 4 + i;
                float gr = acc[0][nt][i] + (float)gi_lds[b * 768 + j]       + brz[0][nt];
                float gz = acc[1][nt][i] + (float)gi_lds[b * 768 + 256 + j] + brz[1][nt];
                float gn = (float)gi_lds[b * 768 + 512 + j] + bin_[nt];
                float r = sigm(gr), z = sigm(gz);
                float n = tanh_(gn + r * (acc[2][nt][i] + bhn[nt]));
                float hv = (1.0f - z) * n + z * hold[nt][i];
                hold[nt][i] = hv;
                hnext[b * 264 + j] = (bf16_t)hv;
                if (y) y[((size_t)tp * B_ + b0 + b) * DH_ + dir * H_ + j] = (bf16_t)hv;
                if (t == T_ - 1) hT[(size_t)(b0 + b) * DH_ + dir * H_ + j] = hv;
            }
        }
        __syncthreads();
#pragma unroll
        for (int it = 0; it < 3; it++)
            *(bf16x8*)(&gi_lds[(it * 512 + tid) * 8]) = pg[it];
        __syncthreads();
    }
#pragma unroll
    for (int nt = 0; nt < 2; nt++)
#pragma unroll
        for (int i = 0; i < 4; i++) {
            int j = w * 32 + nt * 16 + col;
            hstate[dir * 65536 + (b0 + quad * 4 + i) * 256 + j] = hold[nt][i];
        }
}

// --------------------------- batch-local decoder ---------------------------
// 16 WGs x 512 thr; WG owns batch rows [wg*16, wg*16+16) and computes the
// FULL 512-j state for both cells each step. h0/h1 in LDS (swizzled bf16),
// f32 carries in registers. No inter-WG communication of any kind.
// Wave w owns j in [w*64, w*64+64) as 4 nt-subtiles of 16.

__device__ __forceinline__ bf16x8 fragrd(const bf16_t* lds, int kt, int col, int quad) {
    int byte = (col * 1024 + kt * 64 + quad * 16) ^ ((col & 7) << 4);
    return *(const bf16x8*)((const char*)lds + byte);
}

__global__ __launch_bounds__(512) void dec_batch(
    const bf16_t* __restrict__ weff, const float* __restrict__ beff,
    const float* __restrict__ ov,
    const bf16_t* __restrict__ wdhh0, const float* __restrict__ dbhh0,
    const bf16_t* __restrict__ wdih1, const float* __restrict__ dbih1,
    const bf16_t* __restrict__ wdhh1, const float* __restrict__ dbhh1,
    const float* __restrict__ h0init, const float* __restrict__ h1init,
    float* __restrict__ hist) {
    __shared__ bf16_t sh0[16 * 512];   // h0 (current), swizzled
    __shared__ bf16_t sh1[16 * 512];   // h1 (current), swizzled
    int b0 = blockIdx.x * 16;
    int tid = threadIdx.x, w = tid >> 6, lane = tid & 63;
    int col = lane & 15, quad = lane >> 4;

    // per-nt j and folded biases
    int jj[4];
    float c0r[4], c0z[4], c0in[4], c0hn[4];   // cell0 t>0
    float t0r[4], t0z[4], t0in[4];            // cell0 t==0 (ov-based)
    float c1r[4], c1z[4], c1in[4], c1hn[4];   // cell1
#pragma unroll
    for (int nt = 0; nt < 4; ++nt) {
        int j = w * 64 + nt * 16 + col;
        jj[nt] = j;
        c0r[nt]  = beff[j] + dbhh0[j];
        c0z[nt]  = beff[DH_ + j] + dbhh0[DH_ + j];
        c0in[nt] = beff[2 * DH_ + j];
        c0hn[nt] = dbhh0[2 * DH_ + j];
        t0r[nt]  = ov[j] + dbhh0[j];
        t0z[nt]  = ov[DH_ + j] + dbhh0[DH_ + j];
        t0in[nt] = ov[2 * DH_ + j];
        c1r[nt]  = dbih1[j] + dbhh1[j];
        c1z[nt]  = dbih1[DH_ + j] + dbhh1[DH_ + j];
        c1in[nt] = dbih1[2 * DH_ + j];
        c1hn[nt] = dbhh1[2 * DH_ + j];
    }
    // f32 carries: lane owns (b = b0+quad*4+i, j = jj[nt])
    float hold0[4][4], hold1[4][4];
#pragma unroll
    for (int nt = 0; nt < 4; ++nt)
#pragma unroll
        for (int i = 0; i < 4; ++i) {
            int b = b0 + quad * 4 + i;
            hold0[nt][i] = h0init[(size_t)b * DH_ + jj[nt]];
            hold1[nt][i] = h1init[(size_t)b * DH_ + jj[nt]];
        }
    // stage initial h into swizzled LDS
    for (int idx = tid; idx < 16 * DH_; idx += 512) {
        int row = idx >> 9, c = idx & 511;
        int byte = (row * 1024 + c * 2) ^ ((row & 7) << 4);
        *(bf16_t*)((char*)sh0 + byte) = (bf16_t)h0init[(size_t)(b0 + row) * DH_ + c];
        *(bf16_t*)((char*)sh1 + byte) = (bf16_t)h1init[(size_t)(b0 + row) * DH_ + c];
    }
    __syncthreads();

    for (int t = 0; t < OSL_; ++t) {
        bool dox0 = (t > 0);
        // ---------------- cell0: h0' = GRU(x=fc(h1), h0) ----------------
        f32x4 aR[4] = {}, aZ[4] = {}, aIN[4] = {}, aHN[4] = {};
#pragma unroll 2
        for (int kt = 0; kt < 16; ++kt) {
            bf16x8 ah = fragrd(sh0, kt, col, quad);   // h0(t-1)
            bf16x8 ax = fragrd(sh1, kt, col, quad);   // h1(t-1)
            const bf16_t* whb = wdhh0 + (size_t)kt * 32 + quad * 8;
            const bf16_t* wxb = weff  + (size_t)kt * 32 + quad * 8;
#pragma unroll
            for (int nt = 0; nt < 4; ++nt) {
                size_t j = (size_t)jj[nt];
                aR[nt]  = __builtin_amdgcn_mfma_f32_16x16x32_bf16(ah, *(const bf16x8*)(whb + j * DH_), aR[nt], 0, 0, 0);
                aZ[nt]  = __builtin_amdgcn_mfma_f32_16x16x32_bf16(ah, *(const bf16x8*)(whb + (DH_ + j) * DH_), aZ[nt], 0, 0, 0);
                aHN[nt] = __builtin_amdgcn_mfma_f32_16x16x32_bf16(ah, *(const bf16x8*)(whb + (2 * DH_ + j) * DH_), aHN[nt], 0, 0, 0);
                if (dox0) {
                    aR[nt]  = __builtin_amdgcn_mfma_f32_16x16x32_bf16(ax, *(const bf16x8*)(wxb + j * DH_), aR[nt], 0, 0, 0);
                    aZ[nt]  = __builtin_amdgcn_mfma_f32_16x16x32_bf16(ax, *(const bf16x8*)(wxb + (DH_ + j) * DH_), aZ[nt], 0, 0, 0);
                    aIN[nt] = __builtin_amdgcn_mfma_f32_16x16x32_bf16(ax, *(const bf16x8*)(wxb + (2 * DH_ + j) * DH_), aIN[nt], 0, 0, 0);
                }
            }
        }
        float h0new[4][4];
#pragma unroll
        for (int nt = 0; nt < 4; ++nt)
#pragma unroll
            for (int i = 0; i < 4; ++i) {
                float r = sigm(aR[nt][i] + (dox0 ? c0r[nt] : t0r[nt]));
                float z = sigm(aZ[nt][i] + (dox0 ? c0z[nt] : t0z[nt]));
                float gin = dox0 ? (aIN[nt][i] + c0in[nt]) : t0in[nt];
                float n = tanh_(gin + r * (aHN[nt][i] + c0hn[nt]));
                float hv = (1.0f - z) * n + z * hold0[nt][i];
                hold0[nt][i] = hv;
                h0new[nt][i] = hv;
            }
        __syncthreads();   // all sh0 reads complete
#pragma unroll
        for (int nt = 0; nt < 4; ++nt)
#pragma unroll
            for (int i = 0; i < 4; ++i) {
                int row = quad * 4 + i;
                int byte = (row * 1024 + jj[nt] * 2) ^ ((row & 7) << 4);
                *(bf16_t*)((char*)sh0 + byte) = (bf16_t)h0new[nt][i];
            }
        __syncthreads();   // sh0 = h0(t)

        // ---------------- cell1: h1' = GRU(x=h0(t), h1) -----------------
        f32x4 bR[4] = {}, bZ[4] = {}, bIN[4] = {}, bHN[4] = {};
#pragma unroll 2
        for (int kt = 0; kt < 16; ++kt) {
            bf16x8 a0 = fragrd(sh0, kt, col, quad);   // h0(t)
            bf16x8 a1 = fragrd(sh1, kt, col, quad);   // h1(t-1)
            const bf16_t* wxb = wdih1 + (size_t)kt * 32 + quad * 8;
            const bf16_t* whb = wdhh1 + (size_t)kt * 32 + quad * 8;
#pragma unroll
            for (int nt = 0; nt < 4; ++nt) {
                size_t j = (size_t)jj[nt];
                bR[nt]  = __builtin_amdgcn_mfma_f32_16x16x32_bf16(a0, *(const bf16x8*)(wxb + j * DH_), bR[nt], 0, 0, 0);
                bZ[nt]  = __builtin_amdgcn_mfma_f32_16x16x32_bf16(a0, *(const bf16x8*)(wxb + (DH_ + j) * DH_), bZ[nt], 0, 0, 0);
                bIN[nt] = __builtin_amdgcn_mfma_f32_16x16x32_bf16(a0, *(const bf16x8*)(wxb + (2 * DH_ + j) * DH_), bIN[nt], 0, 0, 0);
                bR[nt]  = __builtin_amdgcn_mfma_f32_16x16x32_bf16(a1, *(const bf16x8*)(whb + j * DH_), bR[nt], 0, 0, 0);
                bZ[nt]  = __builtin_amdgcn_mfma_f32_16x16x32_bf16(a1, *(const bf16x8*)(whb + (DH_ + j) * DH_), bZ[nt], 0, 0, 0);
                bHN[nt] = __builtin_amdgcn_mfma_f32_16x16x32_bf16(a1, *(const bf16x8*)(whb + (2 * DH_ + j) * DH_), bHN[nt], 0, 0, 0);
            }
        }
        float* hist_t = hist + (size_t)t * B_ * DH_;
        float h1new[4][4];
#pragma unroll
        for (int nt = 0; nt < 4; ++nt)
#pragma unroll
            for (int i = 0; i < 4; ++i) {
                int b = b0 + quad * 4 + i;
                float r = sigm(bR[nt][i] + c1r[nt]);
                float z = sigm(bZ[nt][i] + c1z[nt]);
                float n = tanh_(bIN[nt][i] + c1in[nt] + r * (bHN[nt][i] + c1hn[nt]));
                float hv = (1.0f - z) * n + z * hold1[nt][i];
                hold1[nt][i] = hv;
                h1new[nt][i] = hv;
                hist_t[(size_t)b * DH_ + jj[nt]] = hv;
            }
        __syncthreads();   // all sh1 reads complete
#pragma unroll
        for (int nt = 0; nt < 4; ++nt)
#pragma unroll
            for (int i = 0; i < 4; ++i) {
                int row = quad * 4 + i;
                int byte = (row * 1024 + jj[nt] * 2) ^ ((row & 7) << 4);
                *(bf16_t*)((char*)sh1 + byte) = (bf16_t)h1new[nt][i];
            }
        __syncthreads();   // sh1 = h1(t)
    }
}

// ------------------------------- FC head -----------------------------------
__global__ __launch_bounds__(256) void fc_all(
    const float* __restrict__ hist, const float* __restrict__ fcw,
    const float* __restrict__ fcb, float* __restrict__ out) {
    int t  = blockIdx.x >> 4;
    int b0 = (blockIdx.x & 15) * 16;
    int tid = threadIdx.x;
    int bl = tid >> 4, o = (tid >> 3) & 1, part = tid & 7;
    const float* hp = hist + ((size_t)t * B_ + b0 + bl) * DH_;
    const float* wp = fcw + o * DH_;
    float s = 0.0f;
    for (int k = part * 64; k < part * 64 + 64; k += 4) {
        f32x4 hv = *(const f32x4*)(hp + k);
        f32x4 wv = *(const f32x4*)(wp + k);
        s += hv[0] * wv[0] + hv[1] * wv[1] + hv[2] * wv[2] + hv[3] * wv[3];
    }
    s += __shfl_down(s, 4); s += __shfl_down(s, 2); s += __shfl_down(s, 1);
    if (part == 0) out[(size_t)(b0 + bl) * (OSL_ * 2) + t * 2 + o] = s + fcb[o];
}

// ------------------------------ launcher -----------------------------------

#define OFF_WIH0E 0ull
#define OFF_WHH0E 196608ull
#define OFF_WIH1E 983040ull
#define OFF_WHH1E 2555904ull
#define OFF_WDHH0 3342336ull
#define OFF_WDIH1 4915200ull
#define OFF_WDHH1 6488064ull
#define OFF_WEFF  8060928ull
#define OFF_BEFF  9633792ull
#define OFF_OV    9658368ull
#define OFF_H0A   9682944ull
#define OFF_H1A   10731520ull
#define OFF_HST   11780096ull
#define OFF_HIST  12304384ull
#define OFF_XCAT  22790144ull
#define OFF_GI    157007872ull

extern "C" void kernel_launch(void* const* d_in, const int* in_sizes, int n_in,
                              void* d_out, int out_size, void* d_ws, size_t ws_size,
                              hipStream_t stream) {
    const float* x      = (const float*)d_in[0];
    const float* st     = (const float*)d_in[1];
    const float* eWih0  = (const float*)d_in[2];
    const float* eWhh0  = (const float*)d_in[3];
    const float* ebih0  = (const float*)d_in[4];
    const float* ebhh0  = (const float*)d_in[5];
    const float* eWih1  = (const float*)d_in[6];
    const float* eWhh1  = (const float*)d_in[7];
    const float* ebih1  = (const float*)d_in[8];
    const float* ebhh1  = (const float*)d_in[9];
    const float* dWih0  = (const float*)d_in[10];
    const float* dWhh0  = (const float*)d_in[11];
    const float* dbih0  = (const float*)d_in[12];
    const float* dbhh0  = (const float*)d_in[13];
    const float* dWih1  = (const float*)d_in[14];
    const float* dWhh1  = (const float*)d_in[15];
    const float* dbih1  = (const float*)d_in[16];
    const float* dbhh1  = (const float*)d_in[17];
    const float* fcW    = (const float*)d_in[18];
    const float* fcb    = (const float*)d_in[19];

    char* ws = (char*)d_ws;
    bf16_t* wih0e = (bf16_t*)(ws + OFF_WIH0E);
    bf16_t* whh0e = (bf16_t*)(ws + OFF_WHH0E);
    bf16_t* wih1e = (bf16_t*)(ws + OFF_WIH1E);
    bf16_t* whh1e = (bf16_t*)(ws + OFF_WHH1E);
    bf16_t* wdhh0 = (bf16_t*)(ws + OFF_WDHH0);
    bf16_t* wdih1 = (bf16_t*)(ws + OFF_WDIH1);
    bf16_t* wdhh1 = (bf16_t*)(ws + OFF_WDHH1);
    bf16_t* weff  = (bf16_t*)(ws + OFF_WEFF);
    float*  beff  = (float*)(ws + OFF_BEFF);
    float*  ovp   = (float*)(ws + OFF_OV);
    float*  h0init = (float*)(ws + OFF_H0A);
    float*  h1init = (float*)(ws + OFF_H1A);
    float*  hstate = (float*)(ws + OFF_HST);
    float*  hist  = (float*)(ws + OFF_HIST);
    bf16_t* xcat  = (bf16_t*)(ws + OFF_XCAT);
    bf16_t* gi    = (bf16_t*)(ws + OFF_GI);

    int Tc = 512;
    while (Tc > 8 && OFF_GI + (unsigned long long)Tc * 786432ull > (unsigned long long)ws_size)
        Tc >>= 1;
    int nch = T_ / Tc;

    prep_all<<<dim3(3072, 8), 256, 0, stream>>>(
        eWih0, eWhh0, eWih1, eWhh1, dWhh0, dWih1, dWhh1,
        wih0e, whh0e, wih1e, whh1e, wdhh0, wdih1, wdhh1,
        dWih0, fcW, fcb, dbih0, st, weff, beff, ovp);

    for (int c = 0; c < nch; c++) {
        gemm_gi<<<dim3(Tc * 2, 12), 256, 0, stream>>>(x, nullptr, wih0e, gi, c * Tc, 64);
        gru_scan<<<32, 512, 0, stream>>>(gi, c * Tc, Tc, whh0e, ebih0, ebhh0, hstate, xcat, h0init);
    }
    for (int c = 0; c < nch; c++) {
        gemm_gi<<<dim3(Tc * 2, 12), 256, 0, stream>>>(nullptr, xcat, wih1e, gi, c * Tc, 512);
        gru_scan<<<32, 512, 0, stream>>>(gi, c * Tc, Tc, whh1e, ebih1, ebhh1, hstate, nullptr, h1init);
    }

    dec_batch<<<16, 512, 0, stream>>>(weff, beff, ovp,
                                      wdhh0, dbhh0, wdih1, dbih1, wdhh1, dbhh1,
                                      h0init, h1init, hist);

    fc_all<<<OSL_ * 16, 256, 0, stream>>>(hist, fcW, fcb, (float*)d_out);
}

// Round 7
// 4769.928 us; speedup vs baseline: 1.6550x; 1.6550x over previous
//
#include <hip/hip_runtime.h>
#include <hip/hip_bf16.h>
#include <stdint.h>
#include <stddef.h>

// ---------------------------------------------------------------------------
// Seq2Seq BiGRU: B=256 T=512 F=64 H=256 (2-layer bidir encoder),
// decoder DH=512 2-layer, OSL=20, OUT=2.
//
// Round-9 structure:
//  - prep_all / gemm_gi (m-major) / gru_scan / fc_all: r3-proven versions.
//  - dec_persist v3: j-sliced 128-WG persistent decoder (r3 structure), but
//    the h exchange now stays in the XCD-local L2:
//      * grp = blockIdx&15 -> the 8 partner WGs of a group share blockIdx%8
//        -> same XCD (mapping empirically confirmed in r4: FETCH 308->88MB).
//      * publish: plain u32 stores (write-through L1->L2).
//      * stage: inline-asm global_load_dwordx4 sc0 (L1-bypass, 16B) reads
//        the shared L2 (was: 8B coherence-point atomics ~900cyc each -> the
//        20us/phase toll identified in r3-r5).
//      * stage-reuse: h0 stays in LDS across phase B->A, h1 across A->B ->
//        ONE 16KB stage per phase (r3 had two).
//      * barrier: unchanged device-scope RMW + bounded spin (never hangs;
//        if the XCD mapping assumption breaks -> visible absmax failure).
// ---------------------------------------------------------------------------

typedef __bf16 bf16_t;
typedef bf16_t bf16x8 __attribute__((ext_vector_type(8)));
typedef float  f32x4  __attribute__((ext_vector_type(4)));

#define B_   256
#define T_   512
#define F_   64
#define H_   256
#define G_   768      // 3*H
#define DH_  512
#define DG_  1536     // 3*DH
#define OSL_ 20

__device__ __forceinline__ float sigm(float x) {
    float e = __builtin_amdgcn_exp2f(-1.442695040888963f * x);
    return __builtin_amdgcn_rcpf(1.0f + e);
}
__device__ __forceinline__ float tanh_(float x) {
    float e = __builtin_amdgcn_exp2f(-2.885390081777927f * x);
    return __builtin_amdgcn_rcpf(1.0f + e) * 2.0f - 1.0f;
}

__device__ __forceinline__ bf16x8 load_f32x8_as_bf16(const float* p) {
    f32x4 u = *(const f32x4*)p;
    f32x4 v = *(const f32x4*)(p + 4);
    bf16x8 r;
    r[0]=(bf16_t)u[0]; r[1]=(bf16_t)u[1]; r[2]=(bf16_t)u[2]; r[3]=(bf16_t)u[3];
    r[4]=(bf16_t)v[0]; r[5]=(bf16_t)v[1]; r[6]=(bf16_t)v[2]; r[7]=(bf16_t)v[3];
    return r;
}

// ------------------------------- fused prep --------------------------------
__global__ __launch_bounds__(256) void prep_all(
    const float* __restrict__ s0, const float* __restrict__ s1,
    const float* __restrict__ s2, const float* __restrict__ s3,
    const float* __restrict__ s4, const float* __restrict__ s5,
    const float* __restrict__ s6,
    bf16_t* __restrict__ d0, bf16_t* __restrict__ d1, bf16_t* __restrict__ d2,
    bf16_t* __restrict__ d3, bf16_t* __restrict__ d4, bf16_t* __restrict__ d5,
    bf16_t* __restrict__ d6,
    const float* __restrict__ wih0d, const float* __restrict__ fcw,
    const float* __restrict__ fcb, const float* __restrict__ bih0d,
    const float* __restrict__ st, bf16_t* __restrict__ weff,
    float* __restrict__ beff, float* __restrict__ ov,
    unsigned int* __restrict__ bar) {
    int i = blockIdx.x * 256 + threadIdx.x;
    switch (blockIdx.y) {
      case 0: if (i < 2*G_*F_)  d0[i] = (bf16_t)s0[i]; break;
      case 1: if (i < 2*G_*H_)  d1[i] = (bf16_t)s1[i]; break;
      case 2: if (i < 2*G_*DH_) d2[i] = (bf16_t)s2[i]; break;
      case 3: if (i < 2*G_*H_)  d3[i] = (bf16_t)s3[i]; break;
      case 4: if (i < DG_*DH_)  d4[i] = (bf16_t)s4[i]; break;
      case 5: if (i < DG_*DH_)  d5[i] = (bf16_t)s5[i]; break;
      case 6: if (i < DG_*DH_)  d6[i] = (bf16_t)s6[i]; break;
      default: {
        if (i < 1024) bar[i] = 0u;
        if (i < DG_*DH_) {
          int g = i >> 9, k = i & 511;
          float a0 = wih0d[g * 2], a1 = wih0d[g * 2 + 1];
          weff[i] = (bf16_t)(a0 * fcw[k] + a1 * fcw[DH_ + k]);
          if (k == 0) {
            beff[g] = a0 * fcb[0] + a1 * fcb[1] + bih0d[g];
            ov[g]   = a0 * st[0]  + a1 * st[1]  + bih0d[g];
          }
        }
      } break;
    }
}

// --------------------------- gi chunk GEMM ---------------------------------
__global__ __launch_bounds__(256) void gemm_gi(
    const float* __restrict__ x, const bf16_t* __restrict__ xcat,
    const bf16_t* __restrict__ Bt, bf16_t* __restrict__ gi, int t0, int K) {
    __shared__ bf16_t As[128 * 64];
    __shared__ bf16_t Bs[128 * 64];
    int m0 = blockIdx.x * 128, n0 = blockIdx.y * 128;
    int tid = threadIdx.x;
    int lane = tid & 63, w = tid >> 6;
    int col = lane & 15, quad = lane >> 4;
    int qm = (w >> 1) * 64, qn = (w & 1) * 64;

    int tl = m0 >> 8;              // local chunk time (constant per block)
    int bbase = m0 & 255;          // batch base (0 or 128)
    int t_real = t0 + tl;
    if (n0 >= 768) t_real = (T_ - 1) - t_real;

    f32x4 acc[4][4] = {};
    for (int k0 = 0; k0 < K; k0 += 64) {
        __syncthreads();
#pragma unroll
        for (int i = 0; i < 4; i++) {
            int c = i * 256 + tid;
            int m = c >> 3, kc = c & 7;
            int kcs = kc ^ (m & 7);   // XOR swizzle at source
            bf16x8 av;
            if (K == 64) {
                av = load_f32x8_as_bf16(x + ((size_t)(bbase + m) * T_ + t_real) * F_ + kcs * 8);
            } else {
                av = *(const bf16x8*)(xcat + ((size_t)t_real * B_ + bbase + m) * DH_ + k0 + kcs * 8);
            }
            *(bf16x8*)(&As[c * 8]) = av;
            *(bf16x8*)(&Bs[c * 8]) = *(const bf16x8*)(Bt + (size_t)(n0 + m) * K + k0 + kcs * 8);
        }
        __syncthreads();
#pragma unroll
        for (int kt = 0; kt < 2; kt++) {
            bf16x8 a[4], b[4];
#pragma unroll
            for (int mt = 0; mt < 4; mt++) {
                int r = qm + mt * 16 + col;
                a[mt] = *(const bf16x8*)(&As[(r * 8 + ((kt * 4 + quad) ^ (r & 7))) * 8]);
                int rn = qn + mt * 16 + col;
                b[mt] = *(const bf16x8*)(&Bs[(rn * 8 + ((kt * 4 + quad) ^ (rn & 7))) * 8]);
            }
#pragma unroll
            for (int mt = 0; mt < 4; mt++)
#pragma unroll
                for (int nt = 0; nt < 4; nt++)
                    acc[mt][nt] = __builtin_amdgcn_mfma_f32_16x16x32_bf16(a[mt], b[nt], acc[mt][nt], 0, 0, 0);
        }
    }
#pragma unroll
    for (int mt = 0; mt < 4; mt++)
#pragma unroll
        for (int nt = 0; nt < 4; nt++)
#pragma unroll
            for (int i = 0; i < 4; i++) {
                int row = m0 + qm + mt * 16 + quad * 4 + i;
                int cg  = n0 + qn + nt * 16 + col;
                gi[(size_t)row * DG_ + cg] = (bf16_t)acc[mt][nt][i];
            }
}

// ------------------------------ GRU scan (chunked) -------------------------
__global__ __launch_bounds__(512) void gru_scan(
    const bf16_t* __restrict__ gi, int t0, int tc,
    const bf16_t* __restrict__ whh,
    const float* __restrict__ bih, const float* __restrict__ bhh,
    float* __restrict__ hstate, bf16_t* __restrict__ y, float* __restrict__ hT) {
    __shared__ bf16_t gi_lds[16 * 768];       // [b][768]
    __shared__ bf16_t h_lds[2 * 16 * 264];    // [par][b][256+8 pad]

    int dir = blockIdx.x >> 4;
    int b0  = (blockIdx.x & 15) * 16;
    int tid = threadIdx.x;
    int w = tid >> 6, lane = tid & 63, col = lane & 15, quad = lane >> 4;

    bf16x8 wf[3][2][8];
    const bf16_t* wbase = whh + (size_t)dir * G_ * H_;
#pragma unroll
    for (int g = 0; g < 3; g++)
#pragma unroll
        for (int nt = 0; nt < 2; nt++) {
            int row = g * 256 + w * 32 + nt * 16 + col;
#pragma unroll
            for (int kt = 0; kt < 8; kt++)
                wf[g][nt][kt] = *(const bf16x8*)(wbase + (size_t)row * H_ + kt * 32 + quad * 8);
        }
    float brz[2][2], bin_[2], bhn[2];
#pragma unroll
    for (int nt = 0; nt < 2; nt++) {
        int j = w * 32 + nt * 16 + col;
        brz[0][nt] = bih[dir * G_ + j] + bhh[dir * G_ + j];
        brz[1][nt] = bih[dir * G_ + 256 + j] + bhh[dir * G_ + 256 + j];
        bin_[nt]   = bih[dir * G_ + 512 + j];
        bhn[nt]    = bhh[dir * G_ + 512 + j];
    }
    int bb[3], oo[3];
#pragma unroll
    for (int it = 0; it < 3; it++) {
        int c = it * 512 + tid;
        bb[it] = c / 96;
        oo[it] = (c % 96) * 8;
    }
    float hold[2][4];
#pragma unroll
    for (int nt = 0; nt < 2; nt++)
#pragma unroll
        for (int i = 0; i < 4; i++) {
            int j = w * 32 + nt * 16 + col;
            hold[nt][i] = t0 ? hstate[dir * 65536 + (b0 + quad * 4 + i) * 256 + j] : 0.0f;
        }
    for (int i = tid; i < 16 * 264; i += 512) {
        int b = i / 264, j = i % 264;
        float v = (t0 && j < 256) ? hstate[dir * 65536 + (b0 + b) * 256 + j] : 0.0f;
        h_lds[i] = (bf16_t)v;
    }
#pragma unroll
    for (int it = 0; it < 3; it++) {
        int c = it * 512 + tid;
        *(bf16x8*)(&gi_lds[c * 8]) =
            *(const bf16x8*)(gi + ((size_t)0 * B_ + b0 + bb[it]) * DG_ + dir * G_ + oo[it]);
    }
    __syncthreads();

    for (int s = 0; s < tc; s++) {
        int par = s & 1;
        int t = t0 + s;
        int sn = (s + 1 < tc) ? (s + 1) : s;

        bf16x8 pg[3];
#pragma unroll
        for (int it = 0; it < 3; it++)
            pg[it] = *(const bf16x8*)(gi + ((size_t)sn * B_ + b0 + bb[it]) * DG_ + dir * G_ + oo[it]);

        f32x4 acc[3][2] = {};
        const bf16_t* hcur = &h_lds[par * 4224];
#pragma unroll
        for (int kt = 0; kt < 8; kt++) {
            bf16x8 af = *(const bf16x8*)(hcur + col * 264 + kt * 32 + quad * 8);
#pragma unroll
            for (int g = 0; g < 3; g++)
#pragma unroll
                for (int nt = 0; nt < 2; nt++)
                    acc[g][nt] = __builtin_amdgcn_mfma_f32_16x16x32_bf16(af, wf[g][nt][kt], acc[g][nt], 0, 0, 0);
        }

        bf16_t* hnext = &h_lds[(par ^ 1) * 4224];
        int tp = dir ? (T_ - 1 - t) : t;
#pragma unroll
        for (int nt = 0; nt < 2; nt++) {
            int j = w * 32 + nt * 16 + col;
#pragma unroll
            for (int i = 0; i < 4; i++) {
                int b = quad * 4 + i;
                float gr = acc[0][nt][i] + (float)gi_lds[b * 768 + j]       + brz[0][nt];
                float gz = acc[1][nt][i] + (float)gi_lds[b * 768 + 256 + j] + brz[1][nt];
                float gn = (float)gi_lds[b * 768 + 512 + j] + bin_[nt];
                float r = sigm(gr), z = sigm(gz);
                float n = tanh_(gn + r * (acc[2][nt][i] + bhn[nt]));
                float hv = (1.0f - z) * n + z * hold[nt][i];
                hold[nt][i] = hv;
                hnext[b * 264 + j] = (bf16_t)hv;
                if (y) y[((size_t)tp * B_ + b0 + b) * DH_ + dir * H_ + j] = (bf16_t)hv;
                if (t == T_ - 1) hT[(size_t)(b0 + b) * DH_ + dir * H_ + j] = hv;
            }
        }
        __syncthreads();
#pragma unroll
        for (int it = 0; it < 3; it++)
            *(bf16x8*)(&gi_lds[(it * 512 + tid) * 8]) = pg[it];
        __syncthreads();
    }
#pragma unroll
    for (int nt = 0; nt < 2; nt++)
#pragma unroll
        for (int i = 0; i < 4; i++) {
            int j = w * 32 + nt * 16 + col;
            hstate[dir * 65536 + (b0 + quad * 4 + i) * 256 + j] = hold[nt][i];
        }
}

// ------------------------- persistent fused decoder ------------------------
// 128 WGs = 16 batch-groups (grp = blockIdx&15) x 8 j-blocks (blockIdx>>4).
// Partner WGs of a group differ by 16 in blockIdx -> SAME XCD (%8) -> the h
// exchange lives in the XCD-local L2: plain stores (write-through L1->L2),
// sc0 (L1-bypass) 16B loads. Barrier = device-scope RMW, bounded spin.

__device__ __forceinline__ void gbar(unsigned int* cnt) {
    __syncthreads();   // drains vmcnt -> publishes in L2 before arrival
    if (threadIdx.x == 0) {
        __hip_atomic_fetch_add(cnt, 1u, __ATOMIC_RELEASE, __HIP_MEMORY_SCOPE_AGENT);
        unsigned int s = 0;
        while (__hip_atomic_load(cnt, __ATOMIC_RELAXED, __HIP_MEMORY_SCOPE_AGENT) < 8u
               && ++s < (1u << 20))
            __builtin_amdgcn_s_sleep(1);
    }
    __syncthreads();
}

// stage 16 rows x 512 bf16 (16 KB) from XCD-local L2 into XOR-swizzled LDS.
// sc0 = bypass L1, read shared L2 (partners are intra-XCD).
__device__ __forceinline__ void stage16_l2(bf16_t* lds, const bf16_t* src) {
    f32x4 v0, v1, v2, v3;
    const char* s = (const char*)src;
    const char* a0 = s + threadIdx.x * 16;
    asm volatile(
        "global_load_dwordx4 %0, %4, off sc0\n\t"
        "global_load_dwordx4 %1, %5, off sc0\n\t"
        "global_load_dwordx4 %2, %6, off sc0\n\t"
        "global_load_dwordx4 %3, %7, off sc0\n\t"
        "s_waitcnt vmcnt(0)"
        : "=&v"(v0), "=&v"(v1), "=&v"(v2), "=&v"(v3)
        : "v"(a0), "v"(a0 + 4096), "v"(a0 + 8192), "v"(a0 + 12288)
        : "memory");
    f32x4 vv[4] = { v0, v1, v2, v3 };
#pragma unroll
    for (int i2 = 0; i2 < 4; ++i2) {
        int off = i2 * 4096 + threadIdx.x * 16;
        int row = off >> 10;
        int swz = off ^ ((row & 7) << 4);
        *(f32x4*)((char*)lds + swz) = vv[i2];
    }
}

__device__ __forceinline__ bf16x8 fragrd(const bf16_t* lds, int kt, int col, int quad) {
    int byte = (col * 1024 + kt * 64 + quad * 16) ^ ((col & 7) << 4);
    return *(const bf16x8*)((const char*)lds + byte);
}

// publish hv as bf16 into packed u32 pairs (even-col lanes store j, j+1);
// plain store -> write-through to the XCD-local L2.
__device__ __forceinline__ void publish(bf16_t* dst, int b, int j, float hv, int col) {
    bf16_t hb = (bf16_t)hv;
    unsigned short mb;
    __builtin_memcpy(&mb, &hb, 2);
    unsigned int pv = (unsigned int)__shfl_xor((int)(unsigned int)mb, 1);
    if ((col & 1) == 0) {
        unsigned int word = (unsigned int)mb | (pv << 16);
        *(unsigned int*)((char*)dst + (size_t)(b * DH_ + j) * 2) = word;
    }
}

__device__ __forceinline__ void cell_step(
    const bf16_t* sh, const bf16_t* sx, bool dox,
    const bf16_t* __restrict__ Wx, const bf16_t* __restrict__ Wh,
    int j, int col, int quad, int grp,
    float br, float bz, float bin_, float bhn,
    float hold[4], bf16_t* hout, float* hist_t) {
    f32x4 aR = {}, aZ = {}, aIN = {}, aHN = {};
#pragma unroll
    for (int kt = 0; kt < 16; ++kt) {
        bf16x8 ah = fragrd(sh, kt, col, quad);
        bf16x8 w0 = *(const bf16x8*)(Wh + (size_t)j * DH_ + kt * 32 + quad * 8);
        bf16x8 w1 = *(const bf16x8*)(Wh + (size_t)(DH_ + j) * DH_ + kt * 32 + quad * 8);
        bf16x8 w2 = *(const bf16x8*)(Wh + (size_t)(2 * DH_ + j) * DH_ + kt * 32 + quad * 8);
        aR  = __builtin_amdgcn_mfma_f32_16x16x32_bf16(ah, w0, aR, 0, 0, 0);
        aZ  = __builtin_amdgcn_mfma_f32_16x16x32_bf16(ah, w1, aZ, 0, 0, 0);
        aHN = __builtin_amdgcn_mfma_f32_16x16x32_bf16(ah, w2, aHN, 0, 0, 0);
        if (dox) {
            bf16x8 ax = fragrd(sx, kt, col, quad);
            bf16x8 x0 = *(const bf16x8*)(Wx + (size_t)j * DH_ + kt * 32 + quad * 8);
            bf16x8 x1 = *(const bf16x8*)(Wx + (size_t)(DH_ + j) * DH_ + kt * 32 + quad * 8);
            bf16x8 x2 = *(const bf16x8*)(Wx + (size_t)(2 * DH_ + j) * DH_ + kt * 32 + quad * 8);
            aR  = __builtin_amdgcn_mfma_f32_16x16x32_bf16(ax, x0, aR, 0, 0, 0);
            aZ  = __builtin_amdgcn_mfma_f32_16x16x32_bf16(ax, x1, aZ, 0, 0, 0);
            aIN = __builtin_amdgcn_mfma_f32_16x16x32_bf16(ax, x2, aIN, 0, 0, 0);
        }
    }
#pragma unroll
    for (int i = 0; i < 4; ++i) {
        int b = grp * 16 + quad * 4 + i;
        float r = sigm(aR[i] + br);
        float z = sigm(aZ[i] + bz);
        float n = tanh_(aIN[i] + bin_ + r * (aHN[i] + bhn));
        float hv = (1.0f - z) * n + z * hold[i];
        hold[i] = hv;
        if (hist_t) hist_t[(size_t)b * DH_ + j] = hv;
        publish(hout, b, j, hv, col);
    }
}

__global__ __launch_bounds__(256) void dec_persist(
    const bf16_t* __restrict__ weff, const float* __restrict__ beff,
    const float* __restrict__ ov,
    const bf16_t* __restrict__ wdhh0, const float* __restrict__ dbhh0,
    const bf16_t* __restrict__ wdih1, const float* __restrict__ dbih1,
    const bf16_t* __restrict__ wdhh1, const float* __restrict__ dbhh1,
    const float* __restrict__ h0init, const float* __restrict__ h1init,
    bf16_t* hx00, bf16_t* hx01, bf16_t* hx10, bf16_t* hx11,
    float* __restrict__ hist, unsigned int* __restrict__ bar) {
    __shared__ bf16_t sh[16 * 512];   // holds h0 across phases
    __shared__ bf16_t sx[16 * 512];   // holds h1 across phases
    int grp = blockIdx.x & 15;        // partners 16 apart -> same XCD (%8)
    int jblk = blockIdx.x >> 4;
    int tid = threadIdx.x, w = tid >> 6, lane = tid & 63;
    int col = lane & 15, quad = lane >> 4;
    int j = jblk * 64 + w * 16 + col;

    // per-lane folded biases
    float b0r = beff[j] + dbhh0[j],           b0z = beff[DH_ + j] + dbhh0[DH_ + j];
    float b0in = beff[2 * DH_ + j],           b0hn = dbhh0[2 * DH_ + j];
    float o0r = ov[j] + dbhh0[j],             o0z = ov[DH_ + j] + dbhh0[DH_ + j];
    float o0in = ov[2 * DH_ + j];
    float b1r = dbih1[j] + dbhh1[j],          b1z = dbih1[DH_ + j] + dbhh1[DH_ + j];
    float b1in = dbih1[2 * DH_ + j],          b1hn = dbhh1[2 * DH_ + j];

    // fp32 carries in registers; publish initial bf16 state to parity-1 bufs
    float hold0[4], hold1[4];
#pragma unroll
    for (int i = 0; i < 4; ++i) {
        int b = grp * 16 + quad * 4 + i;
        float v0 = h0init[(size_t)b * DH_ + j];
        float v1 = h1init[(size_t)b * DH_ + j];
        hold0[i] = v0; hold1[i] = v1;
        publish(hx01, b, j, v0, col);
        publish(hx11, b, j, v1, col);
    }
    gbar(bar + grp);   // phase 0: init state visible in shared L2

    int ph = 1;
    for (int t = 0; t < OSL_; ++t) {
        bf16_t* write0 = (t & 1) ? hx01 : hx00;
        bf16_t* read0  = (t & 1) ? hx00 : hx01;
        bf16_t* write1 = (t & 1) ? hx11 : hx10;
        bf16_t* read1  = (t & 1) ? hx10 : hx11;
        bool dox0 = (t > 0);

        // ---- phase A: cell0 (h0' from h0, x=Weff@h1) ----
        // sh already holds h0(t-1) (staged in phase B of t-1); stage h1 only.
        if (t == 0) stage16_l2(sh, read0 + (size_t)grp * 16 * DH_);
        stage16_l2(sx, read1 + (size_t)grp * 16 * DH_);
        __syncthreads();
        cell_step(sh, sx, dox0, weff, wdhh0, j, col, quad, grp,
                  dox0 ? b0r : o0r, dox0 ? b0z : o0z, dox0 ? b0in : o0in, b0hn,
                  hold0, write0, nullptr);
        gbar(bar + ph * 16 + grp); ph++;

        // ---- phase B: cell1 (h1' from h1 in sx, x=h0(t) staged to sh) ----
        stage16_l2(sh, write0 + (size_t)grp * 16 * DH_);
        __syncthreads();
        cell_step(sx, sh, true, wdih1, wdhh1, j, col, quad, grp,
                  b1r, b1z, b1in, b1hn,
                  hold1, write1, hist + (size_t)t * B_ * DH_);
        if (t < OSL_ - 1) { gbar(bar + ph * 16 + grp); ph++; }
    }
}

// ------------------------------- FC head -----------------------------------
__global__ __launch_bounds__(256) void fc_all(
    const float* __restrict__ hist, const float* __restrict__ fcw,
    const float* __restrict__ fcb, float* __restrict__ out) {
    int t  = blockIdx.x >> 4;
    int b0 = (blockIdx.x & 15) * 16;
    int tid = threadIdx.x;
    int bl = tid >> 4, o = (tid >> 3) & 1, part = tid & 7;
    const float* hp = hist + ((size_t)t * B_ + b0 + bl) * DH_;
    const float* wp = fcw + o * DH_;
    float s = 0.0f;
    for (int k = part * 64; k < part * 64 + 64; k += 4) {
        f32x4 hv = *(const f32x4*)(hp + k);
        f32x4 wv = *(const f32x4*)(wp + k);
        s += hv[0] * wv[0] + hv[1] * wv[1] + hv[2] * wv[2] + hv[3] * wv[3];
    }
    s += __shfl_down(s, 4); s += __shfl_down(s, 2); s += __shfl_down(s, 1);
    if (part == 0) out[(size_t)(b0 + bl) * (OSL_ * 2) + t * 2 + o] = s + fcb[o];
}

// ------------------------------ launcher -----------------------------------

#define OFF_WIH0E 0ull
#define OFF_WHH0E 196608ull
#define OFF_WIH1E 983040ull
#define OFF_WHH1E 2555904ull
#define OFF_WDHH0 3342336ull
#define OFF_WDIH1 4915200ull
#define OFF_WDHH1 6488064ull
#define OFF_WEFF  8060928ull
#define OFF_BEFF  9633792ull
#define OFF_BAR   9641984ull    // 41 phases x 16 groups (zeroed 1024 u32)
#define OFF_OV    9658368ull
#define OFF_H0A   9682944ull
#define OFF_H0B   10207232ull   // hx00 (256 KB) + hx01 (256 KB)
#define OFF_H1A   10731520ull
#define OFF_H1B   11255808ull   // hx10 (256 KB) + hx11 (256 KB)
#define OFF_HST   11780096ull
#define OFF_HIST  12304384ull
#define OFF_XCAT  22790144ull
#define OFF_GI    157007872ull

extern "C" void kernel_launch(void* const* d_in, const int* in_sizes, int n_in,
                              void* d_out, int out_size, void* d_ws, size_t ws_size,
                              hipStream_t stream) {
    const float* x      = (const float*)d_in[0];
    const float* st     = (const float*)d_in[1];
    const float* eWih0  = (const float*)d_in[2];
    const float* eWhh0  = (const float*)d_in[3];
    const float* ebih0  = (const float*)d_in[4];
    const float* ebhh0  = (const float*)d_in[5];
    const float* eWih1  = (const float*)d_in[6];
    const float* eWhh1  = (const float*)d_in[7];
    const float* ebih1  = (const float*)d_in[8];
    const float* ebhh1  = (const float*)d_in[9];
    const float* dWih0  = (const float*)d_in[10];
    const float* dWhh0  = (const float*)d_in[11];
    const float* dbih0  = (const float*)d_in[12];
    const float* dbhh0  = (const float*)d_in[13];
    const float* dWih1  = (const float*)d_in[14];
    const float* dWhh1  = (const float*)d_in[15];
    const float* dbih1  = (const float*)d_in[16];
    const float* dbhh1  = (const float*)d_in[17];
    const float* fcW    = (const float*)d_in[18];
    const float* fcb    = (const float*)d_in[19];

    char* ws = (char*)d_ws;
    bf16_t* wih0e = (bf16_t*)(ws + OFF_WIH0E);
    bf16_t* whh0e = (bf16_t*)(ws + OFF_WHH0E);
    bf16_t* wih1e = (bf16_t*)(ws + OFF_WIH1E);
    bf16_t* whh1e = (bf16_t*)(ws + OFF_WHH1E);
    bf16_t* wdhh0 = (bf16_t*)(ws + OFF_WDHH0);
    bf16_t* wdih1 = (bf16_t*)(ws + OFF_WDIH1);
    bf16_t* wdhh1 = (bf16_t*)(ws + OFF_WDHH1);
    bf16_t* weff  = (bf16_t*)(ws + OFF_WEFF);
    float*  beff  = (float*)(ws + OFF_BEFF);
    unsigned int* bar = (unsigned int*)(ws + OFF_BAR);
    float*  ovp   = (float*)(ws + OFF_OV);
    float*  h0init = (float*)(ws + OFF_H0A);
    float*  h1init = (float*)(ws + OFF_H1A);
    bf16_t* hx00  = (bf16_t*)(ws + OFF_H0B);
    bf16_t* hx01  = (bf16_t*)(ws + OFF_H0B + 262144ull);
    bf16_t* hx10  = (bf16_t*)(ws + OFF_H1B);
    bf16_t* hx11  = (bf16_t*)(ws + OFF_H1B + 262144ull);
    float*  hstate = (float*)(ws + OFF_HST);
    float*  hist  = (float*)(ws + OFF_HIST);
    bf16_t* xcat  = (bf16_t*)(ws + OFF_XCAT);
    bf16_t* gi    = (bf16_t*)(ws + OFF_GI);

    int Tc = 512;
    while (Tc > 8 && OFF_GI + (unsigned long long)Tc * 786432ull > (unsigned long long)ws_size)
        Tc >>= 1;
    int nch = T_ / Tc;

    prep_all<<<dim3(3072, 8), 256, 0, stream>>>(
        eWih0, eWhh0, eWih1, eWhh1, dWhh0, dWih1, dWhh1,
        wih0e, whh0e, wih1e, whh1e, wdhh0, wdih1, wdhh1,
        dWih0, fcW, fcb, dbih0, st, weff, beff, ovp, bar);

    for (int c = 0; c < nch; c++) {
        gemm_gi<<<dim3(Tc * 2, 12), 256, 0, stream>>>(x, nullptr, wih0e, gi, c * Tc, 64);
        gru_scan<<<32, 512, 0, stream>>>(gi, c * Tc, Tc, whh0e, ebih0, ebhh0, hstate, xcat, h0init);
    }
    for (int c = 0; c < nch; c++) {
        gemm_gi<<<dim3(Tc * 2, 12), 256, 0, stream>>>(nullptr, xcat, wih1e, gi, c * Tc, 512);
        gru_scan<<<32, 512, 0, stream>>>(gi, c * Tc, Tc, whh1e, ebih1, ebhh1, hstate, nullptr, h1init);
    }

    dec_persist<<<128, 256, 0, stream>>>(weff, beff, ovp,
                                         wdhh0, dbhh0, wdih1, dbih1, wdhh1, dbhh1,
                                         h0init, h1init,
                                         hx00, hx01, hx10, hx11,
                                         hist, bar);

    fc_all<<<OSL_ * 16, 256, 0, stream>>>(hist, fcW, fcb, (float*)d_out);
}

// Round 9
// 4655.251 us; speedup vs baseline: 1.6958x; 1.0246x over previous
//
#include <hip/hip_runtime.h>
#include <hip/hip_bf16.h>
#include <stdint.h>
#include <stddef.h>

// ---------------------------------------------------------------------------
// Seq2Seq BiGRU: B=256 T=512 F=64 H=256 (2-layer bidir encoder),
// decoder DH=512 2-layer, OSL=20, OUT=2.
//
// Round-11 structure (= r7-passing kernel + ONE change):
//  - gbar: RELEASE -> RELAXED on the arrival fetch_add. Evidence: per-phase
//    decoder cost invariant at ~19-20us across r3/r4/r5/r7 while weight
//    traffic varied 5.6x -> the toll is NOT bandwidth; the common element is
//    the RELEASE's L2-writeback (buffer_wbl2) + completion wait, paid 40x.
//    With r7's mapping all 8 partners share one XCD L2: plain stores are in
//    that L2 before the barrier (vmcnt(0) drain at __syncthreads), partner
//    sc0 loads read the same L2 -> no cache maintenance needed.
//  - Everything else byte-identical to r7 (4770us, passed): intra-XCD h
//    exchange (grp=blockIdx&15), stage reuse, sc0 16B staging, bounded spin,
//    r3-proven scans/gemms. (r8's launch_bounds+pipeline changes dropped --
//    container failed twice with no profile; unexplained, not retried.)
// ---------------------------------------------------------------------------

typedef __bf16 bf16_t;
typedef bf16_t bf16x8 __attribute__((ext_vector_type(8)));
typedef float  f32x4  __attribute__((ext_vector_type(4)));

#define B_   256
#define T_   512
#define F_   64
#define H_   256
#define G_   768      // 3*H
#define DH_  512
#define DG_  1536     // 3*DH
#define OSL_ 20

__device__ __forceinline__ float sigm(float x) {
    float e = __builtin_amdgcn_exp2f(-1.442695040888963f * x);
    return __builtin_amdgcn_rcpf(1.0f + e);
}
__device__ __forceinline__ float tanh_(float x) {
    float e = __builtin_amdgcn_exp2f(-2.885390081777927f * x);
    return __builtin_amdgcn_rcpf(1.0f + e) * 2.0f - 1.0f;
}

__device__ __forceinline__ bf16x8 load_f32x8_as_bf16(const float* p) {
    f32x4 u = *(const f32x4*)p;
    f32x4 v = *(const f32x4*)(p + 4);
    bf16x8 r;
    r[0]=(bf16_t)u[0]; r[1]=(bf16_t)u[1]; r[2]=(bf16_t)u[2]; r[3]=(bf16_t)u[3];
    r[4]=(bf16_t)v[0]; r[5]=(bf16_t)v[1]; r[6]=(bf16_t)v[2]; r[7]=(bf16_t)v[3];
    return r;
}

// ------------------------------- fused prep --------------------------------
__global__ __launch_bounds__(256) void prep_all(
    const float* __restrict__ s0, const float* __restrict__ s1,
    const float* __restrict__ s2, const float* __restrict__ s3,
    const float* __restrict__ s4, const float* __restrict__ s5,
    const float* __restrict__ s6,
    bf16_t* __restrict__ d0, bf16_t* __restrict__ d1, bf16_t* __restrict__ d2,
    bf16_t* __restrict__ d3, bf16_t* __restrict__ d4, bf16_t* __restrict__ d5,
    bf16_t* __restrict__ d6,
    const float* __restrict__ wih0d, const float* __restrict__ fcw,
    const float* __restrict__ fcb, const float* __restrict__ bih0d,
    const float* __restrict__ st, bf16_t* __restrict__ weff,
    float* __restrict__ beff, float* __restrict__ ov,
    unsigned int* __restrict__ bar) {
    int i = blockIdx.x * 256 + threadIdx.x;
    switch (blockIdx.y) {
      case 0: if (i < 2*G_*F_)  d0[i] = (bf16_t)s0[i]; break;
      case 1: if (i < 2*G_*H_)  d1[i] = (bf16_t)s1[i]; break;
      case 2: if (i < 2*G_*DH_) d2[i] = (bf16_t)s2[i]; break;
      case 3: if (i < 2*G_*H_)  d3[i] = (bf16_t)s3[i]; break;
      case 4: if (i < DG_*DH_)  d4[i] = (bf16_t)s4[i]; break;
      case 5: if (i < DG_*DH_)  d5[i] = (bf16_t)s5[i]; break;
      case 6: if (i < DG_*DH_)  d6[i] = (bf16_t)s6[i]; break;
      default: {
        if (i < 1024) bar[i] = 0u;
        if (i < DG_*DH_) {
          int g = i >> 9, k = i & 511;
          float a0 = wih0d[g * 2], a1 = wih0d[g * 2 + 1];
          weff[i] = (bf16_t)(a0 * fcw[k] + a1 * fcw[DH_ + k]);
          if (k == 0) {
            beff[g] = a0 * fcb[0] + a1 * fcb[1] + bih0d[g];
            ov[g]   = a0 * st[0]  + a1 * st[1]  + bih0d[g];
          }
        }
      } break;
    }
}

// --------------------------- gi chunk GEMM ---------------------------------
__global__ __launch_bounds__(256) void gemm_gi(
    const float* __restrict__ x, const bf16_t* __restrict__ xcat,
    const bf16_t* __restrict__ Bt, bf16_t* __restrict__ gi, int t0, int K) {
    __shared__ bf16_t As[128 * 64];
    __shared__ bf16_t Bs[128 * 64];
    int m0 = blockIdx.x * 128, n0 = blockIdx.y * 128;
    int tid = threadIdx.x;
    int lane = tid & 63, w = tid >> 6;
    int col = lane & 15, quad = lane >> 4;
    int qm = (w >> 1) * 64, qn = (w & 1) * 64;

    int tl = m0 >> 8;              // local chunk time (constant per block)
    int bbase = m0 & 255;          // batch base (0 or 128)
    int t_real = t0 + tl;
    if (n0 >= 768) t_real = (T_ - 1) - t_real;

    f32x4 acc[4][4] = {};
    for (int k0 = 0; k0 < K; k0 += 64) {
        __syncthreads();
#pragma unroll
        for (int i = 0; i < 4; i++) {
            int c = i * 256 + tid;
            int m = c >> 3, kc = c & 7;
            int kcs = kc ^ (m & 7);   // XOR swizzle at source
            bf16x8 av;
            if (K == 64) {
                av = load_f32x8_as_bf16(x + ((size_t)(bbase + m) * T_ + t_real) * F_ + kcs * 8);
            } else {
                av = *(const bf16x8*)(xcat + ((size_t)t_real * B_ + bbase + m) * DH_ + k0 + kcs * 8);
            }
            *(bf16x8*)(&As[c * 8]) = av;
            *(bf16x8*)(&Bs[c * 8]) = *(const bf16x8*)(Bt + (size_t)(n0 + m) * K + k0 + kcs * 8);
        }
        __syncthreads();
#pragma unroll
        for (int kt = 0; kt < 2; kt++) {
            bf16x8 a[4], b[4];
#pragma unroll
            for (int mt = 0; mt < 4; mt++) {
                int r = qm + mt * 16 + col;
                a[mt] = *(const bf16x8*)(&As[(r * 8 + ((kt * 4 + quad) ^ (r & 7))) * 8]);
                int rn = qn + mt * 16 + col;
                b[mt] = *(const bf16x8*)(&Bs[(rn * 8 + ((kt * 4 + quad) ^ (rn & 7))) * 8]);
            }
#pragma unroll
            for (int mt = 0; mt < 4; mt++)
#pragma unroll
                for (int nt = 0; nt < 4; nt++)
                    acc[mt][nt] = __builtin_amdgcn_mfma_f32_16x16x32_bf16(a[mt], b[nt], acc[mt][nt], 0, 0, 0);
        }
    }
#pragma unroll
    for (int mt = 0; mt < 4; mt++)
#pragma unroll
        for (int nt = 0; nt < 4; nt++)
#pragma unroll
            for (int i = 0; i < 4; i++) {
                int row = m0 + qm + mt * 16 + quad * 4 + i;
                int cg  = n0 + qn + nt * 16 + col;
                gi[(size_t)row * DG_ + cg] = (bf16_t)acc[mt][nt][i];
            }
}

// ------------------------------ GRU scan (chunked) -------------------------
__global__ __launch_bounds__(512) void gru_scan(
    const bf16_t* __restrict__ gi, int t0, int tc,
    const bf16_t* __restrict__ whh,
    const float* __restrict__ bih, const float* __restrict__ bhh,
    float* __restrict__ hstate, bf16_t* __restrict__ y, float* __restrict__ hT) {
    __shared__ bf16_t gi_lds[16 * 768];       // [b][768]
    __shared__ bf16_t h_lds[2 * 16 * 264];    // [par][b][256+8 pad]

    int dir = blockIdx.x >> 4;
    int b0  = (blockIdx.x & 15) * 16;
    int tid = threadIdx.x;
    int w = tid >> 6, lane = tid & 63, col = lane & 15, quad = lane >> 4;

    bf16x8 wf[3][2][8];
    const bf16_t* wbase = whh + (size_t)dir * G_ * H_;
#pragma unroll
    for (int g = 0; g < 3; g++)
#pragma unroll
        for (int nt = 0; nt < 2; nt++) {
            int row = g * 256 + w * 32 + nt * 16 + col;
#pragma unroll
            for (int kt = 0; kt < 8; kt++)
                wf[g][nt][kt] = *(const bf16x8*)(wbase + (size_t)row * H_ + kt * 32 + quad * 8);
        }
    float brz[2][2], bin_[2], bhn[2];
#pragma unroll
    for (int nt = 0; nt < 2; nt++) {
        int j = w * 32 + nt * 16 + col;
        brz[0][nt] = bih[dir * G_ + j] + bhh[dir * G_ + j];
        brz[1][nt] = bih[dir * G_ + 256 + j] + bhh[dir * G_ + 256 + j];
        bin_[nt]   = bih[dir * G_ + 512 + j];
        bhn[nt]    = bhh[dir * G_ + 512 + j];
    }
    int bb[3], oo[3];
#pragma unroll
    for (int it = 0; it < 3; it++) {
        int c = it * 512 + tid;
        bb[it] = c / 96;
        oo[it] = (c % 96) * 8;
    }
    float hold[2][4];
#pragma unroll
    for (int nt = 0; nt < 2; nt++)
#pragma unroll
        for (int i = 0; i < 4; i++) {
            int j = w * 32 + nt * 16 + col;
            hold[nt][i] = t0 ? hstate[dir * 65536 + (b0 + quad * 4 + i) * 256 + j] : 0.0f;
        }
    for (int i = tid; i < 16 * 264; i += 512) {
        int b = i / 264, j = i % 264;
        float v = (t0 && j < 256) ? hstate[dir * 65536 + (b0 + b) * 256 + j] : 0.0f;
        h_lds[i] = (bf16_t)v;
    }
#pragma unroll
    for (int it = 0; it < 3; it++) {
        int c = it * 512 + tid;
        *(bf16x8*)(&gi_lds[c * 8]) =
            *(const bf16x8*)(gi + ((size_t)0 * B_ + b0 + bb[it]) * DG_ + dir * G_ + oo[it]);
    }
    __syncthreads();

    for (int s = 0; s < tc; s++) {
        int par = s & 1;
        int t = t0 + s;
        int sn = (s + 1 < tc) ? (s + 1) : s;

        bf16x8 pg[3];
#pragma unroll
        for (int it = 0; it < 3; it++)
            pg[it] = *(const bf16x8*)(gi + ((size_t)sn * B_ + b0 + bb[it]) * DG_ + dir * G_ + oo[it]);

        f32x4 acc[3][2] = {};
        const bf16_t* hcur = &h_lds[par * 4224];
#pragma unroll
        for (int kt = 0; kt < 8; kt++) {
            bf16x8 af = *(const bf16x8*)(hcur + col * 264 + kt * 32 + quad * 8);
#pragma unroll
            for (int g = 0; g < 3; g++)
#pragma unroll
                for (int nt = 0; nt < 2; nt++)
                    acc[g][nt] = __builtin_amdgcn_mfma_f32_16x16x32_bf16(af, wf[g][nt][kt], acc[g][nt], 0, 0, 0);
        }

        bf16_t* hnext = &h_lds[(par ^ 1) * 4224];
        int tp = dir ? (T_ - 1 - t) : t;
#pragma unroll
        for (int nt = 0; nt < 2; nt++) {
            int j = w * 32 + nt * 16 + col;
#pragma unroll
            for (int i = 0; i < 4; i++) {
                int b = quad * 4 + i;
                float gr = acc[0][nt][i] + (float)gi_lds[b * 768 + j]       + brz[0][nt];
                float gz = acc[1][nt][i] + (float)gi_lds[b * 768 + 256 + j] + brz[1][nt];
                float gn = (float)gi_lds[b * 768 + 512 + j] + bin_[nt];
                float r = sigm(gr), z = sigm(gz);
                float n = tanh_(gn + r * (acc[2][nt][i] + bhn[nt]));
                float hv = (1.0f - z) * n + z * hold[nt][i];
                hold[nt][i] = hv;
                hnext[b * 264 + j] = (bf16_t)hv;
                if (y) y[((size_t)tp * B_ + b0 + b) * DH_ + dir * H_ + j] = (bf16_t)hv;
                if (t == T_ - 1) hT[(size_t)(b0 + b) * DH_ + dir * H_ + j] = hv;
            }
        }
        __syncthreads();
#pragma unroll
        for (int it = 0; it < 3; it++)
            *(bf16x8*)(&gi_lds[(it * 512 + tid) * 8]) = pg[it];
        __syncthreads();
    }
#pragma unroll
    for (int nt = 0; nt < 2; nt++)
#pragma unroll
        for (int i = 0; i < 4; i++) {
            int j = w * 32 + nt * 16 + col;
            hstate[dir * 65536 + (b0 + quad * 4 + i) * 256 + j] = hold[nt][i];
        }
}

// ------------------------- persistent fused decoder ------------------------
// 128 WGs = 16 batch-groups (grp = blockIdx&15) x 8 j-blocks (blockIdx>>4).
// Partner WGs of a group differ by 16 in blockIdx -> SAME XCD (%8) -> the h
// exchange lives in the XCD-local L2: plain stores (write-through L1->L2),
// sc0 (L1-bypass) 16B loads. Barrier = RELAXED device RMW + bounded spin:
// no RELEASE -> no buffer_wbl2 cache maintenance (visibility is via the
// shared XCD L2; stores are drained to L2 by the vmcnt(0) at __syncthreads).

__device__ __forceinline__ void gbar(unsigned int* cnt) {
    __syncthreads();   // drains vmcnt -> publishes in L2 before arrival
    if (threadIdx.x == 0) {
        __hip_atomic_fetch_add(cnt, 1u, __ATOMIC_RELAXED, __HIP_MEMORY_SCOPE_AGENT);
        unsigned int s = 0;
        while (__hip_atomic_load(cnt, __ATOMIC_RELAXED, __HIP_MEMORY_SCOPE_AGENT) < 8u
               && ++s < (1u << 20))
            __builtin_amdgcn_s_sleep(1);
    }
    __syncthreads();
}

// stage 16 rows x 512 bf16 (16 KB) from XCD-local L2 into XOR-swizzled LDS.
// sc0 = bypass L1, read shared L2 (partners are intra-XCD).
__device__ __forceinline__ void stage16_l2(bf16_t* lds, const bf16_t* src) {
    f32x4 v0, v1, v2, v3;
    const char* s = (const char*)src;
    const char* a0 = s + threadIdx.x * 16;
    asm volatile(
        "global_load_dwordx4 %0, %4, off sc0\n\t"
        "global_load_dwordx4 %1, %5, off sc0\n\t"
        "global_load_dwordx4 %2, %6, off sc0\n\t"
        "global_load_dwordx4 %3, %7, off sc0\n\t"
        "s_waitcnt vmcnt(0)"
        : "=&v"(v0), "=&v"(v1), "=&v"(v2), "=&v"(v3)
        : "v"(a0), "v"(a0 + 4096), "v"(a0 + 8192), "v"(a0 + 12288)
        : "memory");
    f32x4 vv[4] = { v0, v1, v2, v3 };
#pragma unroll
    for (int i2 = 0; i2 < 4; ++i2) {
        int off = i2 * 4096 + threadIdx.x * 16;
        int row = off >> 10;
        int swz = off ^ ((row & 7) << 4);
        *(f32x4*)((char*)lds + swz) = vv[i2];
    }
}

__device__ __forceinline__ bf16x8 fragrd(const bf16_t* lds, int kt, int col, int quad) {
    int byte = (col * 1024 + kt * 64 + quad * 16) ^ ((col & 7) << 4);
    return *(const bf16x8*)((const char*)lds + byte);
}

// publish hv as bf16 into packed u32 pairs (even-col lanes store j, j+1);
// plain store -> write-through to the XCD-local L2.
__device__ __forceinline__ void publish(bf16_t* dst, int b, int j, float hv, int col) {
    bf16_t hb = (bf16_t)hv;
    unsigned short mb;
    __builtin_memcpy(&mb, &hb, 2);
    unsigned int pv = (unsigned int)__shfl_xor((int)(unsigned int)mb, 1);
    if ((col & 1) == 0) {
        unsigned int word = (unsigned int)mb | (pv << 16);
        *(unsigned int*)((char*)dst + (size_t)(b * DH_ + j) * 2) = word;
    }
}

__device__ __forceinline__ void cell_step(
    const bf16_t* sh, const bf16_t* sx, bool dox,
    const bf16_t* __restrict__ Wx, const bf16_t* __restrict__ Wh,
    int j, int col, int quad, int grp,
    float br, float bz, float bin_, float bhn,
    float hold[4], bf16_t* hout, float* hist_t) {
    f32x4 aR = {}, aZ = {}, aIN = {}, aHN = {};
#pragma unroll
    for (int kt = 0; kt < 16; ++kt) {
        bf16x8 ah = fragrd(sh, kt, col, quad);
        bf16x8 w0 = *(const bf16x8*)(Wh + (size_t)j * DH_ + kt * 32 + quad * 8);
        bf16x8 w1 = *(const bf16x8*)(Wh + (size_t)(DH_ + j) * DH_ + kt * 32 + quad * 8);
        bf16x8 w2 = *(const bf16x8*)(Wh + (size_t)(2 * DH_ + j) * DH_ + kt * 32 + quad * 8);
        aR  = __builtin_amdgcn_mfma_f32_16x16x32_bf16(ah, w0, aR, 0, 0, 0);
        aZ  = __builtin_amdgcn_mfma_f32_16x16x32_bf16(ah, w1, aZ, 0, 0, 0);
        aHN = __builtin_amdgcn_mfma_f32_16x16x32_bf16(ah, w2, aHN, 0, 0, 0);
        if (dox) {
            bf16x8 ax = fragrd(sx, kt, col, quad);
            bf16x8 x0 = *(const bf16x8*)(Wx + (size_t)j * DH_ + kt * 32 + quad * 8);
            bf16x8 x1 = *(const bf16x8*)(Wx + (size_t)(DH_ + j) * DH_ + kt * 32 + quad * 8);
            bf16x8 x2 = *(const bf16x8*)(Wx + (size_t)(2 * DH_ + j) * DH_ + kt * 32 + quad * 8);
            aR  = __builtin_amdgcn_mfma_f32_16x16x32_bf16(ax, x0, aR, 0, 0, 0);
            aZ  = __builtin_amdgcn_mfma_f32_16x16x32_bf16(ax, x1, aZ, 0, 0, 0);
            aIN = __builtin_amdgcn_mfma_f32_16x16x32_bf16(ax, x2, aIN, 0, 0, 0);
        }
    }
#pragma unroll
    for (int i = 0; i < 4; ++i) {
        int b = grp * 16 + quad * 4 + i;
        float r = sigm(aR[i] + br);
        float z = sigm(aZ[i] + bz);
        float n = tanh_(aIN[i] + bin_ + r * (aHN[i] + bhn));
        float hv = (1.0f - z) * n + z * hold[i];
        hold[i] = hv;
        if (hist_t) hist_t[(size_t)b * DH_ + j] = hv;
        publish(hout, b, j, hv, col);
    }
}

__global__ __launch_bounds__(256) void dec_persist(
    const bf16_t* __restrict__ weff, const float* __restrict__ beff,
    const float* __restrict__ ov,
    const bf16_t* __restrict__ wdhh0, const float* __restrict__ dbhh0,
    const bf16_t* __restrict__ wdih1, const float* __restrict__ dbih1,
    const bf16_t* __restrict__ wdhh1, const float* __restrict__ dbhh1,
    const float* __restrict__ h0init, const float* __restrict__ h1init,
    bf16_t* hx00, bf16_t* hx01, bf16_t* hx10, bf16_t* hx11,
    float* __restrict__ hist, unsigned int* __restrict__ bar) {
    __shared__ bf16_t sh[16 * 512];   // holds h0 across phases
    __shared__ bf16_t sx[16 * 512];   // holds h1 across phases
    int grp = blockIdx.x & 15;        // partners 16 apart -> same XCD (%8)
    int jblk = blockIdx.x >> 4;
    int tid = threadIdx.x, w = tid >> 6, lane = tid & 63;
    int col = lane & 15, quad = lane >> 4;
    int j = jblk * 64 + w * 16 + col;

    // per-lane folded biases
    float b0r = beff[j] + dbhh0[j],           b0z = beff[DH_ + j] + dbhh0[DH_ + j];
    float b0in = beff[2 * DH_ + j],           b0hn = dbhh0[2 * DH_ + j];
    float o0r = ov[j] + dbhh0[j],             o0z = ov[DH_ + j] + dbhh0[DH_ + j];
    float o0in = ov[2 * DH_ + j];
    float b1r = dbih1[j] + dbhh1[j],          b1z = dbih1[DH_ + j] + dbhh1[DH_ + j];
    float b1in = dbih1[2 * DH_ + j],          b1hn = dbhh1[2 * DH_ + j];

    // fp32 carries in registers; publish initial bf16 state to parity-1 bufs
    float hold0[4], hold1[4];
#pragma unroll
    for (int i = 0; i < 4; ++i) {
        int b = grp * 16 + quad * 4 + i;
        float v0 = h0init[(size_t)b * DH_ + j];
        float v1 = h1init[(size_t)b * DH_ + j];
        hold0[i] = v0; hold1[i] = v1;
        publish(hx01, b, j, v0, col);
        publish(hx11, b, j, v1, col);
    }
    gbar(bar + grp);   // phase 0: init state visible in shared L2

    int ph = 1;
    for (int t = 0; t < OSL_; ++t) {
        bf16_t* write0 = (t & 1) ? hx01 : hx00;
        bf16_t* read0  = (t & 1) ? hx00 : hx01;
        bf16_t* write1 = (t & 1) ? hx11 : hx10;
        bf16_t* read1  = (t & 1) ? hx10 : hx11;
        bool dox0 = (t > 0);

        // ---- phase A: cell0 (h0' from h0, x=Weff@h1) ----
        // sh already holds h0(t-1) (staged in phase B of t-1); stage h1 only.
        if (t == 0) stage16_l2(sh, read0 + (size_t)grp * 16 * DH_);
        stage16_l2(sx, read1 + (size_t)grp * 16 * DH_);
        __syncthreads();
        cell_step(sh, sx, dox0, weff, wdhh0, j, col, quad, grp,
                  dox0 ? b0r : o0r, dox0 ? b0z : o0z, dox0 ? b0in : o0in, b0hn,
                  hold0, write0, nullptr);
        gbar(bar + ph * 16 + grp); ph++;

        // ---- phase B: cell1 (h1' from h1 in sx, x=h0(t) staged to sh) ----
        stage16_l2(sh, write0 + (size_t)grp * 16 * DH_);
        __syncthreads();
        cell_step(sx, sh, true, wdih1, wdhh1, j, col, quad, grp,
                  b1r, b1z, b1in, b1hn,
                  hold1, write1, hist + (size_t)t * B_ * DH_);
        if (t < OSL_ - 1) { gbar(bar + ph * 16 + grp); ph++; }
    }
}

// ------------------------------- FC head -----------------------------------
__global__ __launch_bounds__(256) void fc_all(
    const float* __restrict__ hist, const float* __restrict__ fcw,
    const float* __restrict__ fcb, float* __restrict__ out) {
    int t  = blockIdx.x >> 4;
    int b0 = (blockIdx.x & 15) * 16;
    int tid = threadIdx.x;
    int bl = tid >> 4, o = (tid >> 3) & 1, part = tid & 7;
    const float* hp = hist + ((size_t)t * B_ + b0 + bl) * DH_;
    const float* wp = fcw + o * DH_;
    float s = 0.0f;
    for (int k = part * 64; k < part * 64 + 64; k += 4) {
        f32x4 hv = *(const f32x4*)(hp + k);
        f32x4 wv = *(const f32x4*)(wp + k);
        s += hv[0] * wv[0] + hv[1] * wv[1] + hv[2] * wv[2] + hv[3] * wv[3];
    }
    s += __shfl_down(s, 4); s += __shfl_down(s, 2); s += __shfl_down(s, 1);
    if (part == 0) out[(size_t)(b0 + bl) * (OSL_ * 2) + t * 2 + o] = s + fcb[o];
}

// ------------------------------ launcher -----------------------------------

#define OFF_WIH0E 0ull
#define OFF_WHH0E 196608ull
#define OFF_WIH1E 983040ull
#define OFF_WHH1E 2555904ull
#define OFF_WDHH0 3342336ull
#define OFF_WDIH1 4915200ull
#define OFF_WDHH1 6488064ull
#define OFF_WEFF  8060928ull
#define OFF_BEFF  9633792ull
#define OFF_BAR   9641984ull    // 41 phases x 16 groups (zeroed 1024 u32)
#define OFF_OV    9658368ull
#define OFF_H0A   9682944ull
#define OFF_H0B   10207232ull   // hx00 (256 KB) + hx01 (256 KB)
#define OFF_H1A   10731520ull
#define OFF_H1B   11255808ull   // hx10 (256 KB) + hx11 (256 KB)
#define OFF_HST   11780096ull
#define OFF_HIST  12304384ull
#define OFF_XCAT  22790144ull
#define OFF_GI    157007872ull

extern "C" void kernel_launch(void* const* d_in, const int* in_sizes, int n_in,
                              void* d_out, int out_size, void* d_ws, size_t ws_size,
                              hipStream_t stream) {
    const float* x      = (const float*)d_in[0];
    const float* st     = (const float*)d_in[1];
    const float* eWih0  = (const float*)d_in[2];
    const float* eWhh0  = (const float*)d_in[3];
    const float* ebih0  = (const float*)d_in[4];
    const float* ebhh0  = (const float*)d_in[5];
    const float* eWih1  = (const float*)d_in[6];
    const float* eWhh1  = (const float*)d_in[7];
    const float* ebih1  = (const float*)d_in[8];
    const float* ebhh1  = (const float*)d_in[9];
    const float* dWih0  = (const float*)d_in[10];
    const float* dWhh0  = (const float*)d_in[11];
    const float* dbih0  = (const float*)d_in[12];
    const float* dbhh0  = (const float*)d_in[13];
    const float* dWih1  = (const float*)d_in[14];
    const float* dWhh1  = (const float*)d_in[15];
    const float* dbih1  = (const float*)d_in[16];
    const float* dbhh1  = (const float*)d_in[17];
    const float* fcW    = (const float*)d_in[18];
    const float* fcb    = (const float*)d_in[19];

    char* ws = (char*)d_ws;
    bf16_t* wih0e = (bf16_t*)(ws + OFF_WIH0E);
    bf16_t* whh0e = (bf16_t*)(ws + OFF_WHH0E);
    bf16_t* wih1e = (bf16_t*)(ws + OFF_WIH1E);
    bf16_t* whh1e = (bf16_t*)(ws + OFF_WHH1E);
    bf16_t* wdhh0 = (bf16_t*)(ws + OFF_WDHH0);
    bf16_t* wdih1 = (bf16_t*)(ws + OFF_WDIH1);
    bf16_t* wdhh1 = (bf16_t*)(ws + OFF_WDHH1);
    bf16_t* weff  = (bf16_t*)(ws + OFF_WEFF);
    float*  beff  = (float*)(ws + OFF_BEFF);
    unsigned int* bar = (unsigned int*)(ws + OFF_BAR);
    float*  ovp   = (float*)(ws + OFF_OV);
    float*  h0init = (float*)(ws + OFF_H0A);
    float*  h1init = (float*)(ws + OFF_H1A);
    bf16_t* hx00  = (bf16_t*)(ws + OFF_H0B);
    bf16_t* hx01  = (bf16_t*)(ws + OFF_H0B + 262144ull);
    bf16_t* hx10  = (bf16_t*)(ws + OFF_H1B);
    bf16_t* hx11  = (bf16_t*)(ws + OFF_H1B + 262144ull);
    float*  hstate = (float*)(ws + OFF_HST);
    float*  hist  = (float*)(ws + OFF_HIST);
    bf16_t* xcat  = (bf16_t*)(ws + OFF_XCAT);
    bf16_t* gi    = (bf16_t*)(ws + OFF_GI);

    int Tc = 512;
    while (Tc > 8 && OFF_GI + (unsigned long long)Tc * 786432ull > (unsigned long long)ws_size)
        Tc >>= 1;
    int nch = T_ / Tc;

    prep_all<<<dim3(3072, 8), 256, 0, stream>>>(
        eWih0, eWhh0, eWih1, eWhh1, dWhh0, dWih1, dWhh1,
        wih0e, whh0e, wih1e, whh1e, wdhh0, wdih1, wdhh1,
        dWih0, fcW, fcb, dbih0, st, weff, beff, ovp, bar);

    for (int c = 0; c < nch; c++) {
        gemm_gi<<<dim3(Tc * 2, 12), 256, 0, stream>>>(x, nullptr, wih0e, gi, c * Tc, 64);
        gru_scan<<<32, 512, 0, stream>>>(gi, c * Tc, Tc, whh0e, ebih0, ebhh0, hstate, xcat, h0init);
    }
    for (int c = 0; c < nch; c++) {
        gemm_gi<<<dim3(Tc * 2, 12), 256, 0, stream>>>(nullptr, xcat, wih1e, gi, c * Tc, 512);
        gru_scan<<<32, 512, 0, stream>>>(gi, c * Tc, Tc, whh1e, ebih1, ebhh1, hstate, nullptr, h1init);
    }

    dec_persist<<<128, 256, 0, stream>>>(weff, beff, ovp,
                                         wdhh0, dbhh0, wdih1, dbih1, wdhh1, dbhh1,
                                         h0init, h1init,
                                         hx00, hx01, hx10, hx11,
                                         hist, bar);

    fc_all<<<OSL_ * 16, 256, 0, stream>>>(hist, fcW, fcb, (float*)d_out);
}

// Round 10
// 4631.292 us; speedup vs baseline: 1.7046x; 1.0052x over previous
//
#include <hip/hip_runtime.h>
#include <hip/hip_bf16.h>
#include <stdint.h>
#include <stddef.h>

// ---------------------------------------------------------------------------
// Seq2Seq BiGRU: B=256 T=512 F=64 H=256 (2-layer bidir encoder),
// decoder DH=512 2-layer, OSL=20, OUT=2.
//
// Round-12 structure (= r9 + decoder weight-resident remap):
//  - dec_persist: jblk = blockIdx&7 (r4-proven: per-XCD weight slice 790KB/
//    cell -> L2-resident, FETCH 308->88MB measured) combined with the r7/r9
//    fast exchange (batched 16B asm staging, single vmcnt; RELAXED barrier;
//    stage-reuse). h exchange is now CROSS-XCD -> loads AND stores carry
//    agent-scope sc0 sc1 flags (same coherence-point path r3/r4/r5's atomics
//    proved correct; batched form avoids hipcc's per-element atomic
//    serialization that made r4 slow). Barrier: RELAXED RMW + bounded spin
//    (any visibility mistake -> absmax failure, never a hang).
//  - r9 evidence this is the right lever: 666us = 39 x 17us/phase with
//    weight-L3-latency the dominant component (FETCH 491MB; MFMA+stage+bar
//    account for ~4us). r4 evidence: &7 map kills the weight traffic.
//  - prep/gemm/scan/fc byte-identical to r9 (4655us, passed).
// ---------------------------------------------------------------------------

typedef __bf16 bf16_t;
typedef bf16_t bf16x8 __attribute__((ext_vector_type(8)));
typedef float  f32x4  __attribute__((ext_vector_type(4)));

#define B_   256
#define T_   512
#define F_   64
#define H_   256
#define G_   768      // 3*H
#define DH_  512
#define DG_  1536     // 3*DH
#define OSL_ 20

__device__ __forceinline__ float sigm(float x) {
    float e = __builtin_amdgcn_exp2f(-1.442695040888963f * x);
    return __builtin_amdgcn_rcpf(1.0f + e);
}
__device__ __forceinline__ float tanh_(float x) {
    float e = __builtin_amdgcn_exp2f(-2.885390081777927f * x);
    return __builtin_amdgcn_rcpf(1.0f + e) * 2.0f - 1.0f;
}

__device__ __forceinline__ bf16x8 load_f32x8_as_bf16(const float* p) {
    f32x4 u = *(const f32x4*)p;
    f32x4 v = *(const f32x4*)(p + 4);
    bf16x8 r;
    r[0]=(bf16_t)u[0]; r[1]=(bf16_t)u[1]; r[2]=(bf16_t)u[2]; r[3]=(bf16_t)u[3];
    r[4]=(bf16_t)v[0]; r[5]=(bf16_t)v[1]; r[6]=(bf16_t)v[2]; r[7]=(bf16_t)v[3];
    return r;
}

// ------------------------------- fused prep --------------------------------
__global__ __launch_bounds__(256) void prep_all(
    const float* __restrict__ s0, const float* __restrict__ s1,
    const float* __restrict__ s2, const float* __restrict__ s3,
    const float* __restrict__ s4, const float* __restrict__ s5,
    const float* __restrict__ s6,
    bf16_t* __restrict__ d0, bf16_t* __restrict__ d1, bf16_t* __restrict__ d2,
    bf16_t* __restrict__ d3, bf16_t* __restrict__ d4, bf16_t* __restrict__ d5,
    bf16_t* __restrict__ d6,
    const float* __restrict__ wih0d, const float* __restrict__ fcw,
    const float* __restrict__ fcb, const float* __restrict__ bih0d,
    const float* __restrict__ st, bf16_t* __restrict__ weff,
    float* __restrict__ beff, float* __restrict__ ov,
    unsigned int* __restrict__ bar) {
    int i = blockIdx.x * 256 + threadIdx.x;
    switch (blockIdx.y) {
      case 0: if (i < 2*G_*F_)  d0[i] = (bf16_t)s0[i]; break;
      case 1: if (i < 2*G_*H_)  d1[i] = (bf16_t)s1[i]; break;
      case 2: if (i < 2*G_*DH_) d2[i] = (bf16_t)s2[i]; break;
      case 3: if (i < 2*G_*H_)  d3[i] = (bf16_t)s3[i]; break;
      case 4: if (i < DG_*DH_)  d4[i] = (bf16_t)s4[i]; break;
      case 5: if (i < DG_*DH_)  d5[i] = (bf16_t)s5[i]; break;
      case 6: if (i < DG_*DH_)  d6[i] = (bf16_t)s6[i]; break;
      default: {
        if (i < 1024) bar[i] = 0u;
        if (i < DG_*DH_) {
          int g = i >> 9, k = i & 511;
          float a0 = wih0d[g * 2], a1 = wih0d[g * 2 + 1];
          weff[i] = (bf16_t)(a0 * fcw[k] + a1 * fcw[DH_ + k]);
          if (k == 0) {
            beff[g] = a0 * fcb[0] + a1 * fcb[1] + bih0d[g];
            ov[g]   = a0 * st[0]  + a1 * st[1]  + bih0d[g];
          }
        }
      } break;
    }
}

// --------------------------- gi chunk GEMM ---------------------------------
__global__ __launch_bounds__(256) void gemm_gi(
    const float* __restrict__ x, const bf16_t* __restrict__ xcat,
    const bf16_t* __restrict__ Bt, bf16_t* __restrict__ gi, int t0, int K) {
    __shared__ bf16_t As[128 * 64];
    __shared__ bf16_t Bs[128 * 64];
    int m0 = blockIdx.x * 128, n0 = blockIdx.y * 128;
    int tid = threadIdx.x;
    int lane = tid & 63, w = tid >> 6;
    int col = lane & 15, quad = lane >> 4;
    int qm = (w >> 1) * 64, qn = (w & 1) * 64;

    int tl = m0 >> 8;              // local chunk time (constant per block)
    int bbase = m0 & 255;          // batch base (0 or 128)
    int t_real = t0 + tl;
    if (n0 >= 768) t_real = (T_ - 1) - t_real;

    f32x4 acc[4][4] = {};
    for (int k0 = 0; k0 < K; k0 += 64) {
        __syncthreads();
#pragma unroll
        for (int i = 0; i < 4; i++) {
            int c = i * 256 + tid;
            int m = c >> 3, kc = c & 7;
            int kcs = kc ^ (m & 7);   // XOR swizzle at source
            bf16x8 av;
            if (K == 64) {
                av = load_f32x8_as_bf16(x + ((size_t)(bbase + m) * T_ + t_real) * F_ + kcs * 8);
            } else {
                av = *(const bf16x8*)(xcat + ((size_t)t_real * B_ + bbase + m) * DH_ + k0 + kcs * 8);
            }
            *(bf16x8*)(&As[c * 8]) = av;
            *(bf16x8*)(&Bs[c * 8]) = *(const bf16x8*)(Bt + (size_t)(n0 + m) * K + k0 + kcs * 8);
        }
        __syncthreads();
#pragma unroll
        for (int kt = 0; kt < 2; kt++) {
            bf16x8 a[4], b[4];
#pragma unroll
            for (int mt = 0; mt < 4; mt++) {
                int r = qm + mt * 16 + col;
                a[mt] = *(const bf16x8*)(&As[(r * 8 + ((kt * 4 + quad) ^ (r & 7))) * 8]);
                int rn = qn + mt * 16 + col;
                b[mt] = *(const bf16x8*)(&Bs[(rn * 8 + ((kt * 4 + quad) ^ (rn & 7))) * 8]);
            }
#pragma unroll
            for (int mt = 0; mt < 4; mt++)
#pragma unroll
                for (int nt = 0; nt < 4; nt++)
                    acc[mt][nt] = __builtin_amdgcn_mfma_f32_16x16x32_bf16(a[mt], b[nt], acc[mt][nt], 0, 0, 0);
        }
    }
#pragma unroll
    for (int mt = 0; mt < 4; mt++)
#pragma unroll
        for (int nt = 0; nt < 4; nt++)
#pragma unroll
            for (int i = 0; i < 4; i++) {
                int row = m0 + qm + mt * 16 + quad * 4 + i;
                int cg  = n0 + qn + nt * 16 + col;
                gi[(size_t)row * DG_ + cg] = (bf16_t)acc[mt][nt][i];
            }
}

// ------------------------------ GRU scan (chunked) -------------------------
__global__ __launch_bounds__(512) void gru_scan(
    const bf16_t* __restrict__ gi, int t0, int tc,
    const bf16_t* __restrict__ whh,
    const float* __restrict__ bih, const float* __restrict__ bhh,
    float* __restrict__ hstate, bf16_t* __restrict__ y, float* __restrict__ hT) {
    __shared__ bf16_t gi_lds[16 * 768];       // [b][768]
    __shared__ bf16_t h_lds[2 * 16 * 264];    // [par][b][256+8 pad]

    int dir = blockIdx.x >> 4;
    int b0  = (blockIdx.x & 15) * 16;
    int tid = threadIdx.x;
    int w = tid >> 6, lane = tid & 63, col = lane & 15, quad = lane >> 4;

    bf16x8 wf[3][2][8];
    const bf16_t* wbase = whh + (size_t)dir * G_ * H_;
#pragma unroll
    for (int g = 0; g < 3; g++)
#pragma unroll
        for (int nt = 0; nt < 2; nt++) {
            int row = g * 256 + w * 32 + nt * 16 + col;
#pragma unroll
            for (int kt = 0; kt < 8; kt++)
                wf[g][nt][kt] = *(const bf16x8*)(wbase + (size_t)row * H_ + kt * 32 + quad * 8);
        }
    float brz[2][2], bin_[2], bhn[2];
#pragma unroll
    for (int nt = 0; nt < 2; nt++) {
        int j = w * 32 + nt * 16 + col;
        brz[0][nt] = bih[dir * G_ + j] + bhh[dir * G_ + j];
        brz[1][nt] = bih[dir * G_ + 256 + j] + bhh[dir * G_ + 256 + j];
        bin_[nt]   = bih[dir * G_ + 512 + j];
        bhn[nt]    = bhh[dir * G_ + 512 + j];
    }
    int bb[3], oo[3];
#pragma unroll
    for (int it = 0; it < 3; it++) {
        int c = it * 512 + tid;
        bb[it] = c / 96;
        oo[it] = (c % 96) * 8;
    }
    float hold[2][4];
#pragma unroll
    for (int nt = 0; nt < 2; nt++)
#pragma unroll
        for (int i = 0; i < 4; i++) {
            int j = w * 32 + nt * 16 + col;
            hold[nt][i] = t0 ? hstate[dir * 65536 + (b0 + quad * 4 + i) * 256 + j] : 0.0f;
        }
    for (int i = tid; i < 16 * 264; i += 512) {
        int b = i / 264, j = i % 264;
        float v = (t0 && j < 256) ? hstate[dir * 65536 + (b0 + b) * 256 + j] : 0.0f;
        h_lds[i] = (bf16_t)v;
    }
#pragma unroll
    for (int it = 0; it < 3; it++) {
        int c = it * 512 + tid;
        *(bf16x8*)(&gi_lds[c * 8]) =
            *(const bf16x8*)(gi + ((size_t)0 * B_ + b0 + bb[it]) * DG_ + dir * G_ + oo[it]);
    }
    __syncthreads();

    for (int s = 0; s < tc; s++) {
        int par = s & 1;
        int t = t0 + s;
        int sn = (s + 1 < tc) ? (s + 1) : s;

        bf16x8 pg[3];
#pragma unroll
        for (int it = 0; it < 3; it++)
            pg[it] = *(const bf16x8*)(gi + ((size_t)sn * B_ + b0 + bb[it]) * DG_ + dir * G_ + oo[it]);

        f32x4 acc[3][2] = {};
        const bf16_t* hcur = &h_lds[par * 4224];
#pragma unroll
        for (int kt = 0; kt < 8; kt++) {
            bf16x8 af = *(const bf16x8*)(hcur + col * 264 + kt * 32 + quad * 8);
#pragma unroll
            for (int g = 0; g < 3; g++)
#pragma unroll
                for (int nt = 0; nt < 2; nt++)
                    acc[g][nt] = __builtin_amdgcn_mfma_f32_16x16x32_bf16(af, wf[g][nt][kt], acc[g][nt], 0, 0, 0);
        }

        bf16_t* hnext = &h_lds[(par ^ 1) * 4224];
        int tp = dir ? (T_ - 1 - t) : t;
#pragma unroll
        for (int nt = 0; nt < 2; nt++) {
            int j = w * 32 + nt * 16 + col;
#pragma unroll
            for (int i = 0; i < 4; i++) {
                int b = quad * 4 + i;
                float gr = acc[0][nt][i] + (float)gi_lds[b * 768 + j]       + brz[0][nt];
                float gz = acc[1][nt][i] + (float)gi_lds[b * 768 + 256 + j] + brz[1][nt];
                float gn = (float)gi_lds[b * 768 + 512 + j] + bin_[nt];
                float r = sigm(gr), z = sigm(gz);
                float n = tanh_(gn + r * (acc[2][nt][i] + bhn[nt]));
                float hv = (1.0f - z) * n + z * hold[nt][i];
                hold[nt][i] = hv;
                hnext[b * 264 + j] = (bf16_t)hv;
                if (y) y[((size_t)tp * B_ + b0 + b) * DH_ + dir * H_ + j] = (bf16_t)hv;
                if (t == T_ - 1) hT[(size_t)(b0 + b) * DH_ + dir * H_ + j] = hv;
            }
        }
        __syncthreads();
#pragma unroll
        for (int it = 0; it < 3; it++)
            *(bf16x8*)(&gi_lds[(it * 512 + tid) * 8]) = pg[it];
        __syncthreads();
    }
#pragma unroll
    for (int nt = 0; nt < 2; nt++)
#pragma unroll
        for (int i = 0; i < 4; i++) {
            int j = w * 32 + nt * 16 + col;
            hstate[dir * 65536 + (b0 + quad * 4 + i) * 256 + j] = hold[nt][i];
        }
}

// ------------------------- persistent fused decoder ------------------------
// 128 WGs = 8 j-blocks (jblk = blockIdx&7) x 16 batch-groups (blockIdx>>3).
// jblk=&7 -> each XCD hosts ONE j-slice's weight rows (~790KB/cell) ->
// L2-resident across all 40 phases (r4-measured: FETCH 308->88MB).
// h exchange is cross-XCD -> agent-scope (sc0 sc1) batched 16B asm loads
// and sc0 sc1 stores (coherence-point path; r3/r4/r5-proven semantics,
// batched form avoids hipcc's per-element atomic serialization).
// Barrier = RELAXED device RMW + bounded spin (fails visibly, never hangs).

__device__ __forceinline__ void gbar(unsigned int* cnt) {
    __syncthreads();   // drains vmcnt -> publishes at coherence point
    if (threadIdx.x == 0) {
        __hip_atomic_fetch_add(cnt, 1u, __ATOMIC_RELAXED, __HIP_MEMORY_SCOPE_AGENT);
        unsigned int s = 0;
        while (__hip_atomic_load(cnt, __ATOMIC_RELAXED, __HIP_MEMORY_SCOPE_AGENT) < 8u
               && ++s < (1u << 20))
            __builtin_amdgcn_s_sleep(1);
    }
    __syncthreads();
}

// stage 16 rows x 512 bf16 (16 KB) from coherence point into swizzled LDS.
// sc0 sc1 = device-coherent read (bypasses stale L1/L2 for cross-XCD data);
// 4 loads issued back-to-back, ONE vmcnt drain (not per-element).
__device__ __forceinline__ void stage16_x(bf16_t* lds, const bf16_t* src) {
    f32x4 v0, v1, v2, v3;
    const char* s = (const char*)src;
    const char* a0 = s + threadIdx.x * 16;
    asm volatile(
        "global_load_dwordx4 %0, %4, off sc0 sc1\n\t"
        "global_load_dwordx4 %1, %5, off sc0 sc1\n\t"
        "global_load_dwordx4 %2, %6, off sc0 sc1\n\t"
        "global_load_dwordx4 %3, %7, off sc0 sc1\n\t"
        "s_waitcnt vmcnt(0)"
        : "=&v"(v0), "=&v"(v1), "=&v"(v2), "=&v"(v3)
        : "v"(a0), "v"(a0 + 4096), "v"(a0 + 8192), "v"(a0 + 12288)
        : "memory");
    f32x4 vv[4] = { v0, v1, v2, v3 };
#pragma unroll
    for (int i2 = 0; i2 < 4; ++i2) {
        int off = i2 * 4096 + threadIdx.x * 16;
        int row = off >> 10;
        int swz = off ^ ((row & 7) << 4);
        *(f32x4*)((char*)lds + swz) = vv[i2];
    }
}

__device__ __forceinline__ bf16x8 fragrd(const bf16_t* lds, int kt, int col, int quad) {
    int byte = (col * 1024 + kt * 64 + quad * 16) ^ ((col & 7) << 4);
    return *(const bf16x8*)((const char*)lds + byte);
}

// publish hv as bf16 packed u32 (even-col lanes store j, j+1) with
// device-coherent write-through (sc0 sc1) so cross-XCD readers see it.
__device__ __forceinline__ void publish(bf16_t* dst, int b, int j, float hv, int col) {
    bf16_t hb = (bf16_t)hv;
    unsigned short mb;
    __builtin_memcpy(&mb, &hb, 2);
    unsigned int pv = (unsigned int)__shfl_xor((int)(unsigned int)mb, 1);
    if ((col & 1) == 0) {
        unsigned int word = (unsigned int)mb | (pv << 16);
        void* addr = (char*)dst + (size_t)(b * DH_ + j) * 2;
        asm volatile("global_store_dword %0, %1, off sc0 sc1"
                     :: "v"(addr), "v"(word) : "memory");
    }
}

__device__ __forceinline__ void cell_step(
    const bf16_t* sh, const bf16_t* sx, bool dox,
    const bf16_t* __restrict__ Wx, const bf16_t* __restrict__ Wh,
    int j, int col, int quad, int grp,
    float br, float bz, float bin_, float bhn,
    float hold[4], bf16_t* hout, float* hist_t) {
    f32x4 aR = {}, aZ = {}, aIN = {}, aHN = {};
#pragma unroll
    for (int kt = 0; kt < 16; ++kt) {
        bf16x8 ah = fragrd(sh, kt, col, quad);
        bf16x8 w0 = *(const bf16x8*)(Wh + (size_t)j * DH_ + kt * 32 + quad * 8);
        bf16x8 w1 = *(const bf16x8*)(Wh + (size_t)(DH_ + j) * DH_ + kt * 32 + quad * 8);
        bf16x8 w2 = *(const bf16x8*)(Wh + (size_t)(2 * DH_ + j) * DH_ + kt * 32 + quad * 8);
        aR  = __builtin_amdgcn_mfma_f32_16x16x32_bf16(ah, w0, aR, 0, 0, 0);
        aZ  = __builtin_amdgcn_mfma_f32_16x16x32_bf16(ah, w1, aZ, 0, 0, 0);
        aHN = __builtin_amdgcn_mfma_f32_16x16x32_bf16(ah, w2, aHN, 0, 0, 0);
        if (dox) {
            bf16x8 ax = fragrd(sx, kt, col, quad);
            bf16x8 x0 = *(const bf16x8*)(Wx + (size_t)j * DH_ + kt * 32 + quad * 8);
            bf16x8 x1 = *(const bf16x8*)(Wx + (size_t)(DH_ + j) * DH_ + kt * 32 + quad * 8);
            bf16x8 x2 = *(const bf16x8*)(Wx + (size_t)(2 * DH_ + j) * DH_ + kt * 32 + quad * 8);
            aR  = __builtin_amdgcn_mfma_f32_16x16x32_bf16(ax, x0, aR, 0, 0, 0);
            aZ  = __builtin_amdgcn_mfma_f32_16x16x32_bf16(ax, x1, aZ, 0, 0, 0);
            aIN = __builtin_amdgcn_mfma_f32_16x16x32_bf16(ax, x2, aIN, 0, 0, 0);
        }
    }
#pragma unroll
    for (int i = 0; i < 4; ++i) {
        int b = grp * 16 + quad * 4 + i;
        float r = sigm(aR[i] + br);
        float z = sigm(aZ[i] + bz);
        float n = tanh_(aIN[i] + bin_ + r * (aHN[i] + bhn));
        float hv = (1.0f - z) * n + z * hold[i];
        hold[i] = hv;
        if (hist_t) hist_t[(size_t)b * DH_ + j] = hv;
        publish(hout, b, j, hv, col);
    }
}

__global__ __launch_bounds__(256) void dec_persist(
    const bf16_t* __restrict__ weff, const float* __restrict__ beff,
    const float* __restrict__ ov,
    const bf16_t* __restrict__ wdhh0, const float* __restrict__ dbhh0,
    const bf16_t* __restrict__ wdih1, const float* __restrict__ dbih1,
    const bf16_t* __restrict__ wdhh1, const float* __restrict__ dbhh1,
    const float* __restrict__ h0init, const float* __restrict__ h1init,
    bf16_t* hx00, bf16_t* hx01, bf16_t* hx10, bf16_t* hx11,
    float* __restrict__ hist, unsigned int* __restrict__ bar) {
    __shared__ bf16_t sh[16 * 512];   // holds h0 across phases
    __shared__ bf16_t sx[16 * 512];   // holds h1 across phases
    int jblk = blockIdx.x & 7;        // same jblk -> same XCD -> weights L2-resident
    int grp  = blockIdx.x >> 3;       // 16 batch-groups (partners cross-XCD)
    int tid = threadIdx.x, w = tid >> 6, lane = tid & 63;
    int col = lane & 15, quad = lane >> 4;
    int j = jblk * 64 + w * 16 + col;

    // per-lane folded biases
    float b0r = beff[j] + dbhh0[j],           b0z = beff[DH_ + j] + dbhh0[DH_ + j];
    float b0in = beff[2 * DH_ + j],           b0hn = dbhh0[2 * DH_ + j];
    float o0r = ov[j] + dbhh0[j],             o0z = ov[DH_ + j] + dbhh0[DH_ + j];
    float o0in = ov[2 * DH_ + j];
    float b1r = dbih1[j] + dbhh1[j],          b1z = dbih1[DH_ + j] + dbhh1[DH_ + j];
    float b1in = dbih1[2 * DH_ + j],          b1hn = dbhh1[2 * DH_ + j];

    // fp32 carries in registers; publish initial bf16 state to parity-1 bufs
    float hold0[4], hold1[4];
#pragma unroll
    for (int i = 0; i < 4; ++i) {
        int b = grp * 16 + quad * 4 + i;
        float v0 = h0init[(size_t)b * DH_ + j];
        float v1 = h1init[(size_t)b * DH_ + j];
        hold0[i] = v0; hold1[i] = v1;
        publish(hx01, b, j, v0, col);
        publish(hx11, b, j, v1, col);
    }
    gbar(bar + grp);   // phase 0: init state visible at coherence point

    int ph = 1;
    for (int t = 0; t < OSL_; ++t) {
        bf16_t* write0 = (t & 1) ? hx01 : hx00;
        bf16_t* read0  = (t & 1) ? hx00 : hx01;
        bf16_t* write1 = (t & 1) ? hx11 : hx10;
        bf16_t* read1  = (t & 1) ? hx10 : hx11;
        bool dox0 = (t > 0);

        // ---- phase A: cell0 (h0' from h0, x=Weff@h1) ----
        // sh already holds h0(t-1) (staged in phase B of t-1); stage h1 only.
        if (t == 0) stage16_x(sh, read0 + (size_t)grp * 16 * DH_);
        stage16_x(sx, read1 + (size_t)grp * 16 * DH_);
        __syncthreads();
        cell_step(sh, sx, dox0, weff, wdhh0, j, col, quad, grp,
                  dox0 ? b0r : o0r, dox0 ? b0z : o0z, dox0 ? b0in : o0in, b0hn,
                  hold0, write0, nullptr);
        gbar(bar + ph * 16 + grp); ph++;

        // ---- phase B: cell1 (h1' from h1 in sx, x=h0(t) staged to sh) ----
        stage16_x(sh, write0 + (size_t)grp * 16 * DH_);
        __syncthreads();
        cell_step(sx, sh, true, wdih1, wdhh1, j, col, quad, grp,
                  b1r, b1z, b1in, b1hn,
                  hold1, write1, hist + (size_t)t * B_ * DH_);
        if (t < OSL_ - 1) { gbar(bar + ph * 16 + grp); ph++; }
    }
}

// ------------------------------- FC head -----------------------------------
__global__ __launch_bounds__(256) void fc_all(
    const float* __restrict__ hist, const float* __restrict__ fcw,
    const float* __restrict__ fcb, float* __restrict__ out) {
    int t  = blockIdx.x >> 4;
    int b0 = (blockIdx.x & 15) * 16;
    int tid = threadIdx.x;
    int bl = tid >> 4, o = (tid >> 3) & 1, part = tid & 7;
    const float* hp = hist + ((size_t)t * B_ + b0 + bl) * DH_;
    const float* wp = fcw + o * DH_;
    float s = 0.0f;
    for (int k = part * 64; k < part * 64 + 64; k += 4) {
        f32x4 hv = *(const f32x4*)(hp + k);
        f32x4 wv = *(const f32x4*)(wp + k);
        s += hv[0] * wv[0] + hv[1] * wv[1] + hv[2] * wv[2] + hv[3] * wv[3];
    }
    s += __shfl_down(s, 4); s += __shfl_down(s, 2); s += __shfl_down(s, 1);
    if (part == 0) out[(size_t)(b0 + bl) * (OSL_ * 2) + t * 2 + o] = s + fcb[o];
}

// ------------------------------ launcher -----------------------------------

#define OFF_WIH0E 0ull
#define OFF_WHH0E 196608ull
#define OFF_WIH1E 983040ull
#define OFF_WHH1E 2555904ull
#define OFF_WDHH0 3342336ull
#define OFF_WDIH1 4915200ull
#define OFF_WDHH1 6488064ull
#define OFF_WEFF  8060928ull
#define OFF_BEFF  9633792ull
#define OFF_BAR   9641984ull    // 41 phases x 16 groups (zeroed 1024 u32)
#define OFF_OV    9658368ull
#define OFF_H0A   9682944ull
#define OFF_H0B   10207232ull   // hx00 (256 KB) + hx01 (256 KB)
#define OFF_H1A   10731520ull
#define OFF_H1B   11255808ull   // hx10 (256 KB) + hx11 (256 KB)
#define OFF_HST   11780096ull
#define OFF_HIST  12304384ull
#define OFF_XCAT  22790144ull
#define OFF_GI    157007872ull

extern "C" void kernel_launch(void* const* d_in, const int* in_sizes, int n_in,
                              void* d_out, int out_size, void* d_ws, size_t ws_size,
                              hipStream_t stream) {
    const float* x      = (const float*)d_in[0];
    const float* st     = (const float*)d_in[1];
    const float* eWih0  = (const float*)d_in[2];
    const float* eWhh0  = (const float*)d_in[3];
    const float* ebih0  = (const float*)d_in[4];
    const float* ebhh0  = (const float*)d_in[5];
    const float* eWih1  = (const float*)d_in[6];
    const float* eWhh1  = (const float*)d_in[7];
    const float* ebih1  = (const float*)d_in[8];
    const float* ebhh1  = (const float*)d_in[9];
    const float* dWih0  = (const float*)d_in[10];
    const float* dWhh0  = (const float*)d_in[11];
    const float* dbih0  = (const float*)d_in[12];
    const float* dbhh0  = (const float*)d_in[13];
    const float* dWih1  = (const float*)d_in[14];
    const float* dWhh1  = (const float*)d_in[15];
    const float* dbih1  = (const float*)d_in[16];
    const float* dbhh1  = (const float*)d_in[17];
    const float* fcW    = (const float*)d_in[18];
    const float* fcb    = (const float*)d_in[19];

    char* ws = (char*)d_ws;
    bf16_t* wih0e = (bf16_t*)(ws + OFF_WIH0E);
    bf16_t* whh0e = (bf16_t*)(ws + OFF_WHH0E);
    bf16_t* wih1e = (bf16_t*)(ws + OFF_WIH1E);
    bf16_t* whh1e = (bf16_t*)(ws + OFF_WHH1E);
    bf16_t* wdhh0 = (bf16_t*)(ws + OFF_WDHH0);
    bf16_t* wdih1 = (bf16_t*)(ws + OFF_WDIH1);
    bf16_t* wdhh1 = (bf16_t*)(ws + OFF_WDHH1);
    bf16_t* weff  = (bf16_t*)(ws + OFF_WEFF);
    float*  beff  = (float*)(ws + OFF_BEFF);
    unsigned int* bar = (unsigned int*)(ws + OFF_BAR);
    float*  ovp   = (float*)(ws + OFF_OV);
    float*  h0init = (float*)(ws + OFF_H0A);
    float*  h1init = (float*)(ws + OFF_H1A);
    bf16_t* hx00  = (bf16_t*)(ws + OFF_H0B);
    bf16_t* hx01  = (bf16_t*)(ws + OFF_H0B + 262144ull);
    bf16_t* hx10  = (bf16_t*)(ws + OFF_H1B);
    bf16_t* hx11  = (bf16_t*)(ws + OFF_H1B + 262144ull);
    float*  hstate = (float*)(ws + OFF_HST);
    float*  hist  = (float*)(ws + OFF_HIST);
    bf16_t* xcat  = (bf16_t*)(ws + OFF_XCAT);
    bf16_t* gi    = (bf16_t*)(ws + OFF_GI);

    int Tc = 512;
    while (Tc > 8 && OFF_GI + (unsigned long long)Tc * 786432ull > (unsigned long long)ws_size)
        Tc >>= 1;
    int nch = T_ / Tc;

    prep_all<<<dim3(3072, 8), 256, 0, stream>>>(
        eWih0, eWhh0, eWih1, eWhh1, dWhh0, dWih1, dWhh1,
        wih0e, whh0e, wih1e, whh1e, wdhh0, wdih1, wdhh1,
        dWih0, fcW, fcb, dbih0, st, weff, beff, ovp, bar);

    for (int c = 0; c < nch; c++) {
        gemm_gi<<<dim3(Tc * 2, 12), 256, 0, stream>>>(x, nullptr, wih0e, gi, c * Tc, 64);
        gru_scan<<<32, 512, 0, stream>>>(gi, c * Tc, Tc, whh0e, ebih0, ebhh0, hstate, xcat, h0init);
    }
    for (int c = 0; c < nch; c++) {
        gemm_gi<<<dim3(Tc * 2, 12), 256, 0, stream>>>(nullptr, xcat, wih1e, gi, c * Tc, 512);
        gru_scan<<<32, 512, 0, stream>>>(gi, c * Tc, Tc, whh1e, ebih1, ebhh1, hstate, nullptr, h1init);
    }

    dec_persist<<<128, 256, 0, stream>>>(weff, beff, ovp,
                                         wdhh0, dbhh0, wdih1, dbih1, wdhh1, dbhh1,
                                         h0init, h1init,
                                         hx00, hx01, hx10, hx11,
                                         hist, bar);

    fc_all<<<OSL_ * 16, 256, 0, stream>>>(hist, fcW, fcb, (float*)d_out);
}

// Round 11
// 4610.567 us; speedup vs baseline: 1.7122x; 1.0045x over previous
//
#include <hip/hip_runtime.h>
#include <hip/hip_bf16.h>
#include <stdint.h>
#include <stddef.h>

// ---------------------------------------------------------------------------
// Seq2Seq BiGRU: B=256 T=512 F=64 H=256 (2-layer bidir encoder),
// decoder DH=512 2-layer, OSL=20, OUT=2.
//
// Round-13 structure (= r10 + register-resident decoder weights):
//  - Diagnosis chain: r4 (traffic -3.5x, time flat) and r10 (FETCH 491->46MB,
//    time flat) prove the ~17us/phase decoder toll is NOT bandwidth. It is
//    L2 TRANSACTION REDUNDANCY: per phase each of 16 WGs/XCD issues 6144
//    scattered 64B line-requests for the same weights -> ~98K transactions
//    /XCD/phase ~ 25-33K cycles ~ the invariant toll. Mapping cannot fix it
//    (unique-lines x redundancy is mapping-invariant); only residency can.
//  - dec_persist v4: 256 WGs x 512 thr = 16 j-slices(32j) x 16 groups.
//    All 4 weight matrices REGISTER-RESIDENT: 24 (mat,gate,jhalf) tiles per
//    WG, 3 per wave (192 VGPR), loaded once in prologue. Full-K per wave ->
//    no reduce; 12KB LDS acc-exchange; waves 0/1 do gate epilogue + publish
//    (f32 carries there). Per-phase weight loads: ZERO.
//  - h exchange/barrier byte-identical to r10 (sc0 sc1 staging, RELAXED RMW,
//    bounded spin -> fails visibly, never hangs); barrier counts to 16.
//  - __launch_bounds__(512,2): guarantees 2 waves/SIMD residency (spills
//    rather than breaking co-residency). 256 WGs <= 256 CUs.
//  - prep/gemm/scan/fc byte-identical to r10 (4631us, passed).
// ---------------------------------------------------------------------------

typedef __bf16 bf16_t;
typedef bf16_t bf16x8 __attribute__((ext_vector_type(8)));
typedef float  f32x4  __attribute__((ext_vector_type(4)));

#define B_   256
#define T_   512
#define F_   64
#define H_   256
#define G_   768      // 3*H
#define DH_  512
#define DG_  1536     // 3*DH
#define OSL_ 20

__device__ __forceinline__ float sigm(float x) {
    float e = __builtin_amdgcn_exp2f(-1.442695040888963f * x);
    return __builtin_amdgcn_rcpf(1.0f + e);
}
__device__ __forceinline__ float tanh_(float x) {
    float e = __builtin_amdgcn_exp2f(-2.885390081777927f * x);
    return __builtin_amdgcn_rcpf(1.0f + e) * 2.0f - 1.0f;
}

__device__ __forceinline__ bf16x8 load_f32x8_as_bf16(const float* p) {
    f32x4 u = *(const f32x4*)p;
    f32x4 v = *(const f32x4*)(p + 4);
    bf16x8 r;
    r[0]=(bf16_t)u[0]; r[1]=(bf16_t)u[1]; r[2]=(bf16_t)u[2]; r[3]=(bf16_t)u[3];
    r[4]=(bf16_t)v[0]; r[5]=(bf16_t)v[1]; r[6]=(bf16_t)v[2]; r[7]=(bf16_t)v[3];
    return r;
}

// ------------------------------- fused prep --------------------------------
__global__ __launch_bounds__(256) void prep_all(
    const float* __restrict__ s0, const float* __restrict__ s1,
    const float* __restrict__ s2, const float* __restrict__ s3,
    const float* __restrict__ s4, const float* __restrict__ s5,
    const float* __restrict__ s6,
    bf16_t* __restrict__ d0, bf16_t* __restrict__ d1, bf16_t* __restrict__ d2,
    bf16_t* __restrict__ d3, bf16_t* __restrict__ d4, bf16_t* __restrict__ d5,
    bf16_t* __restrict__ d6,
    const float* __restrict__ wih0d, const float* __restrict__ fcw,
    const float* __restrict__ fcb, const float* __restrict__ bih0d,
    const float* __restrict__ st, bf16_t* __restrict__ weff,
    float* __restrict__ beff, float* __restrict__ ov,
    unsigned int* __restrict__ bar) {
    int i = blockIdx.x * 256 + threadIdx.x;
    switch (blockIdx.y) {
      case 0: if (i < 2*G_*F_)  d0[i] = (bf16_t)s0[i]; break;
      case 1: if (i < 2*G_*H_)  d1[i] = (bf16_t)s1[i]; break;
      case 2: if (i < 2*G_*DH_) d2[i] = (bf16_t)s2[i]; break;
      case 3: if (i < 2*G_*H_)  d3[i] = (bf16_t)s3[i]; break;
      case 4: if (i < DG_*DH_)  d4[i] = (bf16_t)s4[i]; break;
      case 5: if (i < DG_*DH_)  d5[i] = (bf16_t)s5[i]; break;
      case 6: if (i < DG_*DH_)  d6[i] = (bf16_t)s6[i]; break;
      default: {
        if (i < 1024) bar[i] = 0u;
        if (i < DG_*DH_) {
          int g = i >> 9, k = i & 511;
          float a0 = wih0d[g * 2], a1 = wih0d[g * 2 + 1];
          weff[i] = (bf16_t)(a0 * fcw[k] + a1 * fcw[DH_ + k]);
          if (k == 0) {
            beff[g] = a0 * fcb[0] + a1 * fcb[1] + bih0d[g];
            ov[g]   = a0 * st[0]  + a1 * st[1]  + bih0d[g];
          }
        }
      } break;
    }
}

// --------------------------- gi chunk GEMM ---------------------------------
__global__ __launch_bounds__(256) void gemm_gi(
    const float* __restrict__ x, const bf16_t* __restrict__ xcat,
    const bf16_t* __restrict__ Bt, bf16_t* __restrict__ gi, int t0, int K) {
    __shared__ bf16_t As[128 * 64];
    __shared__ bf16_t Bs[128 * 64];
    int m0 = blockIdx.x * 128, n0 = blockIdx.y * 128;
    int tid = threadIdx.x;
    int lane = tid & 63, w = tid >> 6;
    int col = lane & 15, quad = lane >> 4;
    int qm = (w >> 1) * 64, qn = (w & 1) * 64;

    int tl = m0 >> 8;              // local chunk time (constant per block)
    int bbase = m0 & 255;          // batch base (0 or 128)
    int t_real = t0 + tl;
    if (n0 >= 768) t_real = (T_ - 1) - t_real;

    f32x4 acc[4][4] = {};
    for (int k0 = 0; k0 < K; k0 += 64) {
        __syncthreads();
#pragma unroll
        for (int i = 0; i < 4; i++) {
            int c = i * 256 + tid;
            int m = c >> 3, kc = c & 7;
            int kcs = kc ^ (m & 7);   // XOR swizzle at source
            bf16x8 av;
            if (K == 64) {
                av = load_f32x8_as_bf16(x + ((size_t)(bbase + m) * T_ + t_real) * F_ + kcs * 8);
            } else {
                av = *(const bf16x8*)(xcat + ((size_t)t_real * B_ + bbase + m) * DH_ + k0 + kcs * 8);
            }
            *(bf16x8*)(&As[c * 8]) = av;
            *(bf16x8*)(&Bs[c * 8]) = *(const bf16x8*)(Bt + (size_t)(n0 + m) * K + k0 + kcs * 8);
        }
        __syncthreads();
#pragma unroll
        for (int kt = 0; kt < 2; kt++) {
            bf16x8 a[4], b[4];
#pragma unroll
            for (int mt = 0; mt < 4; mt++) {
                int r = qm + mt * 16 + col;
                a[mt] = *(const bf16x8*)(&As[(r * 8 + ((kt * 4 + quad) ^ (r & 7))) * 8]);
                int rn = qn + mt * 16 + col;
                b[mt] = *(const bf16x8*)(&Bs[(rn * 8 + ((kt * 4 + quad) ^ (rn & 7))) * 8]);
            }
#pragma unroll
            for (int mt = 0; mt < 4; mt++)
#pragma unroll
                for (int nt = 0; nt < 4; nt++)
                    acc[mt][nt] = __builtin_amdgcn_mfma_f32_16x16x32_bf16(a[mt], b[nt], acc[mt][nt], 0, 0, 0);
        }
    }
#pragma unroll
    for (int mt = 0; mt < 4; mt++)
#pragma unroll
        for (int nt = 0; nt < 4; nt++)
#pragma unroll
            for (int i = 0; i < 4; i++) {
                int row = m0 + qm + mt * 16 + quad * 4 + i;
                int cg  = n0 + qn + nt * 16 + col;
                gi[(size_t)row * DG_ + cg] = (bf16_t)acc[mt][nt][i];
            }
}

// ------------------------------ GRU scan (chunked) -------------------------
__global__ __launch_bounds__(512) void gru_scan(
    const bf16_t* __restrict__ gi, int t0, int tc,
    const bf16_t* __restrict__ whh,
    const float* __restrict__ bih, const float* __restrict__ bhh,
    float* __restrict__ hstate, bf16_t* __restrict__ y, float* __restrict__ hT) {
    __shared__ bf16_t gi_lds[16 * 768];       // [b][768]
    __shared__ bf16_t h_lds[2 * 16 * 264];    // [par][b][256+8 pad]

    int dir = blockIdx.x >> 4;
    int b0  = (blockIdx.x & 15) * 16;
    int tid = threadIdx.x;
    int w = tid >> 6, lane = tid & 63, col = lane & 15, quad = lane >> 4;

    bf16x8 wf[3][2][8];
    const bf16_t* wbase = whh + (size_t)dir * G_ * H_;
#pragma unroll
    for (int g = 0; g < 3; g++)
#pragma unroll
        for (int nt = 0; nt < 2; nt++) {
            int row = g * 256 + w * 32 + nt * 16 + col;
#pragma unroll
            for (int kt = 0; kt < 8; kt++)
                wf[g][nt][kt] = *(const bf16x8*)(wbase + (size_t)row * H_ + kt * 32 + quad * 8);
        }
    float brz[2][2], bin_[2], bhn[2];
#pragma unroll
    for (int nt = 0; nt < 2; nt++) {
        int j = w * 32 + nt * 16 + col;
        brz[0][nt] = bih[dir * G_ + j] + bhh[dir * G_ + j];
        brz[1][nt] = bih[dir * G_ + 256 + j] + bhh[dir * G_ + 256 + j];
        bin_[nt]   = bih[dir * G_ + 512 + j];
        bhn[nt]    = bhh[dir * G_ + 512 + j];
    }
    int bb[3], oo[3];
#pragma unroll
    for (int it = 0; it < 3; it++) {
        int c = it * 512 + tid;
        bb[it] = c / 96;
        oo[it] = (c % 96) * 8;
    }
    float hold[2][4];
#pragma unroll
    for (int nt = 0; nt < 2; nt++)
#pragma unroll
        for (int i = 0; i < 4; i++) {
            int j = w * 32 + nt * 16 + col;
            hold[nt][i] = t0 ? hstate[dir * 65536 + (b0 + quad * 4 + i) * 256 + j] : 0.0f;
        }
    for (int i = tid; i < 16 * 264; i += 512) {
        int b = i / 264, j = i % 264;
        float v = (t0 && j < 256) ? hstate[dir * 65536 + (b0 + b) * 256 + j] : 0.0f;
        h_lds[i] = (bf16_t)v;
    }
#pragma unroll
    for (int it = 0; it < 3; it++) {
        int c = it * 512 + tid;
        *(bf16x8*)(&gi_lds[c * 8]) =
            *(const bf16x8*)(gi + ((size_t)0 * B_ + b0 + bb[it]) * DG_ + dir * G_ + oo[it]);
    }
    __syncthreads();

    for (int s = 0; s < tc; s++) {
        int par = s & 1;
        int t = t0 + s;
        int sn = (s + 1 < tc) ? (s + 1) : s;

        bf16x8 pg[3];
#pragma unroll
        for (int it = 0; it < 3; it++)
            pg[it] = *(const bf16x8*)(gi + ((size_t)sn * B_ + b0 + bb[it]) * DG_ + dir * G_ + oo[it]);

        f32x4 acc[3][2] = {};
        const bf16_t* hcur = &h_lds[par * 4224];
#pragma unroll
        for (int kt = 0; kt < 8; kt++) {
            bf16x8 af = *(const bf16x8*)(hcur + col * 264 + kt * 32 + quad * 8);
#pragma unroll
            for (int g = 0; g < 3; g++)
#pragma unroll
                for (int nt = 0; nt < 2; nt++)
                    acc[g][nt] = __builtin_amdgcn_mfma_f32_16x16x32_bf16(af, wf[g][nt][kt], acc[g][nt], 0, 0, 0);
        }

        bf16_t* hnext = &h_lds[(par ^ 1) * 4224];
        int tp = dir ? (T_ - 1 - t) : t;
#pragma unroll
        for (int nt = 0; nt < 2; nt++) {
            int j = w * 32 + nt * 16 + col;
#pragma unroll
            for (int i = 0; i < 4; i++) {
                int b = quad * 4 + i;
                float gr = acc[0][nt][i] + (float)gi_lds[b * 768 + j]       + brz[0][nt];
                float gz = acc[1][nt][i] + (float)gi_lds[b * 768 + 256 + j] + brz[1][nt];
                float gn = (float)gi_lds[b * 768 + 512 + j] + bin_[nt];
                float r = sigm(gr), z = sigm(gz);
                float n = tanh_(gn + r * (acc[2][nt][i] + bhn[nt]));
                float hv = (1.0f - z) * n + z * hold[nt][i];
                hold[nt][i] = hv;
                hnext[b * 264 + j] = (bf16_t)hv;
                if (y) y[((size_t)tp * B_ + b0 + b) * DH_ + dir * H_ + j] = (bf16_t)hv;
                if (t == T_ - 1) hT[(size_t)(b0 + b) * DH_ + dir * H_ + j] = hv;
            }
        }
        __syncthreads();
#pragma unroll
        for (int it = 0; it < 3; it++)
            *(bf16x8*)(&gi_lds[(it * 512 + tid) * 8]) = pg[it];
        __syncthreads();
    }
#pragma unroll
    for (int nt = 0; nt < 2; nt++)
#pragma unroll
        for (int i = 0; i < 4; i++) {
            int j = w * 32 + nt * 16 + col;
            hstate[dir * 65536 + (b0 + quad * 4 + i) * 256 + j] = hold[nt][i];
        }
}

// ---------------- persistent decoder, register-resident weights ------------
// 256 WGs x 512 thr = 16 j-slices (s = blockIdx&15, 32 j) x 16 groups
// (g = blockIdx>>4, 16 batch rows). 24 (mat,gate,jhalf) weight tiles per WG,
// 3 per wave (192 VGPR), loaded once. Full-K per wave -> no reduce.
// Waves 0/1 (jh = w) do the gate epilogue + publish; f32 carries live there.
// h exchange + barrier identical to r10 (sc0 sc1, RELAXED RMW, bounded spin).

__device__ __forceinline__ void gbar16(unsigned int* cnt) {
    __syncthreads();   // drains vmcnt -> publishes at coherence point
    if (threadIdx.x == 0) {
        __hip_atomic_fetch_add(cnt, 1u, __ATOMIC_RELAXED, __HIP_MEMORY_SCOPE_AGENT);
        unsigned int s = 0;
        while (__hip_atomic_load(cnt, __ATOMIC_RELAXED, __HIP_MEMORY_SCOPE_AGENT) < 16u
               && ++s < (1u << 20))
            __builtin_amdgcn_s_sleep(1);
    }
    __syncthreads();
}

// stage 16 rows x 512 bf16 (16 KB) with 512 threads: 2 x 16B per thread.
__device__ __forceinline__ void stage16v(bf16_t* lds, const bf16_t* src) {
    f32x4 v0, v1;
    const char* a0 = (const char*)src + threadIdx.x * 16;
    asm volatile(
        "global_load_dwordx4 %0, %2, off sc0 sc1\n\t"
        "global_load_dwordx4 %1, %3, off sc0 sc1\n\t"
        "s_waitcnt vmcnt(0)"
        : "=&v"(v0), "=&v"(v1)
        : "v"(a0), "v"(a0 + 8192)
        : "memory");
    {
        int off = threadIdx.x * 16;
        int row = off >> 10;
        int swz = off ^ ((row & 7) << 4);
        *(f32x4*)((char*)lds + swz) = v0;
    }
    {
        int off = 8192 + threadIdx.x * 16;
        int row = off >> 10;
        int swz = off ^ ((row & 7) << 4);
        *(f32x4*)((char*)lds + swz) = v1;
    }
}

__device__ __forceinline__ bf16x8 fragrd(const bf16_t* lds, int kt, int col, int quad) {
    int byte = (col * 1024 + kt * 64 + quad * 16) ^ ((col & 7) << 4);
    return *(const bf16x8*)((const char*)lds + byte);
}

// publish hv as bf16 packed u32 (even-col lanes store j, j+1), device-coherent
__device__ __forceinline__ void publish(bf16_t* dst, int b, int j, float hv, int col) {
    bf16_t hb = (bf16_t)hv;
    unsigned short mb;
    __builtin_memcpy(&mb, &hb, 2);
    unsigned int pv = (unsigned int)__shfl_xor((int)(unsigned int)mb, 1);
    if ((col & 1) == 0) {
        unsigned int word = (unsigned int)mb | (pv << 16);
        void* addr = (char*)dst + (size_t)(b * DH_ + j) * 2;
        asm volatile("global_store_dword %0, %1, off sc0 sc1"
                     :: "v"(addr), "v"(word) : "memory");
    }
}

__global__ __launch_bounds__(512, 2) void dec_persist(
    const bf16_t* __restrict__ weff, const float* __restrict__ beff,
    const float* __restrict__ ov,
    const bf16_t* __restrict__ wdhh0, const float* __restrict__ dbhh0,
    const bf16_t* __restrict__ wdih1, const float* __restrict__ dbih1,
    const bf16_t* __restrict__ wdhh1, const float* __restrict__ dbhh1,
    const float* __restrict__ h0init, const float* __restrict__ h1init,
    bf16_t* hx00, bf16_t* hx01, bf16_t* hx10, bf16_t* hx11,
    float* __restrict__ hist, unsigned int* __restrict__ bar) {
    __shared__ bf16_t sh[16 * 512];   // h0 (persists A<-B)
    __shared__ bf16_t sx[16 * 512];   // h1
    __shared__ f32x4 exch[12 * 64];   // acc exchange (12 tiles x 64 lanes)

    int s  = blockIdx.x & 15;         // j-slice
    int g  = blockIdx.x >> 4;         // batch group
    int js = s * 32;
    int tid = threadIdx.x, w = tid >> 6, lane = tid & 63;
    int col = lane & 15, quad = lane >> 4;

    // ---- prologue: load 3 owned weight tiles into registers ----
    const bf16_t* mats[4] = { wdhh0, weff, wdih1, wdhh1 };
    bf16x8 frg[3][16];
    int tmat[3], texch[3];
#pragma unroll
    for (int sl = 0; sl < 3; ++sl) {
        int idx = w + sl * 8;         // 0..23
        int m = idx / 6, rem = idx - m * 6;
        int gate = rem >> 1, jh = rem & 1;
        tmat[sl] = m;
        texch[sl] = (m & 1) * 6 + rem;   // slot within phase: 0..11
        int row = gate * 512 + js + jh * 16 + col;
        const bf16_t* M = mats[m];
#pragma unroll
        for (int kt = 0; kt < 16; ++kt)
            frg[sl][kt] = *(const bf16x8*)(M + (size_t)row * DH_ + kt * 32 + quad * 8);
    }

    // epilogue-lane constants (valid for w<2; harmless elsewhere)
    int je = js + (w & 1) * 16 + col;
    float b0r = beff[je] + dbhh0[je],        b0z = beff[DH_ + je] + dbhh0[DH_ + je];
    float b0in = beff[2 * DH_ + je],         b0hn = dbhh0[2 * DH_ + je];
    float o0r = ov[je] + dbhh0[je],          o0z = ov[DH_ + je] + dbhh0[DH_ + je];
    float o0in = ov[2 * DH_ + je];
    float b1r = dbih1[je] + dbhh1[je],       b1z = dbih1[DH_ + je] + dbhh1[DH_ + je];
    float b1in = dbih1[2 * DH_ + je],        b1hn = dbhh1[2 * DH_ + je];

    // init: epilogue waves publish initial state, keep f32 carries
    float hold0[4], hold1[4];
    if (w < 2) {
#pragma unroll
        for (int i = 0; i < 4; ++i) {
            int b = g * 16 + quad * 4 + i;
            float v0 = h0init[(size_t)b * DH_ + je];
            float v1 = h1init[(size_t)b * DH_ + je];
            hold0[i] = v0; hold1[i] = v1;
            publish(hx01, b, je, v0, col);
            publish(hx11, b, je, v1, col);
        }
    }
    gbar16(bar + g);   // phase 0: init visible

    int ph = 1;
    for (int t = 0; t < OSL_; ++t) {
        bf16_t* write0 = (t & 1) ? hx01 : hx00;
        bf16_t* read0  = (t & 1) ? hx00 : hx01;
        bf16_t* write1 = (t & 1) ? hx11 : hx10;
        bf16_t* read1  = (t & 1) ? hx10 : hx11;
        bool dox = (t > 0);

        // ---------------- phase A: cell0 ----------------
        // sh holds h0(t-1) (staged in phase B of t-1); stage h1(t-1) only.
        if (t == 0) stage16v(sh, read0 + (size_t)g * 16 * DH_);
        stage16v(sx, read1 + (size_t)g * 16 * DH_);
        __syncthreads();

        {
            f32x4 acc[3] = {};
#pragma unroll
            for (int sl = 0; sl < 3; ++sl) {
                if (tmat[sl] == 0) {            // Whh0 x h0(t-1)
#pragma unroll
                    for (int kt = 0; kt < 16; ++kt)
                        acc[sl] = __builtin_amdgcn_mfma_f32_16x16x32_bf16(
                            fragrd(sh, kt, col, quad), frg[sl][kt], acc[sl], 0, 0, 0);
                } else if (tmat[sl] == 1 && dox) { // Weff x h1(t-1)
#pragma unroll
                    for (int kt = 0; kt < 16; ++kt)
                        acc[sl] = __builtin_amdgcn_mfma_f32_16x16x32_bf16(
                            fragrd(sx, kt, col, quad), frg[sl][kt], acc[sl], 0, 0, 0);
                }
            }
#pragma unroll
            for (int sl = 0; sl < 3; ++sl)
                if (tmat[sl] <= 1) exch[texch[sl] * 64 + lane] = acc[sl];
        }
        __syncthreads();

        if (w < 2) {
            int jh = w;
            f32x4 aR0 = exch[(0 + jh) * 64 + lane];
            f32x4 aZ0 = exch[(2 + jh) * 64 + lane];
            f32x4 aN0 = exch[(4 + jh) * 64 + lane];
            f32x4 aR1 = {}, aZ1 = {}, aN1 = {};
            if (dox) {
                aR1 = exch[(6 + jh) * 64 + lane];
                aZ1 = exch[(8 + jh) * 64 + lane];
                aN1 = exch[(10 + jh) * 64 + lane];
            }
#pragma unroll
            for (int i = 0; i < 4; ++i) {
                int b = g * 16 + quad * 4 + i;
                float r = sigm(aR0[i] + aR1[i] + (dox ? b0r : o0r));
                float z = sigm(aZ0[i] + aZ1[i] + (dox ? b0z : o0z));
                float gin = dox ? (aN1[i] + b0in) : o0in;
                float n = tanh_(gin + r * (aN0[i] + b0hn));
                float hv = (1.0f - z) * n + z * hold0[i];
                hold0[i] = hv;
                publish(write0, b, je, hv, col);
            }
        }
        gbar16(bar + ph * 16 + g); ph++;

        // ---------------- phase B: cell1 ----------------
        stage16v(sh, write0 + (size_t)g * 16 * DH_);   // h0(t)
        __syncthreads();

        {
            f32x4 acc[3] = {};
#pragma unroll
            for (int sl = 0; sl < 3; ++sl) {
                if (tmat[sl] == 2) {            // Wih1 x h0(t)
#pragma unroll
                    for (int kt = 0; kt < 16; ++kt)
                        acc[sl] = __builtin_amdgcn_mfma_f32_16x16x32_bf16(
                            fragrd(sh, kt, col, quad), frg[sl][kt], acc[sl], 0, 0, 0);
                } else if (tmat[sl] == 3) {     // Whh1 x h1(t-1)
#pragma unroll
                    for (int kt = 0; kt < 16; ++kt)
                        acc[sl] = __builtin_amdgcn_mfma_f32_16x16x32_bf16(
                            fragrd(sx, kt, col, quad), frg[sl][kt], acc[sl], 0, 0, 0);
                }
            }
#pragma unroll
            for (int sl = 0; sl < 3; ++sl)
                if (tmat[sl] >= 2) exch[texch[sl] * 64 + lane] = acc[sl];
        }
        __syncthreads();

        if (w < 2) {
            int jh = w;
            f32x4 giR = exch[(0 + jh) * 64 + lane];   // Wih1 (m&1==0)
            f32x4 giZ = exch[(2 + jh) * 64 + lane];
            f32x4 giN = exch[(4 + jh) * 64 + lane];
            f32x4 ghR = exch[(6 + jh) * 64 + lane];   // Whh1 (m&1==1)
            f32x4 ghZ = exch[(8 + jh) * 64 + lane];
            f32x4 ghN = exch[(10 + jh) * 64 + lane];
            float* hist_t = hist + (size_t)t * B_ * DH_;
#pragma unroll
            for (int i = 0; i < 4; ++i) {
                int b = g * 16 + quad * 4 + i;
                float r = sigm(giR[i] + ghR[i] + b1r);
                float z = sigm(giZ[i] + ghZ[i] + b1z);
                float n = tanh_(giN[i] + b1in + r * (ghN[i] + b1hn));
                float hv = (1.0f - z) * n + z * hold1[i];
                hold1[i] = hv;
                hist_t[(size_t)b * DH_ + je] = hv;
                publish(write1, b, je, hv, col);
            }
        }
        if (t < OSL_ - 1) { gbar16(bar + ph * 16 + g); ph++; }
    }
}

// ------------------------------- FC head -----------------------------------
__global__ __launch_bounds__(256) void fc_all(
    const float* __restrict__ hist, const float* __restrict__ fcw,
    const float* __restrict__ fcb, float* __restrict__ out) {
    int t  = blockIdx.x >> 4;
    int b0 = (blockIdx.x & 15) * 16;
    int tid = threadIdx.x;
    int bl = tid >> 4, o = (tid >> 3) & 1, part = tid & 7;
    const float* hp = hist + ((size_t)t * B_ + b0 + bl) * DH_;
    const float* wp = fcw + o * DH_;
    float s = 0.0f;
    for (int k = part * 64; k < part * 64 + 64; k += 4) {
        f32x4 hv = *(const f32x4*)(hp + k);
        f32x4 wv = *(const f32x4*)(wp + k);
        s += hv[0] * wv[0] + hv[1] * wv[1] + hv[2] * wv[2] + hv[3] * wv[3];
    }
    s += __shfl_down(s, 4); s += __shfl_down(s, 2); s += __shfl_down(s, 1);
    if (part == 0) out[(size_t)(b0 + bl) * (OSL_ * 2) + t * 2 + o] = s + fcb[o];
}

// ------------------------------ launcher -----------------------------------

#define OFF_WIH0E 0ull
#define OFF_WHH0E 196608ull
#define OFF_WIH1E 983040ull
#define OFF_WHH1E 2555904ull
#define OFF_WDHH0 3342336ull
#define OFF_WDIH1 4915200ull
#define OFF_WDHH1 6488064ull
#define OFF_WEFF  8060928ull
#define OFF_BEFF  9633792ull
#define OFF_BAR   9641984ull    // 41 phases x 16 groups (zeroed 1024 u32)
#define OFF_OV    9658368ull
#define OFF_H0A   9682944ull
#define OFF_H0B   10207232ull   // hx00 (256 KB) + hx01 (256 KB)
#define OFF_H1A   10731520ull
#define OFF_H1B   11255808ull   // hx10 (256 KB) + hx11 (256 KB)
#define OFF_HST   11780096ull
#define OFF_HIST  12304384ull
#define OFF_XCAT  22790144ull
#define OFF_GI    157007872ull

extern "C" void kernel_launch(void* const* d_in, const int* in_sizes, int n_in,
                              void* d_out, int out_size, void* d_ws, size_t ws_size,
                              hipStream_t stream) {
    const float* x      = (const float*)d_in[0];
    const float* st     = (const float*)d_in[1];
    const float* eWih0  = (const float*)d_in[2];
    const float* eWhh0  = (const float*)d_in[3];
    const float* ebih0  = (const float*)d_in[4];
    const float* ebhh0  = (const float*)d_in[5];
    const float* eWih1  = (const float*)d_in[6];
    const float* eWhh1  = (const float*)d_in[7];
    const float* ebih1  = (const float*)d_in[8];
    const float* ebhh1  = (const float*)d_in[9];
    const float* dWih0  = (const float*)d_in[10];
    const float* dWhh0  = (const float*)d_in[11];
    const float* dbih0  = (const float*)d_in[12];
    const float* dbhh0  = (const float*)d_in[13];
    const float* dWih1  = (const float*)d_in[14];
    const float* dWhh1  = (const float*)d_in[15];
    const float* dbih1  = (const float*)d_in[16];
    const float* dbhh1  = (const float*)d_in[17];
    const float* fcW    = (const float*)d_in[18];
    const float* fcb    = (const float*)d_in[19];

    char* ws = (char*)d_ws;
    bf16_t* wih0e = (bf16_t*)(ws + OFF_WIH0E);
    bf16_t* whh0e = (bf16_t*)(ws + OFF_WHH0E);
    bf16_t* wih1e = (bf16_t*)(ws + OFF_WIH1E);
    bf16_t* whh1e = (bf16_t*)(ws + OFF_WHH1E);
    bf16_t* wdhh0 = (bf16_t*)(ws + OFF_WDHH0);
    bf16_t* wdih1 = (bf16_t*)(ws + OFF_WDIH1);
    bf16_t* wdhh1 = (bf16_t*)(ws + OFF_WDHH1);
    bf16_t* weff  = (bf16_t*)(ws + OFF_WEFF);
    float*  beff  = (float*)(ws + OFF_BEFF);
    unsigned int* bar = (unsigned int*)(ws + OFF_BAR);
    float*  ovp   = (float*)(ws + OFF_OV);
    float*  h0init = (float*)(ws + OFF_H0A);
    float*  h1init = (float*)(ws + OFF_H1A);
    bf16_t* hx00  = (bf16_t*)(ws + OFF_H0B);
    bf16_t* hx01  = (bf16_t*)(ws + OFF_H0B + 262144ull);
    bf16_t* hx10  = (bf16_t*)(ws + OFF_H1B);
    bf16_t* hx11  = (bf16_t*)(ws + OFF_H1B + 262144ull);
    float*  hstate = (float*)(ws + OFF_HST);
    float*  hist  = (float*)(ws + OFF_HIST);
    bf16_t* xcat  = (bf16_t*)(ws + OFF_XCAT);
    bf16_t* gi    = (bf16_t*)(ws + OFF_GI);

    int Tc = 512;
    while (Tc > 8 && OFF_GI + (unsigned long long)Tc * 786432ull > (unsigned long long)ws_size)
        Tc >>= 1;
    int nch = T_ / Tc;

    prep_all<<<dim3(3072, 8), 256, 0, stream>>>(
        eWih0, eWhh0, eWih1, eWhh1, dWhh0, dWih1, dWhh1,
        wih0e, whh0e, wih1e, whh1e, wdhh0, wdih1, wdhh1,
        dWih0, fcW, fcb, dbih0, st, weff, beff, ovp, bar);

    for (int c = 0; c < nch; c++) {
        gemm_gi<<<dim3(Tc * 2, 12), 256, 0, stream>>>(x, nullptr, wih0e, gi, c * Tc, 64);
        gru_scan<<<32, 512, 0, stream>>>(gi, c * Tc, Tc, whh0e, ebih0, ebhh0, hstate, xcat, h0init);
    }
    for (int c = 0; c < nch; c++) {
        gemm_gi<<<dim3(Tc * 2, 12), 256, 0, stream>>>(nullptr, xcat, wih1e, gi, c * Tc, 512);
        gru_scan<<<32, 512, 0, stream>>>(gi, c * Tc, Tc, whh1e, ebih1, ebhh1, hstate, nullptr, h1init);
    }

    dec_persist<<<256, 512, 0, stream>>>(weff, beff, ovp,
                                         wdhh0, dbhh0, wdih1, dbih1, wdhh1, dbhh1,
                                         h0init, h1init,
                                         hx00, hx01, hx10, hx11,
                                         hist, bar);

    fc_all<<<OSL_ * 16, 256, 0, stream>>>(hist, fcW, fcb, (float*)d_out);
}

// Round 12
// 4225.169 us; speedup vs baseline: 1.8684x; 1.0912x over previous
//
#include <hip/hip_runtime.h>
#include <hip/hip_bf16.h>
#include <stdint.h>
#include <stddef.h>

// ---------------------------------------------------------------------------
// Seq2Seq BiGRU: B=256 T=512 F=64 H=256 (2-layer bidir encoder),
// decoder DH=512 2-layer, OSL=20, OUT=2.
//
// Round-14 structure (= r11 register-weights + r7 intra-XCD exchange):
//  - r11 kept the ~16us/phase toll despite zero per-phase weight loads ->
//    remaining suspects: (1) cross-XCD h staging (sc0 sc1 coherence-point,
//    ~900cyc x 1024 loads/WG) from r11's mapping, or (2) weight-tile spill.
//  - dec_persist v5: group/slice bit-swap -> s=blockIdx>>4, g=blockIdx&15.
//    A group's 16 WGs stride 16 in blockIdx -> SAME XCD (%8), the exact
//    partner-stride r7/r9 passed with. h exchange reverts to the r7/r9
//    proven intra-XCD path: plain publish stores (write-through L1->L2),
//    sc0-only staged loads (local L2, ~300cyc). Weights stay register-
//    resident (r11) so the old weight-storm reason for avoiding this
//    mapping is gone. Barrier: RELAXED RMW + bounded spin (never hangs).
//  - Per-XCD: groups g and g+8 (32 WGs = 32 CUs) -> full machine.
//  - prep/gemm/scan/fc byte-identical to r11 (4610us, passed).
// ---------------------------------------------------------------------------

typedef __bf16 bf16_t;
typedef bf16_t bf16x8 __attribute__((ext_vector_type(8)));
typedef float  f32x4  __attribute__((ext_vector_type(4)));

#define B_   256
#define T_   512
#define F_   64
#define H_   256
#define G_   768      // 3*H
#define DH_  512
#define DG_  1536     // 3*DH
#define OSL_ 20

__device__ __forceinline__ float sigm(float x) {
    float e = __builtin_amdgcn_exp2f(-1.442695040888963f * x);
    return __builtin_amdgcn_rcpf(1.0f + e);
}
__device__ __forceinline__ float tanh_(float x) {
    float e = __builtin_amdgcn_exp2f(-2.885390081777927f * x);
    return __builtin_amdgcn_rcpf(1.0f + e) * 2.0f - 1.0f;
}

__device__ __forceinline__ bf16x8 load_f32x8_as_bf16(const float* p) {
    f32x4 u = *(const f32x4*)p;
    f32x4 v = *(const f32x4*)(p + 4);
    bf16x8 r;
    r[0]=(bf16_t)u[0]; r[1]=(bf16_t)u[1]; r[2]=(bf16_t)u[2]; r[3]=(bf16_t)u[3];
    r[4]=(bf16_t)v[0]; r[5]=(bf16_t)v[1]; r[6]=(bf16_t)v[2]; r[7]=(bf16_t)v[3];
    return r;
}

// ------------------------------- fused prep --------------------------------
__global__ __launch_bounds__(256) void prep_all(
    const float* __restrict__ s0, const float* __restrict__ s1,
    const float* __restrict__ s2, const float* __restrict__ s3,
    const float* __restrict__ s4, const float* __restrict__ s5,
    const float* __restrict__ s6,
    bf16_t* __restrict__ d0, bf16_t* __restrict__ d1, bf16_t* __restrict__ d2,
    bf16_t* __restrict__ d3, bf16_t* __restrict__ d4, bf16_t* __restrict__ d5,
    bf16_t* __restrict__ d6,
    const float* __restrict__ wih0d, const float* __restrict__ fcw,
    const float* __restrict__ fcb, const float* __restrict__ bih0d,
    const float* __restrict__ st, bf16_t* __restrict__ weff,
    float* __restrict__ beff, float* __restrict__ ov,
    unsigned int* __restrict__ bar) {
    int i = blockIdx.x * 256 + threadIdx.x;
    switch (blockIdx.y) {
      case 0: if (i < 2*G_*F_)  d0[i] = (bf16_t)s0[i]; break;
      case 1: if (i < 2*G_*H_)  d1[i] = (bf16_t)s1[i]; break;
      case 2: if (i < 2*G_*DH_) d2[i] = (bf16_t)s2[i]; break;
      case 3: if (i < 2*G_*H_)  d3[i] = (bf16_t)s3[i]; break;
      case 4: if (i < DG_*DH_)  d4[i] = (bf16_t)s4[i]; break;
      case 5: if (i < DG_*DH_)  d5[i] = (bf16_t)s5[i]; break;
      case 6: if (i < DG_*DH_)  d6[i] = (bf16_t)s6[i]; break;
      default: {
        if (i < 1024) bar[i] = 0u;
        if (i < DG_*DH_) {
          int g = i >> 9, k = i & 511;
          float a0 = wih0d[g * 2], a1 = wih0d[g * 2 + 1];
          weff[i] = (bf16_t)(a0 * fcw[k] + a1 * fcw[DH_ + k]);
          if (k == 0) {
            beff[g] = a0 * fcb[0] + a1 * fcb[1] + bih0d[g];
            ov[g]   = a0 * st[0]  + a1 * st[1]  + bih0d[g];
          }
        }
      } break;
    }
}

// --------------------------- gi chunk GEMM ---------------------------------
__global__ __launch_bounds__(256) void gemm_gi(
    const float* __restrict__ x, const bf16_t* __restrict__ xcat,
    const bf16_t* __restrict__ Bt, bf16_t* __restrict__ gi, int t0, int K) {
    __shared__ bf16_t As[128 * 64];
    __shared__ bf16_t Bs[128 * 64];
    int m0 = blockIdx.x * 128, n0 = blockIdx.y * 128;
    int tid = threadIdx.x;
    int lane = tid & 63, w = tid >> 6;
    int col = lane & 15, quad = lane >> 4;
    int qm = (w >> 1) * 64, qn = (w & 1) * 64;

    int tl = m0 >> 8;              // local chunk time (constant per block)
    int bbase = m0 & 255;          // batch base (0 or 128)
    int t_real = t0 + tl;
    if (n0 >= 768) t_real = (T_ - 1) - t_real;

    f32x4 acc[4][4] = {};
    for (int k0 = 0; k0 < K; k0 += 64) {
        __syncthreads();
#pragma unroll
        for (int i = 0; i < 4; i++) {
            int c = i * 256 + tid;
            int m = c >> 3, kc = c & 7;
            int kcs = kc ^ (m & 7);   // XOR swizzle at source
            bf16x8 av;
            if (K == 64) {
                av = load_f32x8_as_bf16(x + ((size_t)(bbase + m) * T_ + t_real) * F_ + kcs * 8);
            } else {
                av = *(const bf16x8*)(xcat + ((size_t)t_real * B_ + bbase + m) * DH_ + k0 + kcs * 8);
            }
            *(bf16x8*)(&As[c * 8]) = av;
            *(bf16x8*)(&Bs[c * 8]) = *(const bf16x8*)(Bt + (size_t)(n0 + m) * K + k0 + kcs * 8);
        }
        __syncthreads();
#pragma unroll
        for (int kt = 0; kt < 2; kt++) {
            bf16x8 a[4], b[4];
#pragma unroll
            for (int mt = 0; mt < 4; mt++) {
                int r = qm + mt * 16 + col;
                a[mt] = *(const bf16x8*)(&As[(r * 8 + ((kt * 4 + quad) ^ (r & 7))) * 8]);
                int rn = qn + mt * 16 + col;
                b[mt] = *(const bf16x8*)(&Bs[(rn * 8 + ((kt * 4 + quad) ^ (rn & 7))) * 8]);
            }
#pragma unroll
            for (int mt = 0; mt < 4; mt++)
#pragma unroll
                for (int nt = 0; nt < 4; nt++)
                    acc[mt][nt] = __builtin_amdgcn_mfma_f32_16x16x32_bf16(a[mt], b[nt], acc[mt][nt], 0, 0, 0);
        }
    }
#pragma unroll
    for (int mt = 0; mt < 4; mt++)
#pragma unroll
        for (int nt = 0; nt < 4; nt++)
#pragma unroll
            for (int i = 0; i < 4; i++) {
                int row = m0 + qm + mt * 16 + quad * 4 + i;
                int cg  = n0 + qn + nt * 16 + col;
                gi[(size_t)row * DG_ + cg] = (bf16_t)acc[mt][nt][i];
            }
}

// ------------------------------ GRU scan (chunked) -------------------------
__global__ __launch_bounds__(512) void gru_scan(
    const bf16_t* __restrict__ gi, int t0, int tc,
    const bf16_t* __restrict__ whh,
    const float* __restrict__ bih, const float* __restrict__ bhh,
    float* __restrict__ hstate, bf16_t* __restrict__ y, float* __restrict__ hT) {
    __shared__ bf16_t gi_lds[16 * 768];       // [b][768]
    __shared__ bf16_t h_lds[2 * 16 * 264];    // [par][b][256+8 pad]

    int dir = blockIdx.x >> 4;
    int b0  = (blockIdx.x & 15) * 16;
    int tid = threadIdx.x;
    int w = tid >> 6, lane = tid & 63, col = lane & 15, quad = lane >> 4;

    bf16x8 wf[3][2][8];
    const bf16_t* wbase = whh + (size_t)dir * G_ * H_;
#pragma unroll
    for (int g = 0; g < 3; g++)
#pragma unroll
        for (int nt = 0; nt < 2; nt++) {
            int row = g * 256 + w * 32 + nt * 16 + col;
#pragma unroll
            for (int kt = 0; kt < 8; kt++)
                wf[g][nt][kt] = *(const bf16x8*)(wbase + (size_t)row * H_ + kt * 32 + quad * 8);
        }
    float brz[2][2], bin_[2], bhn[2];
#pragma unroll
    for (int nt = 0; nt < 2; nt++) {
        int j = w * 32 + nt * 16 + col;
        brz[0][nt] = bih[dir * G_ + j] + bhh[dir * G_ + j];
        brz[1][nt] = bih[dir * G_ + 256 + j] + bhh[dir * G_ + 256 + j];
        bin_[nt]   = bih[dir * G_ + 512 + j];
        bhn[nt]    = bhh[dir * G_ + 512 + j];
    }
    int bb[3], oo[3];
#pragma unroll
    for (int it = 0; it < 3; it++) {
        int c = it * 512 + tid;
        bb[it] = c / 96;
        oo[it] = (c % 96) * 8;
    }
    float hold[2][4];
#pragma unroll
    for (int nt = 0; nt < 2; nt++)
#pragma unroll
        for (int i = 0; i < 4; i++) {
            int j = w * 32 + nt * 16 + col;
            hold[nt][i] = t0 ? hstate[dir * 65536 + (b0 + quad * 4 + i) * 256 + j] : 0.0f;
        }
    for (int i = tid; i < 16 * 264; i += 512) {
        int b = i / 264, j = i % 264;
        float v = (t0 && j < 256) ? hstate[dir * 65536 + (b0 + b) * 256 + j] : 0.0f;
        h_lds[i] = (bf16_t)v;
    }
#pragma unroll
    for (int it = 0; it < 3; it++) {
        int c = it * 512 + tid;
        *(bf16x8*)(&gi_lds[c * 8]) =
            *(const bf16x8*)(gi + ((size_t)0 * B_ + b0 + bb[it]) * DG_ + dir * G_ + oo[it]);
    }
    __syncthreads();

    for (int s = 0; s < tc; s++) {
        int par = s & 1;
        int t = t0 + s;
        int sn = (s + 1 < tc) ? (s + 1) : s;

        bf16x8 pg[3];
#pragma unroll
        for (int it = 0; it < 3; it++)
            pg[it] = *(const bf16x8*)(gi + ((size_t)sn * B_ + b0 + bb[it]) * DG_ + dir * G_ + oo[it]);

        f32x4 acc[3][2] = {};
        const bf16_t* hcur = &h_lds[par * 4224];
#pragma unroll
        for (int kt = 0; kt < 8; kt++) {
            bf16x8 af = *(const bf16x8*)(hcur + col * 264 + kt * 32 + quad * 8);
#pragma unroll
            for (int g = 0; g < 3; g++)
#pragma unroll
                for (int nt = 0; nt < 2; nt++)
                    acc[g][nt] = __builtin_amdgcn_mfma_f32_16x16x32_bf16(af, wf[g][nt][kt], acc[g][nt], 0, 0, 0);
        }

        bf16_t* hnext = &h_lds[(par ^ 1) * 4224];
        int tp = dir ? (T_ - 1 - t) : t;
#pragma unroll
        for (int nt = 0; nt < 2; nt++) {
            int j = w * 32 + nt * 16 + col;
#pragma unroll
            for (int i = 0; i < 4; i++) {
                int b = quad * 4 + i;
                float gr = acc[0][nt][i] + (float)gi_lds[b * 768 + j]       + brz[0][nt];
                float gz = acc[1][nt][i] + (float)gi_lds[b * 768 + 256 + j] + brz[1][nt];
                float gn = (float)gi_lds[b * 768 + 512 + j] + bin_[nt];
                float r = sigm(gr), z = sigm(gz);
                float n = tanh_(gn + r * (acc[2][nt][i] + bhn[nt]));
                float hv = (1.0f - z) * n + z * hold[nt][i];
                hold[nt][i] = hv;
                hnext[b * 264 + j] = (bf16_t)hv;
                if (y) y[((size_t)tp * B_ + b0 + b) * DH_ + dir * H_ + j] = (bf16_t)hv;
                if (t == T_ - 1) hT[(size_t)(b0 + b) * DH_ + dir * H_ + j] = hv;
            }
        }
        __syncthreads();
#pragma unroll
        for (int it = 0; it < 3; it++)
            *(bf16x8*)(&gi_lds[(it * 512 + tid) * 8]) = pg[it];
        __syncthreads();
    }
#pragma unroll
    for (int nt = 0; nt < 2; nt++)
#pragma unroll
        for (int i = 0; i < 4; i++) {
            int j = w * 32 + nt * 16 + col;
            hstate[dir * 65536 + (b0 + quad * 4 + i) * 256 + j] = hold[nt][i];
        }
}

// ---------------- persistent decoder, register-resident weights ------------
// 256 WGs x 512 thr = 16 j-slices (s = blockIdx>>4, 32 j) x 16 groups
// (g = blockIdx&15, 16 batch rows). A group's 16 WGs stride 16 in blockIdx
// -> SAME XCD (%8; the r7/r9-passing partner stride) -> h exchange stays in
// the XCD-local L2: plain publish stores, sc0-only staged loads (~300cyc).
// 24 (mat,gate,jhalf) weight tiles per WG, 3 per wave (192 VGPR incl. AGPR
// file), loaded once. Full-K per wave -> no reduce; 12KB LDS acc exchange;
// waves 0/1 do gate epilogue + publish (f32 carries there).
// Barrier = RELAXED device RMW + bounded spin (fails visibly, never hangs).

__device__ __forceinline__ void gbar16(unsigned int* cnt) {
    __syncthreads();   // drains vmcnt -> publishes in local L2 before arrival
    if (threadIdx.x == 0) {
        __hip_atomic_fetch_add(cnt, 1u, __ATOMIC_RELAXED, __HIP_MEMORY_SCOPE_AGENT);
        unsigned int s = 0;
        while (__hip_atomic_load(cnt, __ATOMIC_RELAXED, __HIP_MEMORY_SCOPE_AGENT) < 16u
               && ++s < (1u << 20))
            __builtin_amdgcn_s_sleep(1);
    }
    __syncthreads();
}

// stage 16 rows x 512 bf16 (16 KB) with 512 threads: 2 x 16B per thread.
// sc0 = bypass L1, read the shared XCD-local L2 (publishers are intra-XCD).
__device__ __forceinline__ void stage16v(bf16_t* lds, const bf16_t* src) {
    f32x4 v0, v1;
    const char* a0 = (const char*)src + threadIdx.x * 16;
    asm volatile(
        "global_load_dwordx4 %0, %2, off sc0\n\t"
        "global_load_dwordx4 %1, %3, off sc0\n\t"
        "s_waitcnt vmcnt(0)"
        : "=&v"(v0), "=&v"(v1)
        : "v"(a0), "v"(a0 + 8192)
        : "memory");
    {
        int off = threadIdx.x * 16;
        int row = off >> 10;
        int swz = off ^ ((row & 7) << 4);
        *(f32x4*)((char*)lds + swz) = v0;
    }
    {
        int off = 8192 + threadIdx.x * 16;
        int row = off >> 10;
        int swz = off ^ ((row & 7) << 4);
        *(f32x4*)((char*)lds + swz) = v1;
    }
}

__device__ __forceinline__ bf16x8 fragrd(const bf16_t* lds, int kt, int col, int quad) {
    int byte = (col * 1024 + kt * 64 + quad * 16) ^ ((col & 7) << 4);
    return *(const bf16x8*)((const char*)lds + byte);
}

// publish hv as bf16 packed u32 (even-col lanes store j, j+1); plain store
// -> write-through to the XCD-local L2 (readers are intra-XCD, sc0 loads).
__device__ __forceinline__ void publish(bf16_t* dst, int b, int j, float hv, int col) {
    bf16_t hb = (bf16_t)hv;
    unsigned short mb;
    __builtin_memcpy(&mb, &hb, 2);
    unsigned int pv = (unsigned int)__shfl_xor((int)(unsigned int)mb, 1);
    if ((col & 1) == 0) {
        unsigned int word = (unsigned int)mb | (pv << 16);
        *(unsigned int*)((char*)dst + (size_t)(b * DH_ + j) * 2) = word;
    }
}

__global__ __launch_bounds__(512, 2) void dec_persist(
    const bf16_t* __restrict__ weff, const float* __restrict__ beff,
    const float* __restrict__ ov,
    const bf16_t* __restrict__ wdhh0, const float* __restrict__ dbhh0,
    const bf16_t* __restrict__ wdih1, const float* __restrict__ dbih1,
    const bf16_t* __restrict__ wdhh1, const float* __restrict__ dbhh1,
    const float* __restrict__ h0init, const float* __restrict__ h1init,
    bf16_t* hx00, bf16_t* hx01, bf16_t* hx10, bf16_t* hx11,
    float* __restrict__ hist, unsigned int* __restrict__ bar) {
    __shared__ bf16_t sh[16 * 512];   // h0 (persists A<-B)
    __shared__ bf16_t sx[16 * 512];   // h1
    __shared__ f32x4 exch[12 * 64];   // acc exchange (12 tiles x 64 lanes)

    int s  = blockIdx.x >> 4;         // j-slice (partners stride 16 -> same XCD)
    int g  = blockIdx.x & 15;         // batch group
    int js = s * 32;
    int tid = threadIdx.x, w = tid >> 6, lane = tid & 63;
    int col = lane & 15, quad = lane >> 4;

    // ---- prologue: load 3 owned weight tiles into registers ----
    const bf16_t* mats[4] = { wdhh0, weff, wdih1, wdhh1 };
    bf16x8 frg[3][16];
    int tmat[3], texch[3];
#pragma unroll
    for (int sl = 0; sl < 3; ++sl) {
        int idx = w + sl * 8;         // 0..23
        int m = idx / 6, rem = idx - m * 6;
        int gate = rem >> 1, jh = rem & 1;
        tmat[sl] = m;
        texch[sl] = (m & 1) * 6 + rem;   // slot within phase: 0..11
        int row = gate * 512 + js + jh * 16 + col;
        const bf16_t* M = mats[m];
#pragma unroll
        for (int kt = 0; kt < 16; ++kt)
            frg[sl][kt] = *(const bf16x8*)(M + (size_t)row * DH_ + kt * 32 + quad * 8);
    }

    // epilogue-lane constants (valid for w<2; harmless elsewhere)
    int je = js + (w & 1) * 16 + col;
    float b0r = beff[je] + dbhh0[je],        b0z = beff[DH_ + je] + dbhh0[DH_ + je];
    float b0in = beff[2 * DH_ + je],         b0hn = dbhh0[2 * DH_ + je];
    float o0r = ov[je] + dbhh0[je],          o0z = ov[DH_ + je] + dbhh0[DH_ + je];
    float o0in = ov[2 * DH_ + je];
    float b1r = dbih1[je] + dbhh1[je],       b1z = dbih1[DH_ + je] + dbhh1[DH_ + je];
    float b1in = dbih1[2 * DH_ + je],        b1hn = dbhh1[2 * DH_ + je];

    // init: epilogue waves publish initial state, keep f32 carries
    float hold0[4], hold1[4];
    if (w < 2) {
#pragma unroll
        for (int i = 0; i < 4; ++i) {
            int b = g * 16 + quad * 4 + i;
            float v0 = h0init[(size_t)b * DH_ + je];
            float v1 = h1init[(size_t)b * DH_ + je];
            hold0[i] = v0; hold1[i] = v1;
            publish(hx01, b, je, v0, col);
            publish(hx11, b, je, v1, col);
        }
    }
    gbar16(bar + g);   // phase 0: init visible

    int ph = 1;
    for (int t = 0; t < OSL_; ++t) {
        bf16_t* write0 = (t & 1) ? hx01 : hx00;
        bf16_t* read0  = (t & 1) ? hx00 : hx01;
        bf16_t* write1 = (t & 1) ? hx11 : hx10;
        bf16_t* read1  = (t & 1) ? hx10 : hx11;
        bool dox = (t > 0);

        // ---------------- phase A: cell0 ----------------
        // sh holds h0(t-1) (staged in phase B of t-1); stage h1(t-1) only.
        if (t == 0) stage16v(sh, read0 + (size_t)g * 16 * DH_);
        stage16v(sx, read1 + (size_t)g * 16 * DH_);
        __syncthreads();

        {
            f32x4 acc[3] = {};
#pragma unroll
            for (int sl = 0; sl < 3; ++sl) {
                if (tmat[sl] == 0) {            // Whh0 x h0(t-1)
#pragma unroll
                    for (int kt = 0; kt < 16; ++kt)
                        acc[sl] = __builtin_amdgcn_mfma_f32_16x16x32_bf16(
                            fragrd(sh, kt, col, quad), frg[sl][kt], acc[sl], 0, 0, 0);
                } else if (tmat[sl] == 1 && dox) { // Weff x h1(t-1)
#pragma unroll
                    for (int kt = 0; kt < 16; ++kt)
                        acc[sl] = __builtin_amdgcn_mfma_f32_16x16x32_bf16(
                            fragrd(sx, kt, col, quad), frg[sl][kt], acc[sl], 0, 0, 0);
                }
            }
#pragma unroll
            for (int sl = 0; sl < 3; ++sl)
                if (tmat[sl] <= 1) exch[texch[sl] * 64 + lane] = acc[sl];
        }
        __syncthreads();

        if (w < 2) {
            int jh = w;
            f32x4 aR0 = exch[(0 + jh) * 64 + lane];
            f32x4 aZ0 = exch[(2 + jh) * 64 + lane];
            f32x4 aN0 = exch[(4 + jh) * 64 + lane];
            f32x4 aR1 = {}, aZ1 = {}, aN1 = {};
            if (dox) {
                aR1 = exch[(6 + jh) * 64 + lane];
                aZ1 = exch[(8 + jh) * 64 + lane];
                aN1 = exch[(10 + jh) * 64 + lane];
            }
#pragma unroll
            for (int i = 0; i < 4; ++i) {
                int b = g * 16 + quad * 4 + i;
                float r = sigm(aR0[i] + aR1[i] + (dox ? b0r : o0r));
                float z = sigm(aZ0[i] + aZ1[i] + (dox ? b0z : o0z));
                float gin = dox ? (aN1[i] + b0in) : o0in;
                float n = tanh_(gin + r * (aN0[i] + b0hn));
                float hv = (1.0f - z) * n + z * hold0[i];
                hold0[i] = hv;
                publish(write0, b, je, hv, col);
            }
        }
        gbar16(bar + ph * 16 + g); ph++;

        // ---------------- phase B: cell1 ----------------
        stage16v(sh, write0 + (size_t)g * 16 * DH_);   // h0(t)
        __syncthreads();

        {
            f32x4 acc[3] = {};
#pragma unroll
            for (int sl = 0; sl < 3; ++sl) {
                if (tmat[sl] == 2) {            // Wih1 x h0(t)
#pragma unroll
                    for (int kt = 0; kt < 16; ++kt)
                        acc[sl] = __builtin_amdgcn_mfma_f32_16x16x32_bf16(
                            fragrd(sh, kt, col, quad), frg[sl][kt], acc[sl], 0, 0, 0);
                } else if (tmat[sl] == 3) {     // Whh1 x h1(t-1)
#pragma unroll
                    for (int kt = 0; kt < 16; ++kt)
                        acc[sl] = __builtin_amdgcn_mfma_f32_16x16x32_bf16(
                            fragrd(sx, kt, col, quad), frg[sl][kt], acc[sl], 0, 0, 0);
                }
            }
#pragma unroll
            for (int sl = 0; sl < 3; ++sl)
                if (tmat[sl] >= 2) exch[texch[sl] * 64 + lane] = acc[sl];
        }
        __syncthreads();

        if (w < 2) {
            int jh = w;
            f32x4 giR = exch[(0 + jh) * 64 + lane];   // Wih1 (m&1==0)
            f32x4 giZ = exch[(2 + jh) * 64 + lane];
            f32x4 giN = exch[(4 + jh) * 64 + lane];
            f32x4 ghR = exch[(6 + jh) * 64 + lane];   // Whh1 (m&1==1)
            f32x4 ghZ = exch[(8 + jh) * 64 + lane];
            f32x4 ghN = exch[(10 + jh) * 64 + lane];
            float* hist_t = hist + (size_t)t * B_ * DH_;
#pragma unroll
            for (int i = 0; i < 4; ++i) {
                int b = g * 16 + quad * 4 + i;
                float r = sigm(giR[i] + ghR[i] + b1r);
                float z = sigm(giZ[i] + ghZ[i] + b1z);
                float n = tanh_(giN[i] + b1in + r * (ghN[i] + b1hn));
                float hv = (1.0f - z) * n + z * hold1[i];
                hold1[i] = hv;
                hist_t[(size_t)b * DH_ + je] = hv;
                publish(write1, b, je, hv, col);
            }
        }
        if (t < OSL_ - 1) { gbar16(bar + ph * 16 + g); ph++; }
    }
}

// ------------------------------- FC head -----------------------------------
__global__ __launch_bounds__(256) void fc_all(
    const float* __restrict__ hist, const float* __restrict__ fcw,
    const float* __restrict__ fcb, float* __restrict__ out) {
    int t  = blockIdx.x >> 4;
    int b0 = (blockIdx.x & 15) * 16;
    int tid = threadIdx.x;
    int bl = tid >> 4, o = (tid >> 3) & 1, part = tid & 7;
    const float* hp = hist + ((size_t)t * B_ + b0 + bl) * DH_;
    const float* wp = fcw + o * DH_;
    float s = 0.0f;
    for (int k = part * 64; k < part * 64 + 64; k += 4) {
        f32x4 hv = *(const f32x4*)(hp + k);
        f32x4 wv = *(const f32x4*)(wp + k);
        s += hv[0] * wv[0] + hv[1] * wv[1] + hv[2] * wv[2] + hv[3] * wv[3];
    }
    s += __shfl_down(s, 4); s += __shfl_down(s, 2); s += __shfl_down(s, 1);
    if (part == 0) out[(size_t)(b0 + bl) * (OSL_ * 2) + t * 2 + o] = s + fcb[o];
}

// ------------------------------ launcher -----------------------------------

#define OFF_WIH0E 0ull
#define OFF_WHH0E 196608ull
#define OFF_WIH1E 983040ull
#define OFF_WHH1E 2555904ull
#define OFF_WDHH0 3342336ull
#define OFF_WDIH1 4915200ull
#define OFF_WDHH1 6488064ull
#define OFF_WEFF  8060928ull
#define OFF_BEFF  9633792ull
#define OFF_BAR   9641984ull    // 41 phases x 16 groups (zeroed 1024 u32)
#define OFF_OV    9658368ull
#define OFF_H0A   9682944ull
#define OFF_H0B   10207232ull   // hx00 (256 KB) + hx01 (256 KB)
#define OFF_H1A   10731520ull
#define OFF_H1B   11255808ull   // hx10 (256 KB) + hx11 (256 KB)
#define OFF_HST   11780096ull
#define OFF_HIST  12304384ull
#define OFF_XCAT  22790144ull
#define OFF_GI    157007872ull

extern "C" void kernel_launch(void* const* d_in, const int* in_sizes, int n_in,
                              void* d_out, int out_size, void* d_ws, size_t ws_size,
                              hipStream_t stream) {
    const float* x      = (const float*)d_in[0];
    const float* st     = (const float*)d_in[1];
    const float* eWih0  = (const float*)d_in[2];
    const float* eWhh0  = (const float*)d_in[3];
    const float* ebih0  = (const float*)d_in[4];
    const float* ebhh0  = (const float*)d_in[5];
    const float* eWih1  = (const float*)d_in[6];
    const float* eWhh1  = (const float*)d_in[7];
    const float* ebih1  = (const float*)d_in[8];
    const float* ebhh1  = (const float*)d_in[9];
    const float* dWih0  = (const float*)d_in[10];
    const float* dWhh0  = (const float*)d_in[11];
    const float* dbih0  = (const float*)d_in[12];
    const float* dbhh0  = (const float*)d_in[13];
    const float* dWih1  = (const float*)d_in[14];
    const float* dWhh1  = (const float*)d_in[15];
    const float* dbih1  = (const float*)d_in[16];
    const float* dbhh1  = (const float*)d_in[17];
    const float* fcW    = (const float*)d_in[18];
    const float* fcb    = (const float*)d_in[19];

    char* ws = (char*)d_ws;
    bf16_t* wih0e = (bf16_t*)(ws + OFF_WIH0E);
    bf16_t* whh0e = (bf16_t*)(ws + OFF_WHH0E);
    bf16_t* wih1e = (bf16_t*)(ws + OFF_WIH1E);
    bf16_t* whh1e = (bf16_t*)(ws + OFF_WHH1E);
    bf16_t* wdhh0 = (bf16_t*)(ws + OFF_WDHH0);
    bf16_t* wdih1 = (bf16_t*)(ws + OFF_WDIH1);
    bf16_t* wdhh1 = (bf16_t*)(ws + OFF_WDHH1);
    bf16_t* weff  = (bf16_t*)(ws + OFF_WEFF);
    float*  beff  = (float*)(ws + OFF_BEFF);
    unsigned int* bar = (unsigned int*)(ws + OFF_BAR);
    float*  ovp   = (float*)(ws + OFF_OV);
    float*  h0init = (float*)(ws + OFF_H0A);
    float*  h1init = (float*)(ws + OFF_H1A);
    bf16_t* hx00  = (bf16_t*)(ws + OFF_H0B);
    bf16_t* hx01  = (bf16_t*)(ws + OFF_H0B + 262144ull);
    bf16_t* hx10  = (bf16_t*)(ws + OFF_H1B);
    bf16_t* hx11  = (bf16_t*)(ws + OFF_H1B + 262144ull);
    float*  hstate = (float*)(ws + OFF_HST);
    float*  hist  = (float*)(ws + OFF_HIST);
    bf16_t* xcat  = (bf16_t*)(ws + OFF_XCAT);
    bf16_t* gi    = (bf16_t*)(ws + OFF_GI);

    int Tc = 512;
    while (Tc > 8 && OFF_GI + (unsigned long long)Tc * 786432ull > (unsigned long long)ws_size)
        Tc >>= 1;
    int nch = T_ / Tc;

    prep_all<<<dim3(3072, 8), 256, 0, stream>>>(
        eWih0, eWhh0, eWih1, eWhh1, dWhh0, dWih1, dWhh1,
        wih0e, whh0e, wih1e, whh1e, wdhh0, wdih1, wdhh1,
        dWih0, fcW, fcb, dbih0, st, weff, beff, ovp, bar);

    for (int c = 0; c < nch; c++) {
        gemm_gi<<<dim3(Tc * 2, 12), 256, 0, stream>>>(x, nullptr, wih0e, gi, c * Tc, 64);
        gru_scan<<<32, 512, 0, stream>>>(gi, c * Tc, Tc, whh0e, ebih0, ebhh0, hstate, xcat, h0init);
    }
    for (int c = 0; c < nch; c++) {
        gemm_gi<<<dim3(Tc * 2, 12), 256, 0, stream>>>(nullptr, xcat, wih1e, gi, c * Tc, 512);
        gru_scan<<<32, 512, 0, stream>>>(gi, c * Tc, Tc, whh1e, ebih1, ebhh1, hstate, nullptr, h1init);
    }

    dec_persist<<<256, 512, 0, stream>>>(weff, beff, ovp,
                                         wdhh0, dbhh0, wdih1, dbih1, wdhh1, dbhh1,
                                         h0init, h1init,
                                         hx00, hx01, hx10, hx11,
                                         hist, bar);

    fc_all<<<OSL_ * 16, 256, 0, stream>>>(hist, fcW, fcb, (float*)d_out);
}

// Round 13
// 4147.515 us; speedup vs baseline: 1.9034x; 1.0187x over previous
//
#include <hip/hip_runtime.h>
#include <hip/hip_bf16.h>
#include <stdint.h>
#include <stddef.h>

// ---------------------------------------------------------------------------
// Seq2Seq BiGRU: B=256 T=512 F=64 H=256 (2-layer bidir encoder),
// decoder DH=512 2-layer, OSL=20, OUT=2.
//
// Round-15 structure (= r12 + global_load_lds staging in gemm_gi):
//  - r12 settled the accounting: Tc=512/nch=1; scans 2x437us (serial -- bwd
//    L1 consumes xcat in reverse so scanL0 must fully precede scanL1);
//    gemmL1 ~410us; dec now below top-5; ~2.45ms constant harness floor.
//  - gemm_gi: staging converts to __builtin_amdgcn_global_load_lds width=16
//    for the bf16 sources (xcat, Bt). Our layout is already the m173
//    pattern: source-swizzled global address (kcs XOR) + LINEAR LDS dest
//    (byte off = c*16 = wave-uniform base + lane*16) -- exactly the
//    instruction's contract. K=64 As path (f32 x -> bf16) keeps the
//    register conversion. Measured precedent: +67% on this structure
//    (Common-mistake #1, 546->911 TF).
//  - dec_persist v5 (register-resident weights, intra-XCD exchange,
//    RELAXED barrier) and all other kernels byte-identical to r12
//    (4225us, passed).
// ---------------------------------------------------------------------------

typedef __bf16 bf16_t;
typedef bf16_t bf16x8 __attribute__((ext_vector_type(8)));
typedef float  f32x4  __attribute__((ext_vector_type(4)));

#define B_   256
#define T_   512
#define F_   64
#define H_   256
#define G_   768      // 3*H
#define DH_  512
#define DG_  1536     // 3*DH
#define OSL_ 20

__device__ __forceinline__ float sigm(float x) {
    float e = __builtin_amdgcn_exp2f(-1.442695040888963f * x);
    return __builtin_amdgcn_rcpf(1.0f + e);
}
__device__ __forceinline__ float tanh_(float x) {
    float e = __builtin_amdgcn_exp2f(-2.885390081777927f * x);
    return __builtin_amdgcn_rcpf(1.0f + e) * 2.0f - 1.0f;
}

__device__ __forceinline__ bf16x8 load_f32x8_as_bf16(const float* p) {
    f32x4 u = *(const f32x4*)p;
    f32x4 v = *(const f32x4*)(p + 4);
    bf16x8 r;
    r[0]=(bf16_t)u[0]; r[1]=(bf16_t)u[1]; r[2]=(bf16_t)u[2]; r[3]=(bf16_t)u[3];
    r[4]=(bf16_t)v[0]; r[5]=(bf16_t)v[1]; r[6]=(bf16_t)v[2]; r[7]=(bf16_t)v[3];
    return r;
}

// async global->LDS, 16B per lane; LDS dest = wave-uniform base + lane*16
__device__ __forceinline__ void gload_lds16(const void* g, void* l) {
    __builtin_amdgcn_global_load_lds(
        (const __attribute__((address_space(1))) unsigned int*)g,
        (__attribute__((address_space(3))) unsigned int*)l, 16, 0, 0);
}

// ------------------------------- fused prep --------------------------------
__global__ __launch_bounds__(256) void prep_all(
    const float* __restrict__ s0, const float* __restrict__ s1,
    const float* __restrict__ s2, const float* __restrict__ s3,
    const float* __restrict__ s4, const float* __restrict__ s5,
    const float* __restrict__ s6,
    bf16_t* __restrict__ d0, bf16_t* __restrict__ d1, bf16_t* __restrict__ d2,
    bf16_t* __restrict__ d3, bf16_t* __restrict__ d4, bf16_t* __restrict__ d5,
    bf16_t* __restrict__ d6,
    const float* __restrict__ wih0d, const float* __restrict__ fcw,
    const float* __restrict__ fcb, const float* __restrict__ bih0d,
    const float* __restrict__ st, bf16_t* __restrict__ weff,
    float* __restrict__ beff, float* __restrict__ ov,
    unsigned int* __restrict__ bar) {
    int i = blockIdx.x * 256 + threadIdx.x;
    switch (blockIdx.y) {
      case 0: if (i < 2*G_*F_)  d0[i] = (bf16_t)s0[i]; break;
      case 1: if (i < 2*G_*H_)  d1[i] = (bf16_t)s1[i]; break;
      case 2: if (i < 2*G_*DH_) d2[i] = (bf16_t)s2[i]; break;
      case 3: if (i < 2*G_*H_)  d3[i] = (bf16_t)s3[i]; break;
      case 4: if (i < DG_*DH_)  d4[i] = (bf16_t)s4[i]; break;
      case 5: if (i < DG_*DH_)  d5[i] = (bf16_t)s5[i]; break;
      case 6: if (i < DG_*DH_)  d6[i] = (bf16_t)s6[i]; break;
      default: {
        if (i < 1024) bar[i] = 0u;
        if (i < DG_*DH_) {
          int g = i >> 9, k = i & 511;
          float a0 = wih0d[g * 2], a1 = wih0d[g * 2 + 1];
          weff[i] = (bf16_t)(a0 * fcw[k] + a1 * fcw[DH_ + k]);
          if (k == 0) {
            beff[g] = a0 * fcb[0] + a1 * fcb[1] + bih0d[g];
            ov[g]   = a0 * st[0]  + a1 * st[1]  + bih0d[g];
          }
        }
      } break;
    }
}

// --------------------------- gi chunk GEMM ---------------------------------
__global__ __launch_bounds__(256) void gemm_gi(
    const float* __restrict__ x, const bf16_t* __restrict__ xcat,
    const bf16_t* __restrict__ Bt, bf16_t* __restrict__ gi, int t0, int K) {
    __shared__ bf16_t As[128 * 64];
    __shared__ bf16_t Bs[128 * 64];
    int m0 = blockIdx.x * 128, n0 = blockIdx.y * 128;
    int tid = threadIdx.x;
    int lane = tid & 63, w = tid >> 6;
    int col = lane & 15, quad = lane >> 4;
    int qm = (w >> 1) * 64, qn = (w & 1) * 64;

    int tl = m0 >> 8;              // local chunk time (constant per block)
    int bbase = m0 & 255;          // batch base (0 or 128)
    int t_real = t0 + tl;
    if (n0 >= 768) t_real = (T_ - 1) - t_real;

    f32x4 acc[4][4] = {};
    for (int k0 = 0; k0 < K; k0 += 64) {
        __syncthreads();
        if (K == 64) {
#pragma unroll
            for (int i = 0; i < 4; i++) {
                int c = i * 256 + tid;
                int m = c >> 3, kc = c & 7;
                int kcs = kc ^ (m & 7);   // XOR swizzle at source
                bf16x8 av = load_f32x8_as_bf16(
                    x + ((size_t)(bbase + m) * T_ + t_real) * F_ + kcs * 8);
                *(bf16x8*)(&As[c * 8]) = av;
                gload_lds16(Bt + (size_t)(n0 + m) * K + k0 + kcs * 8,
                            &Bs[(i * 256 + w * 64) * 8]);
            }
        } else {
#pragma unroll
            for (int i = 0; i < 4; i++) {
                int c = i * 256 + tid;
                int m = c >> 3, kc = c & 7;
                int kcs = kc ^ (m & 7);   // XOR swizzle at source
                gload_lds16(xcat + ((size_t)t_real * B_ + bbase + m) * DH_ + k0 + kcs * 8,
                            &As[(i * 256 + w * 64) * 8]);
                gload_lds16(Bt + (size_t)(n0 + m) * K + k0 + kcs * 8,
                            &Bs[(i * 256 + w * 64) * 8]);
            }
        }
        __syncthreads();
#pragma unroll
        for (int kt = 0; kt < 2; kt++) {
            bf16x8 a[4], b[4];
#pragma unroll
            for (int mt = 0; mt < 4; mt++) {
                int r = qm + mt * 16 + col;
                a[mt] = *(const bf16x8*)(&As[(r * 8 + ((kt * 4 + quad) ^ (r & 7))) * 8]);
                int rn = qn + mt * 16 + col;
                b[mt] = *(const bf16x8*)(&Bs[(rn * 8 + ((kt * 4 + quad) ^ (rn & 7))) * 8]);
            }
#pragma unroll
            for (int mt = 0; mt < 4; mt++)
#pragma unroll
                for (int nt = 0; nt < 4; nt++)
                    acc[mt][nt] = __builtin_amdgcn_mfma_f32_16x16x32_bf16(a[mt], b[nt], acc[mt][nt], 0, 0, 0);
        }
    }
#pragma unroll
    for (int mt = 0; mt < 4; mt++)
#pragma unroll
        for (int nt = 0; nt < 4; nt++)
#pragma unroll
            for (int i = 0; i < 4; i++) {
                int row = m0 + qm + mt * 16 + quad * 4 + i;
                int cg  = n0 + qn + nt * 16 + col;
                gi[(size_t)row * DG_ + cg] = (bf16_t)acc[mt][nt][i];
            }
}

// ------------------------------ GRU scan (chunked) -------------------------
__global__ __launch_bounds__(512) void gru_scan(
    const bf16_t* __restrict__ gi, int t0, int tc,
    const bf16_t* __restrict__ whh,
    const float* __restrict__ bih, const float* __restrict__ bhh,
    float* __restrict__ hstate, bf16_t* __restrict__ y, float* __restrict__ hT) {
    __shared__ bf16_t gi_lds[16 * 768];       // [b][768]
    __shared__ bf16_t h_lds[2 * 16 * 264];    // [par][b][256+8 pad]

    int dir = blockIdx.x >> 4;
    int b0  = (blockIdx.x & 15) * 16;
    int tid = threadIdx.x;
    int w = tid >> 6, lane = tid & 63, col = lane & 15, quad = lane >> 4;

    bf16x8 wf[3][2][8];
    const bf16_t* wbase = whh + (size_t)dir * G_ * H_;
#pragma unroll
    for (int g = 0; g < 3; g++)
#pragma unroll
        for (int nt = 0; nt < 2; nt++) {
            int row = g * 256 + w * 32 + nt * 16 + col;
#pragma unroll
            for (int kt = 0; kt < 8; kt++)
                wf[g][nt][kt] = *(const bf16x8*)(wbase + (size_t)row * H_ + kt * 32 + quad * 8);
        }
    float brz[2][2], bin_[2], bhn[2];
#pragma unroll
    for (int nt = 0; nt < 2; nt++) {
        int j = w * 32 + nt * 16 + col;
        brz[0][nt] = bih[dir * G_ + j] + bhh[dir * G_ + j];
        brz[1][nt] = bih[dir * G_ + 256 + j] + bhh[dir * G_ + 256 + j];
        bin_[nt]   = bih[dir * G_ + 512 + j];
        bhn[nt]    = bhh[dir * G_ + 512 + j];
    }
    int bb[3], oo[3];
#pragma unroll
    for (int it = 0; it < 3; it++) {
        int c = it * 512 + tid;
        bb[it] = c / 96;
        oo[it] = (c % 96) * 8;
    }
    float hold[2][4];
#pragma unroll
    for (int nt = 0; nt < 2; nt++)
#pragma unroll
        for (int i = 0; i < 4; i++) {
            int j = w * 32 + nt * 16 + col;
            hold[nt][i] = t0 ? hstate[dir * 65536 + (b0 + quad * 4 + i) * 256 + j] : 0.0f;
        }
    for (int i = tid; i < 16 * 264; i += 512) {
        int b = i / 264, j = i % 264;
        float v = (t0 && j < 256) ? hstate[dir * 65536 + (b0 + b) * 256 + j] : 0.0f;
        h_lds[i] = (bf16_t)v;
    }
#pragma unroll
    for (int it = 0; it < 3; it++) {
        int c = it * 512 + tid;
        *(bf16x8*)(&gi_lds[c * 8]) =
            *(const bf16x8*)(gi + ((size_t)0 * B_ + b0 + bb[it]) * DG_ + dir * G_ + oo[it]);
    }
    __syncthreads();

    for (int s = 0; s < tc; s++) {
        int par = s & 1;
        int t = t0 + s;
        int sn = (s + 1 < tc) ? (s + 1) : s;

        bf16x8 pg[3];
#pragma unroll
        for (int it = 0; it < 3; it++)
            pg[it] = *(const bf16x8*)(gi + ((size_t)sn * B_ + b0 + bb[it]) * DG_ + dir * G_ + oo[it]);

        f32x4 acc[3][2] = {};
        const bf16_t* hcur = &h_lds[par * 4224];
#pragma unroll
        for (int kt = 0; kt < 8; kt++) {
            bf16x8 af = *(const bf16x8*)(hcur + col * 264 + kt * 32 + quad * 8);
#pragma unroll
            for (int g = 0; g < 3; g++)
#pragma unroll
                for (int nt = 0; nt < 2; nt++)
                    acc[g][nt] = __builtin_amdgcn_mfma_f32_16x16x32_bf16(af, wf[g][nt][kt], acc[g][nt], 0, 0, 0);
        }

        bf16_t* hnext = &h_lds[(par ^ 1) * 4224];
        int tp = dir ? (T_ - 1 - t) : t;
#pragma unroll
        for (int nt = 0; nt < 2; nt++) {
            int j = w * 32 + nt * 16 + col;
#pragma unroll
            for (int i = 0; i < 4; i++) {
                int b = quad * 4 + i;
                float gr = acc[0][nt][i] + (float)gi_lds[b * 768 + j]       + brz[0][nt];
                float gz = acc[1][nt][i] + (float)gi_lds[b * 768 + 256 + j] + brz[1][nt];
                float gn = (float)gi_lds[b * 768 + 512 + j] + bin_[nt];
                float r = sigm(gr), z = sigm(gz);
                float n = tanh_(gn + r * (acc[2][nt][i] + bhn[nt]));
                float hv = (1.0f - z) * n + z * hold[nt][i];
                hold[nt][i] = hv;
                hnext[b * 264 + j] = (bf16_t)hv;
                if (y) y[((size_t)tp * B_ + b0 + b) * DH_ + dir * H_ + j] = (bf16_t)hv;
                if (t == T_ - 1) hT[(size_t)(b0 + b) * DH_ + dir * H_ + j] = hv;
            }
        }
        __syncthreads();
#pragma unroll
        for (int it = 0; it < 3; it++)
            *(bf16x8*)(&gi_lds[(it * 512 + tid) * 8]) = pg[it];
        __syncthreads();
    }
#pragma unroll
    for (int nt = 0; nt < 2; nt++)
#pragma unroll
        for (int i = 0; i < 4; i++) {
            int j = w * 32 + nt * 16 + col;
            hstate[dir * 65536 + (b0 + quad * 4 + i) * 256 + j] = hold[nt][i];
        }
}

// ---------------- persistent decoder, register-resident weights ------------
// 256 WGs x 512 thr = 16 j-slices (s = blockIdx>>4, 32 j) x 16 groups
// (g = blockIdx&15, 16 batch rows). A group's 16 WGs stride 16 in blockIdx
// -> SAME XCD (%8) -> h exchange stays in the XCD-local L2: plain publish
// stores, sc0-only staged loads. 24 weight tiles per WG, 3 per wave,
// loaded once. Full-K per wave -> no reduce; 12KB LDS acc exchange;
// waves 0/1 do gate epilogue + publish (f32 carries there).
// Barrier = RELAXED device RMW + bounded spin (fails visibly, never hangs).

__device__ __forceinline__ void gbar16(unsigned int* cnt) {
    __syncthreads();   // drains vmcnt -> publishes in local L2 before arrival
    if (threadIdx.x == 0) {
        __hip_atomic_fetch_add(cnt, 1u, __ATOMIC_RELAXED, __HIP_MEMORY_SCOPE_AGENT);
        unsigned int s = 0;
        while (__hip_atomic_load(cnt, __ATOMIC_RELAXED, __HIP_MEMORY_SCOPE_AGENT) < 16u
               && ++s < (1u << 20))
            __builtin_amdgcn_s_sleep(1);
    }
    __syncthreads();
}

// stage 16 rows x 512 bf16 (16 KB) with 512 threads: 2 x 16B per thread.
// sc0 = bypass L1, read the shared XCD-local L2 (publishers are intra-XCD).
__device__ __forceinline__ void stage16v(bf16_t* lds, const bf16_t* src) {
    f32x4 v0, v1;
    const char* a0 = (const char*)src + threadIdx.x * 16;
    asm volatile(
        "global_load_dwordx4 %0, %2, off sc0\n\t"
        "global_load_dwordx4 %1, %3, off sc0\n\t"
        "s_waitcnt vmcnt(0)"
        : "=&v"(v0), "=&v"(v1)
        : "v"(a0), "v"(a0 + 8192)
        : "memory");
    {
        int off = threadIdx.x * 16;
        int row = off >> 10;
        int swz = off ^ ((row & 7) << 4);
        *(f32x4*)((char*)lds + swz) = v0;
    }
    {
        int off = 8192 + threadIdx.x * 16;
        int row = off >> 10;
        int swz = off ^ ((row & 7) << 4);
        *(f32x4*)((char*)lds + swz) = v1;
    }
}

__device__ __forceinline__ bf16x8 fragrd(const bf16_t* lds, int kt, int col, int quad) {
    int byte = (col * 1024 + kt * 64 + quad * 16) ^ ((col & 7) << 4);
    return *(const bf16x8*)((const char*)lds + byte);
}

// publish hv as bf16 packed u32 (even-col lanes store j, j+1); plain store
// -> write-through to the XCD-local L2 (readers are intra-XCD, sc0 loads).
__device__ __forceinline__ void publish(bf16_t* dst, int b, int j, float hv, int col) {
    bf16_t hb = (bf16_t)hv;
    unsigned short mb;
    __builtin_memcpy(&mb, &hb, 2);
    unsigned int pv = (unsigned int)__shfl_xor((int)(unsigned int)mb, 1);
    if ((col & 1) == 0) {
        unsigned int word = (unsigned int)mb | (pv << 16);
        *(unsigned int*)((char*)dst + (size_t)(b * DH_ + j) * 2) = word;
    }
}

__global__ __launch_bounds__(512, 2) void dec_persist(
    const bf16_t* __restrict__ weff, const float* __restrict__ beff,
    const float* __restrict__ ov,
    const bf16_t* __restrict__ wdhh0, const float* __restrict__ dbhh0,
    const bf16_t* __restrict__ wdih1, const float* __restrict__ dbih1,
    const bf16_t* __restrict__ wdhh1, const float* __restrict__ dbhh1,
    const float* __restrict__ h0init, const float* __restrict__ h1init,
    bf16_t* hx00, bf16_t* hx01, bf16_t* hx10, bf16_t* hx11,
    float* __restrict__ hist, unsigned int* __restrict__ bar) {
    __shared__ bf16_t sh[16 * 512];   // h0 (persists A<-B)
    __shared__ bf16_t sx[16 * 512];   // h1
    __shared__ f32x4 exch[12 * 64];   // acc exchange (12 tiles x 64 lanes)

    int s  = blockIdx.x >> 4;         // j-slice (partners stride 16 -> same XCD)
    int g  = blockIdx.x & 15;         // batch group
    int js = s * 32;
    int tid = threadIdx.x, w = tid >> 6, lane = tid & 63;
    int col = lane & 15, quad = lane >> 4;

    // ---- prologue: load 3 owned weight tiles into registers ----
    const bf16_t* mats[4] = { wdhh0, weff, wdih1, wdhh1 };
    bf16x8 frg[3][16];
    int tmat[3], texch[3];
#pragma unroll
    for (int sl = 0; sl < 3; ++sl) {
        int idx = w + sl * 8;         // 0..23
        int m = idx / 6, rem = idx - m * 6;
        int gate = rem >> 1, jh = rem & 1;
        tmat[sl] = m;
        texch[sl] = (m & 1) * 6 + rem;   // slot within phase: 0..11
        int row = gate * 512 + js + jh * 16 + col;
        const bf16_t* M = mats[m];
#pragma unroll
        for (int kt = 0; kt < 16; ++kt)
            frg[sl][kt] = *(const bf16x8*)(M + (size_t)row * DH_ + kt * 32 + quad * 8);
    }

    // epilogue-lane constants (valid for w<2; harmless elsewhere)
    int je = js + (w & 1) * 16 + col;
    float b0r = beff[je] + dbhh0[je],        b0z = beff[DH_ + je] + dbhh0[DH_ + je];
    float b0in = beff[2 * DH_ + je],         b0hn = dbhh0[2 * DH_ + je];
    float o0r = ov[je] + dbhh0[je],          o0z = ov[DH_ + je] + dbhh0[DH_ + je];
    float o0in = ov[2 * DH_ + je];
    float b1r = dbih1[je] + dbhh1[je],       b1z = dbih1[DH_ + je] + dbhh1[DH_ + je];
    float b1in = dbih1[2 * DH_ + je],        b1hn = dbhh1[2 * DH_ + je];

    // init: epilogue waves publish initial state, keep f32 carries
    float hold0[4], hold1[4];
    if (w < 2) {
#pragma unroll
        for (int i = 0; i < 4; ++i) {
            int b = g * 16 + quad * 4 + i;
            float v0 = h0init[(size_t)b * DH_ + je];
            float v1 = h1init[(size_t)b * DH_ + je];
            hold0[i] = v0; hold1[i] = v1;
            publish(hx01, b, je, v0, col);
            publish(hx11, b, je, v1, col);
        }
    }
    gbar16(bar + g);   // phase 0: init visible

    int ph = 1;
    for (int t = 0; t < OSL_; ++t) {
        bf16_t* write0 = (t & 1) ? hx01 : hx00;
        bf16_t* read0  = (t & 1) ? hx00 : hx01;
        bf16_t* write1 = (t & 1) ? hx11 : hx10;
        bf16_t* read1  = (t & 1) ? hx10 : hx11;
        bool dox = (t > 0);

        // ---------------- phase A: cell0 ----------------
        // sh holds h0(t-1) (staged in phase B of t-1); stage h1(t-1) only.
        if (t == 0) stage16v(sh, read0 + (size_t)g * 16 * DH_);
        stage16v(sx, read1 + (size_t)g * 16 * DH_);
        __syncthreads();

        {
            f32x4 acc[3] = {};
#pragma unroll
            for (int sl = 0; sl < 3; ++sl) {
                if (tmat[sl] == 0) {            // Whh0 x h0(t-1)
#pragma unroll
                    for (int kt = 0; kt < 16; ++kt)
                        acc[sl] = __builtin_amdgcn_mfma_f32_16x16x32_bf16(
                            fragrd(sh, kt, col, quad), frg[sl][kt], acc[sl], 0, 0, 0);
                } else if (tmat[sl] == 1 && dox) { // Weff x h1(t-1)
#pragma unroll
                    for (int kt = 0; kt < 16; ++kt)
                        acc[sl] = __builtin_amdgcn_mfma_f32_16x16x32_bf16(
                            fragrd(sx, kt, col, quad), frg[sl][kt], acc[sl], 0, 0, 0);
                }
            }
#pragma unroll
            for (int sl = 0; sl < 3; ++sl)
                if (tmat[sl] <= 1) exch[texch[sl] * 64 + lane] = acc[sl];
        }
        __syncthreads();

        if (w < 2) {
            int jh = w;
            f32x4 aR0 = exch[(0 + jh) * 64 + lane];
            f32x4 aZ0 = exch[(2 + jh) * 64 + lane];
            f32x4 aN0 = exch[(4 + jh) * 64 + lane];
            f32x4 aR1 = {}, aZ1 = {}, aN1 = {};
            if (dox) {
                aR1 = exch[(6 + jh) * 64 + lane];
                aZ1 = exch[(8 + jh) * 64 + lane];
                aN1 = exch[(10 + jh) * 64 + lane];
            }
#pragma unroll
            for (int i = 0; i < 4; ++i) {
                int b = g * 16 + quad * 4 + i;
                float r = sigm(aR0[i] + aR1[i] + (dox ? b0r : o0r));
                float z = sigm(aZ0[i] + aZ1[i] + (dox ? b0z : o0z));
                float gin = dox ? (aN1[i] + b0in) : o0in;
                float n = tanh_(gin + r * (aN0[i] + b0hn));
                float hv = (1.0f - z) * n + z * hold0[i];
                hold0[i] = hv;
                publish(write0, b, je, hv, col);
            }
        }
        gbar16(bar + ph * 16 + g); ph++;

        // ---------------- phase B: cell1 ----------------
        stage16v(sh, write0 + (size_t)g * 16 * DH_);   // h0(t)
        __syncthreads();

        {
            f32x4 acc[3] = {};
#pragma unroll
            for (int sl = 0; sl < 3; ++sl) {
                if (tmat[sl] == 2) {            // Wih1 x h0(t)
#pragma unroll
                    for (int kt = 0; kt < 16; ++kt)
                        acc[sl] = __builtin_amdgcn_mfma_f32_16x16x32_bf16(
                            fragrd(sh, kt, col, quad), frg[sl][kt], acc[sl], 0, 0, 0);
                } else if (tmat[sl] == 3) {     // Whh1 x h1(t-1)
#pragma unroll
                    for (int kt = 0; kt < 16; ++kt)
                        acc[sl] = __builtin_amdgcn_mfma_f32_16x16x32_bf16(
                            fragrd(sx, kt, col, quad), frg[sl][kt], acc[sl], 0, 0, 0);
                }
            }
#pragma unroll
            for (int sl = 0; sl < 3; ++sl)
                if (tmat[sl] >= 2) exch[texch[sl] * 64 + lane] = acc[sl];
        }
        __syncthreads();

        if (w < 2) {
            int jh = w;
            f32x4 giR = exch[(0 + jh) * 64 + lane];   // Wih1 (m&1==0)
            f32x4 giZ = exch[(2 + jh) * 64 + lane];
            f32x4 giN = exch[(4 + jh) * 64 + lane];
            f32x4 ghR = exch[(6 + jh) * 64 + lane];   // Whh1 (m&1==1)
            f32x4 ghZ = exch[(8 + jh) * 64 + lane];
            f32x4 ghN = exch[(10 + jh) * 64 + lane];
            float* hist_t = hist + (size_t)t * B_ * DH_;
#pragma unroll
            for (int i = 0; i < 4; ++i) {
                int b = g * 16 + quad * 4 + i;
                float r = sigm(giR[i] + ghR[i] + b1r);
                float z = sigm(giZ[i] + ghZ[i] + b1z);
                float n = tanh_(giN[i] + b1in + r * (ghN[i] + b1hn));
                float hv = (1.0f - z) * n + z * hold1[i];
                hold1[i] = hv;
                hist_t[(size_t)b * DH_ + je] = hv;
                publish(write1, b, je, hv, col);
            }
        }
        if (t < OSL_ - 1) { gbar16(bar + ph * 16 + g); ph++; }
    }
}

// ------------------------------- FC head -----------------------------------
__global__ __launch_bounds__(256) void fc_all(
    const float* __restrict__ hist, const float* __restrict__ fcw,
    const float* __restrict__ fcb, float* __restrict__ out) {
    int t  = blockIdx.x >> 4;
    int b0 = (blockIdx.x & 15) * 16;
    int tid = threadIdx.x;
    int bl = tid >> 4, o = (tid >> 3) & 1, part = tid & 7;
    const float* hp = hist + ((size_t)t * B_ + b0 + bl) * DH_;
    const float* wp = fcw + o * DH_;
    float s = 0.0f;
    for (int k = part * 64; k < part * 64 + 64; k += 4) {
        f32x4 hv = *(const f32x4*)(hp + k);
        f32x4 wv = *(const f32x4*)(wp + k);
        s += hv[0] * wv[0] + hv[1] * wv[1] + hv[2] * wv[2] + hv[3] * wv[3];
    }
    s += __shfl_down(s, 4); s += __shfl_down(s, 2); s += __shfl_down(s, 1);
    if (part == 0) out[(size_t)(b0 + bl) * (OSL_ * 2) + t * 2 + o] = s + fcb[o];
}

// ------------------------------ launcher -----------------------------------

#define OFF_WIH0E 0ull
#define OFF_WHH0E 196608ull
#define OFF_WIH1E 983040ull
#define OFF_WHH1E 2555904ull
#define OFF_WDHH0 3342336ull
#define OFF_WDIH1 4915200ull
#define OFF_WDHH1 6488064ull
#define OFF_WEFF  8060928ull
#define OFF_BEFF  9633792ull
#define OFF_BAR   9641984ull    // 41 phases x 16 groups (zeroed 1024 u32)
#define OFF_OV    9658368ull
#define OFF_H0A   9682944ull
#define OFF_H0B   10207232ull   // hx00 (256 KB) + hx01 (256 KB)
#define OFF_H1A   10731520ull
#define OFF_H1B   11255808ull   // hx10 (256 KB) + hx11 (256 KB)
#define OFF_HST   11780096ull
#define OFF_HIST  12304384ull
#define OFF_XCAT  22790144ull
#define OFF_GI    157007872ull

extern "C" void kernel_launch(void* const* d_in, const int* in_sizes, int n_in,
                              void* d_out, int out_size, void* d_ws, size_t ws_size,
                              hipStream_t stream) {
    const float* x      = (const float*)d_in[0];
    const float* st     = (const float*)d_in[1];
    const float* eWih0  = (const float*)d_in[2];
    const float* eWhh0  = (const float*)d_in[3];
    const float* ebih0  = (const float*)d_in[4];
    const float* ebhh0  = (const float*)d_in[5];
    const float* eWih1  = (const float*)d_in[6];
    const float* eWhh1  = (const float*)d_in[7];
    const float* ebih1  = (const float*)d_in[8];
    const float* ebhh1  = (const float*)d_in[9];
    const float* dWih0  = (const float*)d_in[10];
    const float* dWhh0  = (const float*)d_in[11];
    const float* dbih0  = (const float*)d_in[12];
    const float* dbhh0  = (const float*)d_in[13];
    const float* dWih1  = (const float*)d_in[14];
    const float* dWhh1  = (const float*)d_in[15];
    const float* dbih1  = (const float*)d_in[16];
    const float* dbhh1  = (const float*)d_in[17];
    const float* fcW    = (const float*)d_in[18];
    const float* fcb    = (const float*)d_in[19];

    char* ws = (char*)d_ws;
    bf16_t* wih0e = (bf16_t*)(ws + OFF_WIH0E);
    bf16_t* whh0e = (bf16_t*)(ws + OFF_WHH0E);
    bf16_t* wih1e = (bf16_t*)(ws + OFF_WIH1E);
    bf16_t* whh1e = (bf16_t*)(ws + OFF_WHH1E);
    bf16_t* wdhh0 = (bf16_t*)(ws + OFF_WDHH0);
    bf16_t* wdih1 = (bf16_t*)(ws + OFF_WDIH1);
    bf16_t* wdhh1 = (bf16_t*)(ws + OFF_WDHH1);
    bf16_t* weff  = (bf16_t*)(ws + OFF_WEFF);
    float*  beff  = (float*)(ws + OFF_BEFF);
    unsigned int* bar = (unsigned int*)(ws + OFF_BAR);
    float*  ovp   = (float*)(ws + OFF_OV);
    float*  h0init = (float*)(ws + OFF_H0A);
    float*  h1init = (float*)(ws + OFF_H1A);
    bf16_t* hx00  = (bf16_t*)(ws + OFF_H0B);
    bf16_t* hx01  = (bf16_t*)(ws + OFF_H0B + 262144ull);
    bf16_t* hx10  = (bf16_t*)(ws + OFF_H1B);
    bf16_t* hx11  = (bf16_t*)(ws + OFF_H1B + 262144ull);
    float*  hstate = (float*)(ws + OFF_HST);
    float*  hist  = (float*)(ws + OFF_HIST);
    bf16_t* xcat  = (bf16_t*)(ws + OFF_XCAT);
    bf16_t* gi    = (bf16_t*)(ws + OFF_GI);

    int Tc = 512;
    while (Tc > 8 && OFF_GI + (unsigned long long)Tc * 786432ull > (unsigned long long)ws_size)
        Tc >>= 1;
    int nch = T_ / Tc;

    prep_all<<<dim3(3072, 8), 256, 0, stream>>>(
        eWih0, eWhh0, eWih1, eWhh1, dWhh0, dWih1, dWhh1,
        wih0e, whh0e, wih1e, whh1e, wdhh0, wdih1, wdhh1,
        dWih0, fcW, fcb, dbih0, st, weff, beff, ovp, bar);

    for (int c = 0; c < nch; c++) {
        gemm_gi<<<dim3(Tc * 2, 12), 256, 0, stream>>>(x, nullptr, wih0e, gi, c * Tc, 64);
        gru_scan<<<32, 512, 0, stream>>>(gi, c * Tc, Tc, whh0e, ebih0, ebhh0, hstate, xcat, h0init);
    }
    for (int c = 0; c < nch; c++) {
        gemm_gi<<<dim3(Tc * 2, 12), 256, 0, stream>>>(nullptr, xcat, wih1e, gi, c * Tc, 512);
        gru_scan<<<32, 512, 0, stream>>>(gi, c * Tc, Tc, whh1e, ebih1, ebhh1, hstate, nullptr, h1init);
    }

    dec_persist<<<256, 512, 0, stream>>>(weff, beff, ovp,
                                         wdhh0, dbhh0, wdih1, dbih1, wdhh1, dbhh1,
                                         h0init, h1init,
                                         hx00, hx01, hx10, hx11,
                                         hist, bar);

    fc_all<<<OSL_ * 16, 256, 0, stream>>>(hist, fcW, fcb, (float*)d_out);
}